// Round 1
// baseline (2369.299 us; speedup 1.0000x reference)
//
#include <hip/hip_runtime.h>
#include <math.h>

#define B_ 32
#define T_ 1024
#define F_ 64
#define H_ 128
#define D_ 192
#define KH_ 16
#define C1_ 128
#define C2_ 256
#define C3_ 128
#define NC_ 10

__device__ __forceinline__ float sig_(float x){ return 1.f/(1.f+__expf(-x)); }
__device__ __forceinline__ float tanh_(float x){ return 1.f - 2.f/(__expf(2.f*x)+1.f); }
__device__ __forceinline__ float gelu_(float x){ return 0.5f*x*(1.f+erff(x*0.70710678118654752f)); }
__device__ __forceinline__ float softplus_(float x){ return fmaxf(x,0.f) + log1pf(__expf(-fabsf(x))); }

// ---------------------------------------------------------------- LSTM scan
// one block per batch element; weights in LDS; c-state in registers (tid<128)
__global__ __launch_bounds__(256) void lstm_kernel(
    const float* __restrict__ x, const float* __restrict__ w1, const float* __restrict__ b1,
    const float* __restrict__ w2, const float* __restrict__ b2, float* __restrict__ hidden)
{
  __shared__ float w1s[D_*KH_];     // [d][j]
  __shared__ float w2s[KH_*4*H_];   // [j][n]
  __shared__ float b2s[4*H_];
  __shared__ float b1s[KH_];
  __shared__ float xh[D_];          // [0..63]=x_t, [64..191]=h
  __shared__ float part[16][17];
  __shared__ float g1s[KH_];
  const int b = blockIdx.x, tid = threadIdx.x;
  for(int i=tid;i<D_*KH_;i+=256) w1s[i]=w1[i];
  for(int i=tid;i<KH_*4*H_;i+=256) w2s[i]=w2[i];
  for(int i=tid;i<4*H_;i+=256) b2s[i]=b2[i];
  if(tid<KH_) b1s[tid]=b1[tid];
  if(tid>=64 && tid<192) xh[tid]=0.f;
  float c = 0.f;
  __syncthreads();
  const float* xb = x + (size_t)b*T_*F_;
  float* hb = hidden + (size_t)b*T_*H_;
  const int p = tid>>4, j = tid&15;
  for(int t=0;t<T_;t++){
    if(tid<64) xh[tid] = xb[t*F_+tid];
    __syncthreads();
    // phase A: g1 = silu(cat @ w1 + b1)
    float s=0.f;
    const int dbase = p*12;
    #pragma unroll
    for(int q=0;q<12;q++){ s += xh[dbase+q]*w1s[(dbase+q)*KH_ + j]; }
    part[p][j]=s;
    __syncthreads();
    if(tid<KH_){
      float v=b1s[tid];
      #pragma unroll
      for(int q=0;q<16;q++) v+=part[q][tid];
      g1s[tid]= v * sig_(v);
    }
    __syncthreads();
    // phase B/C: gates + state
    if(tid<H_){
      float vi=b2s[tid], vf=b2s[H_+tid], vg=b2s[2*H_+tid], vo=b2s[3*H_+tid];
      #pragma unroll
      for(int q=0;q<KH_;q++){
        const float g=g1s[q]; const float* r=&w2s[q*4*H_];
        vi+=g*r[tid]; vf+=g*r[H_+tid]; vg+=g*r[2*H_+tid]; vo+=g*r[3*H_+tid];
      }
      c = sig_(vf)*c + sig_(vi)*tanh_(vg);
      float h = sig_(vo)*tanh_(c);
      xh[64+tid]=h;
      hb[(size_t)t*H_+tid]=h;
    }
    __syncthreads();
  }
}

// ---------------------------------------------------------------- row norms
__global__ __launch_bounds__(256) void norm_kernel(const float* __restrict__ hidden, float* __restrict__ norms)
{
  const int row = blockIdx.x*8 + (threadIdx.x>>5);
  const int l = threadIdx.x&31;
  const float* hr = hidden + (size_t)row*H_;
  float s = 0.f;
  for(int k=l;k<H_;k+=32){ float v=hr[k]; s+=v*v; }
  #pragma unroll
  for(int m=16;m>=1;m>>=1) s += __shfl_xor(s, m, 64);
  if(l==0) norms[row] = fmaxf(sqrtf(s), 1e-8f);
}

// ---------------------------------------------------------------- S rowsums (symmetric trick)
// rowsum[i] = sum_j!=i exp(-5.5(1-hn_i.hn_j)); psum[i] = sum_{j<i} (...)
__global__ __launch_bounds__(256) void s_kernel(
    const float* __restrict__ hidden, const float* __restrict__ norms,
    double* __restrict__ rowsum, double* __restrict__ psum)
{
  __shared__ float As[128][68];     // [k][i]  34.8 KB
  __shared__ float Bs[64][68];      // [k_half][j] 17.4 KB
  __shared__ double red[64][17];    // 8.7 KB
  const int b = blockIdx.x >> 4;
  const int i0 = (blockIdx.x & 15) * 64;
  const int tid = threadIdx.x;
  const float* hb = hidden + (size_t)b*T_*H_;
  const float* nb = norms + (size_t)b*T_;
  // stage A (normalized), layout [k][i]
  for(int idx=tid; idx<64*32; idx+=256){
    const int i = idx>>5, k4 = idx&31;
    float4 v = ((const float4*)(hb + (size_t)(i0+i)*H_))[k4];
    const float inv = 1.f/nb[i0+i];
    As[k4*4+0][i]=v.x*inv; As[k4*4+1][i]=v.y*inv; As[k4*4+2][i]=v.z*inv; As[k4*4+3][i]=v.w*inv;
  }
  double rs[4]={0,0,0,0}, ps[4]={0,0,0,0};
  const int tj = tid&15, ti = tid>>4;
  for(int jt=0;jt<16;jt++){
    const int j0 = jt*64;
    float acc[4][4];
    #pragma unroll
    for(int a=0;a<4;a++){
      #pragma unroll
      for(int cc=0;cc<4;cc++) acc[a][cc]=0.f;
    }
    for(int kh=0;kh<2;kh++){
      __syncthreads();
      for(int idx=tid; idx<64*16; idx+=256){
        const int jj = idx>>4, k4 = idx&15;
        float4 v = ((const float4*)(hb + (size_t)(j0+jj)*H_))[kh*16+k4];
        const float inv = 1.f/nb[j0+jj];
        Bs[k4*4+0][jj]=v.x*inv; Bs[k4*4+1][jj]=v.y*inv; Bs[k4*4+2][jj]=v.z*inv; Bs[k4*4+3][jj]=v.w*inv;
      }
      __syncthreads();
      for(int k=0;k<64;k++){
        const float4 a4 = *(const float4*)&As[kh*64+k][ti*4];
        const float4 b4 = *(const float4*)&Bs[k][tj*4];
        acc[0][0]+=a4.x*b4.x; acc[0][1]+=a4.x*b4.y; acc[0][2]+=a4.x*b4.z; acc[0][3]+=a4.x*b4.w;
        acc[1][0]+=a4.y*b4.x; acc[1][1]+=a4.y*b4.y; acc[1][2]+=a4.y*b4.z; acc[1][3]+=a4.y*b4.w;
        acc[2][0]+=a4.z*b4.x; acc[2][1]+=a4.z*b4.y; acc[2][2]+=a4.z*b4.z; acc[2][3]+=a4.z*b4.w;
        acc[3][0]+=a4.w*b4.x; acc[3][1]+=a4.w*b4.y; acc[3][2]+=a4.w*b4.z; acc[3][3]+=a4.w*b4.w;
      }
    }
    #pragma unroll
    for(int a=0;a<4;a++){
      const int gi = i0 + ti*4 + a;
      #pragma unroll
      for(int cc=0;cc<4;cc++){
        const int gj = j0 + tj*4 + cc;
        if(gi==gj) continue;
        const float sv = __expf(-5.5f*(1.f-acc[a][cc]));
        rs[a]+=(double)sv; if(gj<gi) ps[a]+=(double)sv;
      }
    }
  }
  __syncthreads();
  #pragma unroll
  for(int a=0;a<4;a++) red[ti*4+a][tj] = rs[a];
  __syncthreads();
  if(tid<64){ double v=0; for(int q=0;q<16;q++) v+=red[tid][q]; rowsum[(size_t)b*T_ + i0 + tid]=v; }
  __syncthreads();
  #pragma unroll
  for(int a=0;a<4;a++) red[ti*4+a][tj] = ps[a];
  __syncthreads();
  if(tid<64){ double v=0; for(int q=0;q<16;q++) v+=red[tid][q]; psum[(size_t)b*T_ + i0 + tid]=v; }
}

// ---------------------------------------------------------------- cluster: prefix+dist+argmax+corr
__global__ __launch_bounds__(256) void cluster_kernel(
    const double* __restrict__ rowsum, const double* __restrict__ psum,
    const float* __restrict__ hidden, float* __restrict__ corr, int* __restrict__ cuts)
{
  const int b = blockIdx.x, tid = threadIdx.x;
  const double* r = rowsum + (size_t)b*T_;
  const double* p = psum + (size_t)b*T_;
  __shared__ double sr[256], sp[256];
  __shared__ double totR_s;
  __shared__ double bd[256]; __shared__ int bidx[256];
  __shared__ int cut_s;
  double r4[4], p4[4];
  #pragma unroll
  for(int q=0;q<4;q++){ r4[q]=r[tid*4+q]; p4[q]=p[tid*4+q]; }
  sr[tid]=r4[0]+r4[1]+r4[2]+r4[3];
  sp[tid]=p4[0]+p4[1]+p4[2]+p4[3];
  __syncthreads();
  if(tid==0){
    double ar=0, ap=0;
    for(int i=0;i<256;i++){ double tr=sr[i], tp=sp[i]; sr[i]=ar; sp[i]=ap; ar+=tr; ap+=tp; }
    totR_s = ar;
  }
  __syncthreads();
  double cr = sr[tid], cp = sp[tid];
  const double full = totR_s;
  double best = -1e308; int bi = 1;
  #pragma unroll
  for(int q=0;q<4;q++){
    cr += r4[q]; cp += p4[q];
    const int i = 4*tid + q + 1;
    if(i < T_){
      const double TL = 2.0*cp;
      const double TRv = cr - TL;
      const double BR = full - TL - 2.0*TRv;
      const double di = (double)i, dn = (double)(T_-i);
      const double dist = TL/(di*di) + BR/(dn*dn) - (2.0*TRv)/(di*dn);
      if(dist > best){ best=dist; bi=i; }
    }
  }
  bd[tid]=best; bidx[tid]=bi;
  __syncthreads();
  if(tid==0){
    double bb=-1e308; int ii=1;
    for(int q=0;q<256;q++){ if(bd[q]>bb){ bb=bd[q]; ii=bidx[q]; } }
    cut_s=ii; cuts[b]=ii;
  }
  __syncthreads();
  const int cut = cut_s;
  const int h = tid&127, half = tid>>7;
  float s=0.f;
  const float* hb = hidden + (size_t)b*T_*H_;
  for(int t=half; t<cut; t+=2) s += hb[(size_t)t*H_ + h];
  __shared__ float c2[2][128];
  c2[half][h]=s;
  __syncthreads();
  if(tid<128) corr[b*H_+tid] = (c2[0][tid]+c2[1][tid])/(float)cut;
}

// ---------------------------------------------------------------- VAE heads (mu/std/z/mu_cat/std_cat/x1)
__global__ __launch_bounds__(128) void head1_kernel(
    const float* __restrict__ corr, const float* __restrict__ hidden,
    const float* __restrict__ eps_z, const float* __restrict__ eps_cat,
    const float* __restrict__ mu_w, const float* __restrict__ mu_b,
    const float* __restrict__ std_w, const float* __restrict__ std_b,
    const float* __restrict__ muc_w, const float* __restrict__ muc_b,
    const float* __restrict__ stdc_w, const float* __restrict__ stdc_b,
    float* __restrict__ out_mu, float* __restrict__ out_std,
    float* __restrict__ out_muc, float* __restrict__ out_stdc, float* __restrict__ x1)
{
  const int b=blockIdx.x, h=threadIdx.x;
  __shared__ float cs[128], xz[256];
  cs[h]=corr[b*H_+h];
  xz[h]=hidden[((size_t)b*T_ + (T_-1))*H_ + h];  // last
  __syncthreads();
  float m=mu_b[h], sdv=std_b[h];
  for(int k=0;k<H_;k++){ const float cv=cs[k]; m+=cv*mu_w[k*H_+h]; sdv+=cv*std_w[k*H_+h]; }
  const float stdv = softplus_(sdv);
  out_mu[b*H_+h]=m; out_std[b*H_+h]=stdv;
  xz[128+h] = m + stdv*eps_z[b*H_+h];
  __syncthreads();
  float mc=muc_b[h], sc=stdc_b[h];
  for(int k=0;k<256;k++){ const float v=xz[k]; mc+=v*muc_w[k*H_+h]; sc+=v*stdc_w[k*H_+h]; }
  const float stdc = softplus_(sc);
  out_muc[b*H_+h]=mc; out_stdc[b*H_+h]=stdc;
  x1[b*H_+h]=mc + stdc*eps_cat[b*H_+h];
}

// ---------------------------------------------------------------- transpose x (B,T,F)->(B,F,T)
__global__ __launch_bounds__(256) void transpose_kernel(const float* __restrict__ x, float* __restrict__ xT)
{
  __shared__ float tile[64][65];
  const int b = blockIdx.x>>4, t0 = (blockIdx.x&15)*64;
  const int tid=threadIdx.x;
  const int f = tid&63, r0 = tid>>6;
  for(int q=0;q<16;q++){
    const int tt = r0*16+q;
    tile[tt][f] = x[((size_t)b*T_ + t0+tt)*F_ + f];
  }
  __syncthreads();
  const int tl = tid&63, fr = tid>>6;
  for(int q=0;q<16;q++){
    const int ff = fr*16+q;
    xT[((size_t)b*F_ + ff)*T_ + t0 + tl] = tile[tl][ff];
  }
}

// ---------------------------------------------------------------- causal conv (implicit gemm) + bias + BN partials
__global__ __launch_bounds__(256) void conv_kernel(
    const float* __restrict__ in, const float* __restrict__ w, const float* __restrict__ bias,
    const float* __restrict__ scale, float* __restrict__ y, float* __restrict__ bnacc,
    int Cin, int Cout, int Kw, int TWP)
{
  extern __shared__ float lds[];
  float* xs = lds;                 // 16 * TWP
  float* wsl = lds + 16*TWP;       // 16*Kw*64
  const int b = blockIdx.z, co0 = blockIdx.y*64, t0 = blockIdx.x*64;
  const int tid = threadIdx.x, tj = tid&15, ti = tid>>4;
  const float* inb = in + (size_t)b*Cin*T_;
  const int TW = 64 + Kw - 1;
  float acc[4][4];
  #pragma unroll
  for(int a=0;a<4;a++){
    #pragma unroll
    for(int cc=0;cc<4;cc++) acc[a][cc]=0.f;
  }
  for(int c0=0;c0<Cin;c0+=16){
    __syncthreads();
    for(int idx=tid; idx<16*TW; idx+=256){
      const int ci = idx/TW, tt = idx - ci*TW;
      const int tg = t0 - (Kw-1) + tt;
      float v = (tg>=0) ? inb[(size_t)(c0+ci)*T_ + tg] : 0.f;
      if(scale) v *= scale[b*Cin + c0 + ci];
      xs[ci*TWP + tt] = v;
    }
    const int WR = 16*Kw;
    for(int idx=tid; idx<WR*64; idx+=256){
      const int rr = idx>>6, co = idx&63;
      const int ci = rr/Kw, kw = rr - ci*Kw;
      wsl[rr*64+co] = w[((size_t)(co0+co)*Cin + (c0+ci))*(size_t)Kw + kw];
    }
    __syncthreads();
    for(int ci=0;ci<16;ci++){
      const float* xrow = &xs[ci*TWP + ti*4];
      for(int kw=0; kw<Kw; kw++){
        const float4 b4 = *(const float4*)&wsl[(ci*Kw+kw)*64 + tj*4];
        const float a0=xrow[kw], a1=xrow[kw+1], a2=xrow[kw+2], a3=xrow[kw+3];
        acc[0][0]+=a0*b4.x; acc[0][1]+=a0*b4.y; acc[0][2]+=a0*b4.z; acc[0][3]+=a0*b4.w;
        acc[1][0]+=a1*b4.x; acc[1][1]+=a1*b4.y; acc[1][2]+=a1*b4.z; acc[1][3]+=a1*b4.w;
        acc[2][0]+=a2*b4.x; acc[2][1]+=a2*b4.y; acc[2][2]+=a2*b4.z; acc[2][3]+=a2*b4.w;
        acc[3][0]+=a3*b4.x; acc[3][1]+=a3*b4.y; acc[3][2]+=a3*b4.z; acc[3][3]+=a3*b4.w;
      }
    }
  }
  float psum[4], psq[4];
  #pragma unroll
  for(int cc=0;cc<4;cc++){
    const int co = co0 + tj*4 + cc;
    const float bv = bias[co];
    psum[cc]=0.f; psq[cc]=0.f;
    #pragma unroll
    for(int a=0;a<4;a++){
      const float v = acc[a][cc] + bv;
      y[((size_t)b*Cout + co)*T_ + t0 + ti*4 + a] = v;
      psum[cc]+=v; psq[cc]+=v*v;
    }
  }
  __syncthreads();
  float* red = lds;  // [64][17] reuse
  #pragma unroll
  for(int cc=0;cc<4;cc++) red[(tj*4+cc)*17 + ti] = psum[cc];
  __syncthreads();
  if(tid<64){ float s=0; for(int q=0;q<16;q++) s+=red[tid*17+q]; atomicAdd(&bnacc[co0+tid], s); }
  __syncthreads();
  #pragma unroll
  for(int cc=0;cc<4;cc++) red[(tj*4+cc)*17 + ti] = psq[cc];
  __syncthreads();
  if(tid<64){ float s=0; for(int q=0;q<16;q++) s+=red[tid*17+q]; atomicAdd(&bnacc[Cout+co0+tid], s); }
}

// ---------------------------------------------------------------- BN + gelu (in place) + per-(b,c) time-mean
__global__ __launch_bounds__(256) void bn_act_kernel(
    float* __restrict__ y, const float* __restrict__ bnacc,
    const float* __restrict__ gw, const float* __restrict__ bw,
    float* __restrict__ mean_out, int C)
{
  const int c = blockIdx.x, b = blockIdx.y, tid = threadIdx.x;
  const float cnt = (float)(B_*T_);
  const float m = bnacc[c]/cnt;
  const float var = bnacc[C+c]/cnt - m*m;
  const float sc = gw[c]/sqrtf(var+1e-3f);
  const float sh = bw[c] - m*sc;
  float4* yr = (float4*)(y + ((size_t)b*C + c)*T_);
  float4 v = yr[tid];
  v.x = gelu_(v.x*sc+sh); v.y = gelu_(v.y*sc+sh); v.z = gelu_(v.z*sc+sh); v.w = gelu_(v.w*sc+sh);
  yr[tid] = v;
  float s = v.x+v.y+v.z+v.w;
  #pragma unroll
  for(int m2=32;m2>=1;m2>>=1) s += __shfl_xor(s, m2, 64);
  __shared__ float wsum[4];
  if((tid&63)==0) wsum[tid>>6]=s;
  __syncthreads();
  if(tid==0) mean_out[(size_t)b*C + c] = (wsum[0]+wsum[1]+wsum[2]+wsum[3]) * (1.f/T_);
}

// ---------------------------------------------------------------- SE: scale = sigmoid(relu(mean@w1)@w2)
__global__ __launch_bounds__(256) void se_kernel(
    const float* __restrict__ mean_in, const float* __restrict__ w1, const float* __restrict__ w2,
    float* __restrict__ scale, int C, int R)
{
  __shared__ float ms[256], hs[16];
  const int b=blockIdx.x, tid=threadIdx.x;
  if(tid<C) ms[tid]=mean_in[b*C+tid];
  __syncthreads();
  if(tid<R){ float s=0; for(int k=0;k<C;k++) s+=ms[k]*w1[k*R+tid]; hs[tid]=fmaxf(s,0.f); }
  __syncthreads();
  if(tid<C){ float s=0; for(int k=0;k<R;k++) s+=hs[k]*w2[k*C+tid]; scale[b*C+tid]=sig_(s); }
}

// ---------------------------------------------------------------- final fc + log_softmax
__global__ __launch_bounds__(64) void head2_kernel(
    const float* __restrict__ x1, const float* __restrict__ x2,
    const float* __restrict__ fcw, const float* __restrict__ fcb, float* __restrict__ outls)
{
  const int b=blockIdx.x, tid=threadIdx.x;
  __shared__ float xa[256]; __shared__ float lg[NC_];
  for(int k=tid;k<256;k+=64) xa[k] = (k<128)? x1[b*128+k] : x2[b*128+(k-128)];
  __syncthreads();
  if(tid<NC_){
    float s = fcb[tid];
    for(int k=0;k<256;k++) s += xa[k]*fcw[k*NC_+tid];
    lg[tid]=s;
  }
  __syncthreads();
  if(tid==0){
    float mx=lg[0];
    for(int q=1;q<NC_;q++) mx=fmaxf(mx,lg[q]);
    float se=0;
    for(int q=0;q<NC_;q++) se += __expf(lg[q]-mx);
    const float lse = logf(se)+mx;
    for(int q=0;q<NC_;q++) outls[b*NC_+q] = lg[q]-lse;
  }
}

// ---------------------------------------------------------------- launch
extern "C" void kernel_launch(void* const* d_in, const int* in_sizes, int n_in,
                              void* d_out, int out_size, void* d_ws, size_t ws_size,
                              hipStream_t stream) {
  (void)in_sizes; (void)n_in; (void)out_size; (void)ws_size;
  const float* x        = (const float*)d_in[0];
  const float* eps_z    = (const float*)d_in[1];
  const float* eps_cat  = (const float*)d_in[2];
  const float* kan_w1   = (const float*)d_in[3];
  const float* kan_b1   = (const float*)d_in[4];
  const float* kan_w2   = (const float*)d_in[5];
  const float* kan_b2   = (const float*)d_in[6];
  const float* conv1_w  = (const float*)d_in[7];
  const float* conv1_b  = (const float*)d_in[8];
  const float* conv2_w  = (const float*)d_in[9];
  const float* conv2_b  = (const float*)d_in[10];
  const float* conv3_w  = (const float*)d_in[11];
  const float* conv3_b  = (const float*)d_in[12];
  const float* bn1_g    = (const float*)d_in[13];
  const float* bn1_b    = (const float*)d_in[14];
  const float* bn2_g    = (const float*)d_in[15];
  const float* bn2_b    = (const float*)d_in[16];
  const float* bn3_g    = (const float*)d_in[17];
  const float* bn3_b    = (const float*)d_in[18];
  const float* se1_w1   = (const float*)d_in[19];
  const float* se1_w2   = (const float*)d_in[20];
  const float* se2_w1   = (const float*)d_in[21];
  const float* se2_w2   = (const float*)d_in[22];
  const float* fc_mu_w  = (const float*)d_in[23];
  const float* fc_mu_b  = (const float*)d_in[24];
  const float* fc_std_w = (const float*)d_in[25];
  const float* fc_std_b = (const float*)d_in[26];
  const float* fc_muc_w = (const float*)d_in[27];
  const float* fc_muc_b = (const float*)d_in[28];
  const float* fc_stdc_w= (const float*)d_in[29];
  const float* fc_stdc_b= (const float*)d_in[30];
  const float* fc_w     = (const float*)d_in[31];
  const float* fc_b     = (const float*)d_in[32];

  float* out = (float*)d_out;
  float* out_ls   = out;           // 320
  float* out_mu   = out + 320;     // 4096
  float* out_std  = out + 320 + 4096;
  float* out_muc  = out + 320 + 2*4096;
  float* out_stdc = out + 320 + 3*4096;

  float* ws = (float*)d_ws;
  const size_t SZ_HID = (size_t)B_*T_*H_;          // 4194304
  const size_t SZ_XT  = (size_t)B_*F_*T_;          // 2097152
  const size_t SZ_Y1  = (size_t)B_*C1_*T_;         // 4194304
  const size_t SZ_Y2  = (size_t)B_*C2_*T_;         // 8388608
  float*  hidden = ws;                              // also reused as y3
  float*  xT     = hidden + SZ_HID;
  float*  y1     = xT + SZ_XT;
  float*  y2     = y1 + SZ_Y1;
  float*  norms  = y2 + SZ_Y2;                      // B*T
  float*  after_norms = norms + (size_t)B_*T_;
  double* rowsum = (double*)(after_norms);          // B*T doubles (offset is 8-aligned)
  double* psum   = rowsum + (size_t)B_*T_;
  float*  corr   = (float*)(psum + (size_t)B_*T_);  // B*H
  float*  x1     = corr + (size_t)B_*H_;
  float*  bnbuf  = x1 + (size_t)B_*H_;              // (128+256+128)*2 = 1024 floats
  float*  bn1    = bnbuf;
  float*  bn2    = bnbuf + 2*C1_;
  float*  bn3    = bnbuf + 2*C1_ + 2*C2_;
  float*  se1_in = bnbuf + 1024;
  float*  se1_sc = se1_in + (size_t)B_*C1_;
  float*  se2_in = se1_sc + (size_t)B_*C1_;
  float*  se2_sc = se2_in + (size_t)B_*C2_;
  float*  x2     = se2_sc + (size_t)B_*C2_;         // B*C3
  int*    cuts   = (int*)(x2 + (size_t)B_*C3_);
  float*  y3     = hidden;                          // reuse (LSTM outputs consumed by then)

  // zero BN accumulators
  hipMemsetAsync(bnbuf, 0, 1024*sizeof(float), stream);

  // ---- recurrent branch
  lstm_kernel<<<B_, 256, 0, stream>>>(x, kan_w1, kan_b1, kan_w2, kan_b2, hidden);
  norm_kernel<<<(B_*T_)/8, 256, 0, stream>>>(hidden, norms);
  s_kernel<<<B_*16, 256, 0, stream>>>(hidden, norms, rowsum, psum);
  cluster_kernel<<<B_, 256, 0, stream>>>(rowsum, psum, hidden, corr, cuts);
  head1_kernel<<<B_, 128, 0, stream>>>(corr, hidden, eps_z, eps_cat,
      fc_mu_w, fc_mu_b, fc_std_w, fc_std_b, fc_muc_w, fc_muc_b, fc_stdc_w, fc_stdc_b,
      out_mu, out_std, out_muc, out_stdc, x1);

  // ---- conv branch
  transpose_kernel<<<B_*16, 256, 0, stream>>>(x, xT);
  {
    const int Kw=8, TWP=72, Cin=F_, Cout=C1_;
    const size_t shmem = (size_t)(16*TWP + 16*Kw*64)*sizeof(float);
    conv_kernel<<<dim3(16, Cout/64, B_), 256, shmem, stream>>>(xT, conv1_w, conv1_b, nullptr, y1, bn1, Cin, Cout, Kw, TWP);
  }
  bn_act_kernel<<<dim3(C1_, B_), 256, 0, stream>>>(y1, bn1, bn1_g, bn1_b, se1_in, C1_);
  se_kernel<<<B_, 256, 0, stream>>>(se1_in, se1_w1, se1_w2, se1_sc, C1_, C1_/16);
  {
    const int Kw=5, TWP=68, Cin=C1_, Cout=C2_;
    const size_t shmem = (size_t)(16*TWP + 16*Kw*64)*sizeof(float);
    conv_kernel<<<dim3(16, Cout/64, B_), 256, shmem, stream>>>(y1, conv2_w, conv2_b, se1_sc, y2, bn2, Cin, Cout, Kw, TWP);
  }
  bn_act_kernel<<<dim3(C2_, B_), 256, 0, stream>>>(y2, bn2, bn2_g, bn2_b, se2_in, C2_);
  se_kernel<<<B_, 256, 0, stream>>>(se2_in, se2_w1, se2_w2, se2_sc, C2_, C2_/16);
  {
    const int Kw=3, TWP=68, Cin=C2_, Cout=C3_;
    const size_t shmem = (size_t)(16*TWP + 16*Kw*64)*sizeof(float);
    conv_kernel<<<dim3(16, Cout/64, B_), 256, shmem, stream>>>(y2, conv3_w, conv3_b, se2_sc, y3, bn3, Cin, Cout, Kw, TWP);
  }
  bn_act_kernel<<<dim3(C3_, B_), 256, 0, stream>>>(y3, bn3, bn3_g, bn3_b, x2, C3_);

  // ---- final head
  head2_kernel<<<B_, 64, 0, stream>>>(x1, x2, fc_w, fc_b, out_ls);
}

// Round 2
// 1995.713 us; speedup vs baseline: 1.1872x; 1.1872x over previous
//
#include <hip/hip_runtime.h>
#include <math.h>

#define B_ 32
#define T_ 1024
#define F_ 64
#define H_ 128
#define D_ 192
#define KH_ 16
#define C1_ 128
#define C2_ 256
#define C3_ 128
#define NC_ 10

__device__ __forceinline__ float sig_(float x){ return 1.f/(1.f+__expf(-x)); }
__device__ __forceinline__ float tanh_(float x){ return 1.f - 2.f/(__expf(2.f*x)+1.f); }
__device__ __forceinline__ float gelu_(float x){ return 0.5f*x*(1.f+erff(x*0.70710678118654752f)); }
__device__ __forceinline__ float softplus_(float x){ return fmaxf(x,0.f) + log1pf(__expf(-fabsf(x))); }

// ---------------------------------------------------------------- ax precompute
// ax[b,t,j] = b1[j] + sum_{d<64} x[b,t,d] * w1[d,j]   (the non-recurrent part)
__global__ __launch_bounds__(256) void ax_kernel(
    const float* __restrict__ x, const float* __restrict__ w1, const float* __restrict__ b1,
    float* __restrict__ ax)
{
  __shared__ float xs[16][68];   // padded: avoid 16-way bank conflict on column reads
  __shared__ float w1s[64][16];
  const int bt0 = blockIdx.x*16;
  const int tid = threadIdx.x;
  for(int i=tid;i<64*16;i+=256){ w1s[i>>4][i&15] = w1[i]; }
  for(int i=tid;i<16*64;i+=256){ const int r=i>>6, d=i&63; xs[r][d] = x[(size_t)(bt0+r)*64 + d]; }
  __syncthreads();
  const int r = tid>>4, j = tid&15;
  float s = b1[j];
  #pragma unroll
  for(int d=0; d<64; d++) s += xs[r][d]*w1s[d][j];
  ax[(size_t)(bt0+r)*16 + j] = s;
}

// ---------------------------------------------------------------- LSTM scan
// ONE WAVE per batch element. Wave-synchronous: no barriers. All recurrent
// weights in registers: w2 (16x512) -> 128 VGPR/lane, w1 h-part -> 32 VGPR/lane.
// lane l: j = l&15 (KAN hidden idx for phase A), g = l>>4 (d-chunk);
//         phase B: lane handles h indices {2l, 2l+1} of each gate block.
__global__ __launch_bounds__(64, 1) void lstm_kernel(
    const float* __restrict__ ax, const float* __restrict__ w1,
    const float* __restrict__ w2, const float* __restrict__ b2,
    float* __restrict__ hidden)
{
  __shared__ float hs[128];
  const int b = blockIdx.x, l = threadIdx.x;
  const int j = l & 15, g = l >> 4;

  float w1h[32];
  #pragma unroll
  for(int q=0;q<32;q++) w1h[q] = w1[(64 + g*32 + q)*KH_ + j];

  float w2r[128];   // w2r[k*8 + gg*2 + m] = w2[k][gg*128 + 2l + m]
  #pragma unroll
  for(int k=0;k<16;k++){
    #pragma unroll
    for(int u=0;u<8;u++)
      w2r[k*8+u] = w2[k*512 + (u>>1)*128 + 2*l + (u&1)];
  }
  float b2r[8];
  #pragma unroll
  for(int u=0;u<8;u++) b2r[u] = b2[(u>>1)*128 + 2*l + (u&1)];

  *(float2*)&hs[2*l] = make_float2(0.f, 0.f);
  float c0=0.f, c1=0.f;
  const float* axb = ax + (size_t)b*T_*KH_;
  float* hb = hidden + (size_t)b*T_*H_;
  float ax_cur = axb[j];
  __builtin_amdgcn_wave_barrier();

  for(int t=0;t<T_;t++){
    const float ax_next = (t+1<T_) ? axb[(size_t)(t+1)*KH_ + j] : 0.f;  // prefetch
    // phase A: a[j] = sum_d h[d]*w1h[d][j]  (this lane: d in [g*32, g*32+32))
    float a0=0.f,a1=0.f,a2=0.f,a3=0.f;
    #pragma unroll
    for(int q4=0;q4<8;q4++){
      const float4 hv = *(const float4*)&hs[g*32 + q4*4];
      a0 += hv.x*w1h[q4*4+0];
      a1 += hv.y*w1h[q4*4+1];
      a2 += hv.z*w1h[q4*4+2];
      a3 += hv.w*w1h[q4*4+3];
    }
    float a = (a0+a1)+(a2+a3);
    a += __shfl_xor(a, 16);
    a += __shfl_xor(a, 32);
    a += ax_cur;
    const float g1 = a * sig_(a);       // silu
    // phase B: gates = g1 @ w2 + b2 (registers only)
    float accB[8];
    #pragma unroll
    for(int u=0;u<8;u++) accB[u]=b2r[u];
    #pragma unroll
    for(int k=0;k<16;k++){
      const float gk = __shfl(g1, k);
      #pragma unroll
      for(int u=0;u<8;u++) accB[u] += gk * w2r[k*8+u];
    }
    // activations + state update (2 h per lane)
    float h0, h1;
    {
      const float vi=accB[0], vf=accB[2], vg=accB[4], vo=accB[6];
      c0 = sig_(vf)*c0 + sig_(vi)*tanh_(vg);
      h0 = sig_(vo)*tanh_(c0);
    }
    {
      const float vi=accB[1], vf=accB[3], vg=accB[5], vo=accB[7];
      c1 = sig_(vf)*c1 + sig_(vi)*tanh_(vg);
      h1 = sig_(vo)*tanh_(c1);
    }
    *(float2*)&hs[2*l] = make_float2(h0, h1);
    __builtin_amdgcn_wave_barrier();    // keep compiler from sinking the write past next read
    *(float2*)&hb[(size_t)t*H_ + 2*l] = make_float2(h0, h1);
    ax_cur = ax_next;
  }
}

// ---------------------------------------------------------------- row norms
__global__ __launch_bounds__(256) void norm_kernel(const float* __restrict__ hidden, float* __restrict__ norms)
{
  const int row = blockIdx.x*8 + (threadIdx.x>>5);
  const int l = threadIdx.x&31;
  const float* hr = hidden + (size_t)row*H_;
  float s = 0.f;
  for(int k=l;k<H_;k+=32){ float v=hr[k]; s+=v*v; }
  #pragma unroll
  for(int m=16;m>=1;m>>=1) s += __shfl_xor(s, m, 64);
  if(l==0) norms[row] = fmaxf(sqrtf(s), 1e-8f);
}

// ---------------------------------------------------------------- S rowsums (symmetric trick)
__global__ __launch_bounds__(256) void s_kernel(
    const float* __restrict__ hidden, const float* __restrict__ norms,
    double* __restrict__ rowsum, double* __restrict__ psum)
{
  __shared__ float As[128][68];
  __shared__ float Bs[64][68];
  __shared__ double red[64][17];
  const int b = blockIdx.x >> 4;
  const int i0 = (blockIdx.x & 15) * 64;
  const int tid = threadIdx.x;
  const float* hb = hidden + (size_t)b*T_*H_;
  const float* nb = norms + (size_t)b*T_;
  for(int idx=tid; idx<64*32; idx+=256){
    const int i = idx>>5, k4 = idx&31;
    float4 v = ((const float4*)(hb + (size_t)(i0+i)*H_))[k4];
    const float inv = 1.f/nb[i0+i];
    As[k4*4+0][i]=v.x*inv; As[k4*4+1][i]=v.y*inv; As[k4*4+2][i]=v.z*inv; As[k4*4+3][i]=v.w*inv;
  }
  double rs[4]={0,0,0,0}, ps[4]={0,0,0,0};
  const int tj = tid&15, ti = tid>>4;
  for(int jt=0;jt<16;jt++){
    const int j0 = jt*64;
    float acc[4][4];
    #pragma unroll
    for(int a=0;a<4;a++){
      #pragma unroll
      for(int cc=0;cc<4;cc++) acc[a][cc]=0.f;
    }
    for(int kh=0;kh<2;kh++){
      __syncthreads();
      for(int idx=tid; idx<64*16; idx+=256){
        const int jj = idx>>4, k4 = idx&15;
        float4 v = ((const float4*)(hb + (size_t)(j0+jj)*H_))[kh*16+k4];
        const float inv = 1.f/nb[j0+jj];
        Bs[k4*4+0][jj]=v.x*inv; Bs[k4*4+1][jj]=v.y*inv; Bs[k4*4+2][jj]=v.z*inv; Bs[k4*4+3][jj]=v.w*inv;
      }
      __syncthreads();
      for(int k=0;k<64;k++){
        const float4 a4 = *(const float4*)&As[kh*64+k][ti*4];
        const float4 b4 = *(const float4*)&Bs[k][tj*4];
        acc[0][0]+=a4.x*b4.x; acc[0][1]+=a4.x*b4.y; acc[0][2]+=a4.x*b4.z; acc[0][3]+=a4.x*b4.w;
        acc[1][0]+=a4.y*b4.x; acc[1][1]+=a4.y*b4.y; acc[1][2]+=a4.y*b4.z; acc[1][3]+=a4.y*b4.w;
        acc[2][0]+=a4.z*b4.x; acc[2][1]+=a4.z*b4.y; acc[2][2]+=a4.z*b4.z; acc[2][3]+=a4.z*b4.w;
        acc[3][0]+=a4.w*b4.x; acc[3][1]+=a4.w*b4.y; acc[3][2]+=a4.w*b4.z; acc[3][3]+=a4.w*b4.w;
      }
    }
    #pragma unroll
    for(int a=0;a<4;a++){
      const int gi = i0 + ti*4 + a;
      #pragma unroll
      for(int cc=0;cc<4;cc++){
        const int gj = j0 + tj*4 + cc;
        if(gi==gj) continue;
        const float sv = __expf(-5.5f*(1.f-acc[a][cc]));
        rs[a]+=(double)sv; if(gj<gi) ps[a]+=(double)sv;
      }
    }
  }
  __syncthreads();
  #pragma unroll
  for(int a=0;a<4;a++) red[ti*4+a][tj] = rs[a];
  __syncthreads();
  if(tid<64){ double v=0; for(int q=0;q<16;q++) v+=red[tid][q]; rowsum[(size_t)b*T_ + i0 + tid]=v; }
  __syncthreads();
  #pragma unroll
  for(int a=0;a<4;a++) red[ti*4+a][tj] = ps[a];
  __syncthreads();
  if(tid<64){ double v=0; for(int q=0;q<16;q++) v+=red[tid][q]; psum[(size_t)b*T_ + i0 + tid]=v; }
}

// ---------------------------------------------------------------- cluster: prefix+dist+argmax+corr
__global__ __launch_bounds__(256) void cluster_kernel(
    const double* __restrict__ rowsum, const double* __restrict__ psum,
    const float* __restrict__ hidden, float* __restrict__ corr, int* __restrict__ cuts)
{
  const int b = blockIdx.x, tid = threadIdx.x;
  const double* r = rowsum + (size_t)b*T_;
  const double* p = psum + (size_t)b*T_;
  __shared__ double sr[256], sp[256];
  __shared__ double totR_s;
  __shared__ double bd[256]; __shared__ int bidx[256];
  __shared__ int cut_s;
  double r4[4], p4[4];
  #pragma unroll
  for(int q=0;q<4;q++){ r4[q]=r[tid*4+q]; p4[q]=p[tid*4+q]; }
  sr[tid]=r4[0]+r4[1]+r4[2]+r4[3];
  sp[tid]=p4[0]+p4[1]+p4[2]+p4[3];
  __syncthreads();
  if(tid==0){
    double ar=0, ap=0;
    for(int i=0;i<256;i++){ double tr=sr[i], tp=sp[i]; sr[i]=ar; sp[i]=ap; ar+=tr; ap+=tp; }
    totR_s = ar;
  }
  __syncthreads();
  double cr = sr[tid], cp = sp[tid];
  const double full = totR_s;
  double best = -1e308; int bi = 1;
  #pragma unroll
  for(int q=0;q<4;q++){
    cr += r4[q]; cp += p4[q];
    const int i = 4*tid + q + 1;
    if(i < T_){
      const double TL = 2.0*cp;
      const double TRv = cr - TL;
      const double BR = full - TL - 2.0*TRv;
      const double di = (double)i, dn = (double)(T_-i);
      const double dist = TL/(di*di) + BR/(dn*dn) - (2.0*TRv)/(di*dn);
      if(dist > best){ best=dist; bi=i; }
    }
  }
  bd[tid]=best; bidx[tid]=bi;
  __syncthreads();
  if(tid==0){
    double bb=-1e308; int ii=1;
    for(int q=0;q<256;q++){ if(bd[q]>bb){ bb=bd[q]; ii=bidx[q]; } }
    cut_s=ii; cuts[b]=ii;
  }
  __syncthreads();
  const int cut = cut_s;
  const int h = tid&127, half = tid>>7;
  float s=0.f;
  const float* hb = hidden + (size_t)b*T_*H_;
  for(int t=half; t<cut; t+=2) s += hb[(size_t)t*H_ + h];
  __shared__ float c2[2][128];
  c2[half][h]=s;
  __syncthreads();
  if(tid<128) corr[b*H_+tid] = (c2[0][tid]+c2[1][tid])/(float)cut;
}

// ---------------------------------------------------------------- VAE heads
__global__ __launch_bounds__(128) void head1_kernel(
    const float* __restrict__ corr, const float* __restrict__ hidden,
    const float* __restrict__ eps_z, const float* __restrict__ eps_cat,
    const float* __restrict__ mu_w, const float* __restrict__ mu_b,
    const float* __restrict__ std_w, const float* __restrict__ std_b,
    const float* __restrict__ muc_w, const float* __restrict__ muc_b,
    const float* __restrict__ stdc_w, const float* __restrict__ stdc_b,
    float* __restrict__ out_mu, float* __restrict__ out_std,
    float* __restrict__ out_muc, float* __restrict__ out_stdc, float* __restrict__ x1)
{
  const int b=blockIdx.x, h=threadIdx.x;
  __shared__ float cs[128], xz[256];
  cs[h]=corr[b*H_+h];
  xz[h]=hidden[((size_t)b*T_ + (T_-1))*H_ + h];
  __syncthreads();
  float m=mu_b[h], sdv=std_b[h];
  for(int k=0;k<H_;k++){ const float cv=cs[k]; m+=cv*mu_w[k*H_+h]; sdv+=cv*std_w[k*H_+h]; }
  const float stdv = softplus_(sdv);
  out_mu[b*H_+h]=m; out_std[b*H_+h]=stdv;
  xz[128+h] = m + stdv*eps_z[b*H_+h];
  __syncthreads();
  float mc=muc_b[h], sc=stdc_b[h];
  for(int k=0;k<256;k++){ const float v=xz[k]; mc+=v*muc_w[k*H_+h]; sc+=v*stdc_w[k*H_+h]; }
  const float stdc = softplus_(sc);
  out_muc[b*H_+h]=mc; out_stdc[b*H_+h]=stdc;
  x1[b*H_+h]=mc + stdc*eps_cat[b*H_+h];
}

// ---------------------------------------------------------------- transpose x (B,T,F)->(B,F,T)
__global__ __launch_bounds__(256) void transpose_kernel(const float* __restrict__ x, float* __restrict__ xT)
{
  __shared__ float tile[64][65];
  const int b = blockIdx.x>>4, t0 = (blockIdx.x&15)*64;
  const int tid=threadIdx.x;
  const int f = tid&63, r0 = tid>>6;
  for(int q=0;q<16;q++){
    const int tt = r0*16+q;
    tile[tt][f] = x[((size_t)b*T_ + t0+tt)*F_ + f];
  }
  __syncthreads();
  const int tl = tid&63, fr = tid>>6;
  for(int q=0;q<16;q++){
    const int ff = fr*16+q;
    xT[((size_t)b*F_ + ff)*T_ + t0 + tl] = tile[tl][ff];
  }
}

// ---------------------------------------------------------------- causal conv (implicit gemm) + bias + BN partials
__global__ __launch_bounds__(256) void conv_kernel(
    const float* __restrict__ in, const float* __restrict__ w, const float* __restrict__ bias,
    const float* __restrict__ scale, float* __restrict__ y, float* __restrict__ bnacc,
    int Cin, int Cout, int Kw, int TWP)
{
  extern __shared__ float lds[];
  float* xs = lds;
  float* wsl = lds + 16*TWP;
  const int b = blockIdx.z, co0 = blockIdx.y*64, t0 = blockIdx.x*64;
  const int tid = threadIdx.x, tj = tid&15, ti = tid>>4;
  const float* inb = in + (size_t)b*Cin*T_;
  const int TW = 64 + Kw - 1;
  float acc[4][4];
  #pragma unroll
  for(int a=0;a<4;a++){
    #pragma unroll
    for(int cc=0;cc<4;cc++) acc[a][cc]=0.f;
  }
  for(int c0=0;c0<Cin;c0+=16){
    __syncthreads();
    for(int idx=tid; idx<16*TW; idx+=256){
      const int ci = idx/TW, tt = idx - ci*TW;
      const int tg = t0 - (Kw-1) + tt;
      float v = (tg>=0) ? inb[(size_t)(c0+ci)*T_ + tg] : 0.f;
      if(scale) v *= scale[b*Cin + c0 + ci];
      xs[ci*TWP + tt] = v;
    }
    const int WR = 16*Kw;
    for(int idx=tid; idx<WR*64; idx+=256){
      const int rr = idx>>6, co = idx&63;
      const int ci = rr/Kw, kw = rr - ci*Kw;
      wsl[rr*64+co] = w[((size_t)(co0+co)*Cin + (c0+ci))*(size_t)Kw + kw];
    }
    __syncthreads();
    for(int ci=0;ci<16;ci++){
      const float* xrow = &xs[ci*TWP + ti*4];
      for(int kw=0; kw<Kw; kw++){
        const float4 b4 = *(const float4*)&wsl[(ci*Kw+kw)*64 + tj*4];
        const float a0=xrow[kw], a1=xrow[kw+1], a2=xrow[kw+2], a3=xrow[kw+3];
        acc[0][0]+=a0*b4.x; acc[0][1]+=a0*b4.y; acc[0][2]+=a0*b4.z; acc[0][3]+=a0*b4.w;
        acc[1][0]+=a1*b4.x; acc[1][1]+=a1*b4.y; acc[1][2]+=a1*b4.z; acc[1][3]+=a1*b4.w;
        acc[2][0]+=a2*b4.x; acc[2][1]+=a2*b4.y; acc[2][2]+=a2*b4.z; acc[2][3]+=a2*b4.w;
        acc[3][0]+=a3*b4.x; acc[3][1]+=a3*b4.y; acc[3][2]+=a3*b4.z; acc[3][3]+=a3*b4.w;
      }
    }
  }
  float psum[4], psq[4];
  #pragma unroll
  for(int cc=0;cc<4;cc++){
    const int co = co0 + tj*4 + cc;
    const float bv = bias[co];
    psum[cc]=0.f; psq[cc]=0.f;
    #pragma unroll
    for(int a=0;a<4;a++){
      const float v = acc[a][cc] + bv;
      y[((size_t)b*Cout + co)*T_ + t0 + ti*4 + a] = v;
      psum[cc]+=v; psq[cc]+=v*v;
    }
  }
  __syncthreads();
  float* red = lds;
  #pragma unroll
  for(int cc=0;cc<4;cc++) red[(tj*4+cc)*17 + ti] = psum[cc];
  __syncthreads();
  if(tid<64){ float s=0; for(int q=0;q<16;q++) s+=red[tid*17+q]; atomicAdd(&bnacc[co0+tid], s); }
  __syncthreads();
  #pragma unroll
  for(int cc=0;cc<4;cc++) red[(tj*4+cc)*17 + ti] = psq[cc];
  __syncthreads();
  if(tid<64){ float s=0; for(int q=0;q<16;q++) s+=red[tid*17+q]; atomicAdd(&bnacc[Cout+co0+tid], s); }
}

// ---------------------------------------------------------------- BN + gelu (in place) + time-mean
__global__ __launch_bounds__(256) void bn_act_kernel(
    float* __restrict__ y, const float* __restrict__ bnacc,
    const float* __restrict__ gw, const float* __restrict__ bw,
    float* __restrict__ mean_out, int C)
{
  const int c = blockIdx.x, b = blockIdx.y, tid = threadIdx.x;
  const float cnt = (float)(B_*T_);
  const float m = bnacc[c]/cnt;
  const float var = bnacc[C+c]/cnt - m*m;
  const float sc = gw[c]/sqrtf(var+1e-3f);
  const float sh = bw[c] - m*sc;
  float4* yr = (float4*)(y + ((size_t)b*C + c)*T_);
  float4 v = yr[tid];
  v.x = gelu_(v.x*sc+sh); v.y = gelu_(v.y*sc+sh); v.z = gelu_(v.z*sc+sh); v.w = gelu_(v.w*sc+sh);
  yr[tid] = v;
  float s = v.x+v.y+v.z+v.w;
  #pragma unroll
  for(int m2=32;m2>=1;m2>>=1) s += __shfl_xor(s, m2, 64);
  __shared__ float wsum[4];
  if((tid&63)==0) wsum[tid>>6]=s;
  __syncthreads();
  if(tid==0) mean_out[(size_t)b*C + c] = (wsum[0]+wsum[1]+wsum[2]+wsum[3]) * (1.f/T_);
}

// ---------------------------------------------------------------- SE
__global__ __launch_bounds__(256) void se_kernel(
    const float* __restrict__ mean_in, const float* __restrict__ w1, const float* __restrict__ w2,
    float* __restrict__ scale, int C, int R)
{
  __shared__ float ms[256], hs[16];
  const int b=blockIdx.x, tid=threadIdx.x;
  if(tid<C) ms[tid]=mean_in[b*C+tid];
  __syncthreads();
  if(tid<R){ float s=0; for(int k=0;k<C;k++) s+=ms[k]*w1[k*R+tid]; hs[tid]=fmaxf(s,0.f); }
  __syncthreads();
  if(tid<C){ float s=0; for(int k=0;k<R;k++) s+=hs[k]*w2[k*C+tid]; scale[b*C+tid]=sig_(s); }
}

// ---------------------------------------------------------------- final fc + log_softmax
__global__ __launch_bounds__(64) void head2_kernel(
    const float* __restrict__ x1, const float* __restrict__ x2,
    const float* __restrict__ fcw, const float* __restrict__ fcb, float* __restrict__ outls)
{
  const int b=blockIdx.x, tid=threadIdx.x;
  __shared__ float xa[256]; __shared__ float lg[NC_];
  for(int k=tid;k<256;k+=64) xa[k] = (k<128)? x1[b*128+k] : x2[b*128+(k-128)];
  __syncthreads();
  if(tid<NC_){
    float s = fcb[tid];
    for(int k=0;k<256;k++) s += xa[k]*fcw[k*NC_+tid];
    lg[tid]=s;
  }
  __syncthreads();
  if(tid==0){
    float mx=lg[0];
    for(int q=1;q<NC_;q++) mx=fmaxf(mx,lg[q]);
    float se=0;
    for(int q=0;q<NC_;q++) se += __expf(lg[q]-mx);
    const float lse = logf(se)+mx;
    for(int q=0;q<NC_;q++) outls[b*NC_+q] = lg[q]-lse;
  }
}

// ---------------------------------------------------------------- launch
extern "C" void kernel_launch(void* const* d_in, const int* in_sizes, int n_in,
                              void* d_out, int out_size, void* d_ws, size_t ws_size,
                              hipStream_t stream) {
  (void)in_sizes; (void)n_in; (void)out_size; (void)ws_size;
  const float* x        = (const float*)d_in[0];
  const float* eps_z    = (const float*)d_in[1];
  const float* eps_cat  = (const float*)d_in[2];
  const float* kan_w1   = (const float*)d_in[3];
  const float* kan_b1   = (const float*)d_in[4];
  const float* kan_w2   = (const float*)d_in[5];
  const float* kan_b2   = (const float*)d_in[6];
  const float* conv1_w  = (const float*)d_in[7];
  const float* conv1_b  = (const float*)d_in[8];
  const float* conv2_w  = (const float*)d_in[9];
  const float* conv2_b  = (const float*)d_in[10];
  const float* conv3_w  = (const float*)d_in[11];
  const float* conv3_b  = (const float*)d_in[12];
  const float* bn1_g    = (const float*)d_in[13];
  const float* bn1_b    = (const float*)d_in[14];
  const float* bn2_g    = (const float*)d_in[15];
  const float* bn2_b    = (const float*)d_in[16];
  const float* bn3_g    = (const float*)d_in[17];
  const float* bn3_b    = (const float*)d_in[18];
  const float* se1_w1   = (const float*)d_in[19];
  const float* se1_w2   = (const float*)d_in[20];
  const float* se2_w1   = (const float*)d_in[21];
  const float* se2_w2   = (const float*)d_in[22];
  const float* fc_mu_w  = (const float*)d_in[23];
  const float* fc_mu_b  = (const float*)d_in[24];
  const float* fc_std_w = (const float*)d_in[25];
  const float* fc_std_b = (const float*)d_in[26];
  const float* fc_muc_w = (const float*)d_in[27];
  const float* fc_muc_b = (const float*)d_in[28];
  const float* fc_stdc_w= (const float*)d_in[29];
  const float* fc_stdc_b= (const float*)d_in[30];
  const float* fc_w     = (const float*)d_in[31];
  const float* fc_b     = (const float*)d_in[32];

  float* out = (float*)d_out;
  float* out_ls   = out;
  float* out_mu   = out + 320;
  float* out_std  = out + 320 + 4096;
  float* out_muc  = out + 320 + 2*4096;
  float* out_stdc = out + 320 + 3*4096;

  float* ws = (float*)d_ws;
  const size_t SZ_HID = (size_t)B_*T_*H_;
  const size_t SZ_XT  = (size_t)B_*F_*T_;
  const size_t SZ_Y1  = (size_t)B_*C1_*T_;
  const size_t SZ_Y2  = (size_t)B_*C2_*T_;
  float*  hidden = ws;
  float*  xT     = hidden + SZ_HID;
  float*  y1     = xT + SZ_XT;
  float*  y2     = y1 + SZ_Y1;
  float*  norms  = y2 + SZ_Y2;
  float*  after_norms = norms + (size_t)B_*T_;
  double* rowsum = (double*)(after_norms);
  double* psum   = rowsum + (size_t)B_*T_;
  float*  corr   = (float*)(psum + (size_t)B_*T_);
  float*  x1     = corr + (size_t)B_*H_;
  float*  bnbuf  = x1 + (size_t)B_*H_;
  float*  bn1    = bnbuf;
  float*  bn2    = bnbuf + 2*C1_;
  float*  bn3    = bnbuf + 2*C1_ + 2*C2_;
  float*  se1_in = bnbuf + 1024;
  float*  se1_sc = se1_in + (size_t)B_*C1_;
  float*  se2_in = se1_sc + (size_t)B_*C1_;
  float*  se2_sc = se2_in + (size_t)B_*C2_;
  float*  x2     = se2_sc + (size_t)B_*C2_;
  int*    cuts   = (int*)(x2 + (size_t)B_*C3_);
  float*  axbuf  = (float*)(cuts + B_);             // B*T*KH = 512K floats
  float*  y3     = hidden;

  hipMemsetAsync(bnbuf, 0, 1024*sizeof(float), stream);

  // ---- recurrent branch
  ax_kernel<<<(B_*T_)/16, 256, 0, stream>>>(x, kan_w1, kan_b1, axbuf);
  lstm_kernel<<<B_, 64, 0, stream>>>(axbuf, kan_w1, kan_w2, kan_b2, hidden);
  norm_kernel<<<(B_*T_)/8, 256, 0, stream>>>(hidden, norms);
  s_kernel<<<B_*16, 256, 0, stream>>>(hidden, norms, rowsum, psum);
  cluster_kernel<<<B_, 256, 0, stream>>>(rowsum, psum, hidden, corr, cuts);
  head1_kernel<<<B_, 128, 0, stream>>>(corr, hidden, eps_z, eps_cat,
      fc_mu_w, fc_mu_b, fc_std_w, fc_std_b, fc_muc_w, fc_muc_b, fc_stdc_w, fc_stdc_b,
      out_mu, out_std, out_muc, out_stdc, x1);

  // ---- conv branch
  transpose_kernel<<<B_*16, 256, 0, stream>>>(x, xT);
  {
    const int Kw=8, TWP=72, Cin=F_, Cout=C1_;
    const size_t shmem = (size_t)(16*TWP + 16*Kw*64)*sizeof(float);
    conv_kernel<<<dim3(16, Cout/64, B_), 256, shmem, stream>>>(xT, conv1_w, conv1_b, nullptr, y1, bn1, Cin, Cout, Kw, TWP);
  }
  bn_act_kernel<<<dim3(C1_, B_), 256, 0, stream>>>(y1, bn1, bn1_g, bn1_b, se1_in, C1_);
  se_kernel<<<B_, 256, 0, stream>>>(se1_in, se1_w1, se1_w2, se1_sc, C1_, C1_/16);
  {
    const int Kw=5, TWP=68, Cin=C1_, Cout=C2_;
    const size_t shmem = (size_t)(16*TWP + 16*Kw*64)*sizeof(float);
    conv_kernel<<<dim3(16, Cout/64, B_), 256, shmem, stream>>>(y1, conv2_w, conv2_b, se1_sc, y2, bn2, Cin, Cout, Kw, TWP);
  }
  bn_act_kernel<<<dim3(C2_, B_), 256, 0, stream>>>(y2, bn2, bn2_g, bn2_b, se2_in, C2_);
  se_kernel<<<B_, 256, 0, stream>>>(se2_in, se2_w1, se2_w2, se2_sc, C2_, C2_/16);
  {
    const int Kw=3, TWP=68, Cin=C2_, Cout=C3_;
    const size_t shmem = (size_t)(16*TWP + 16*Kw*64)*sizeof(float);
    conv_kernel<<<dim3(16, Cout/64, B_), 256, shmem, stream>>>(y2, conv3_w, conv3_b, se2_sc, y3, bn3, Cin, Cout, Kw, TWP);
  }
  bn_act_kernel<<<dim3(C3_, B_), 256, 0, stream>>>(y3, bn3, bn3_g, bn3_b, x2, C3_);

  // ---- final head
  head2_kernel<<<B_, 64, 0, stream>>>(x1, x2, fc_w, fc_b, out_ls);
}

// Round 3
// 1623.668 us; speedup vs baseline: 1.4592x; 1.2291x over previous
//
#include <hip/hip_runtime.h>
#include <math.h>

#define B_ 32
#define T_ 1024
#define F_ 64
#define H_ 128
#define D_ 192
#define KH_ 16
#define C1_ 128
#define C2_ 256
#define C3_ 128
#define NC_ 10

typedef float v2f __attribute__((ext_vector_type(2)));

__device__ __forceinline__ float sig_(float x){ return 1.f/(1.f+__expf(-x)); }
__device__ __forceinline__ float tanh_(float x){ return 1.f - 2.f/(__expf(2.f*x)+1.f); }
__device__ __forceinline__ float gelu_(float x){ return 0.5f*x*(1.f+erff(x*0.70710678118654752f)); }
__device__ __forceinline__ float softplus_(float x){ return fmaxf(x,0.f) + log1pf(__expf(-fabsf(x))); }
__device__ __forceinline__ v2f sig2_(v2f x){ v2f r; r.x=sig_(x.x); r.y=sig_(x.y); return r; }
__device__ __forceinline__ v2f tanh2_(v2f x){ v2f r; r.x=tanh_(x.x); r.y=tanh_(x.y); return r; }

#define QPERM_XOR1(x) __int_as_float(__builtin_amdgcn_mov_dpp(__float_as_int(x), 0xB1, 0xF, 0xF, true))
#define QPERM_XOR2(x) __int_as_float(__builtin_amdgcn_mov_dpp(__float_as_int(x), 0x4E, 0xF, 0xF, true))

// ---------------------------------------------------------------- ax precompute
// ax[b,t,j] = b1[j] + sum_{d<64} x[b,t,d] * w1[d,j]   (the non-recurrent part)
__global__ __launch_bounds__(256) void ax_kernel(
    const float* __restrict__ x, const float* __restrict__ w1, const float* __restrict__ b1,
    float* __restrict__ ax)
{
  __shared__ float xs[16][68];
  __shared__ float w1s[64][16];
  const int bt0 = blockIdx.x*16;
  const int tid = threadIdx.x;
  for(int i=tid;i<64*16;i+=256){ w1s[i>>4][i&15] = w1[i]; }
  for(int i=tid;i<16*64;i+=256){ const int r=i>>6, d=i&63; xs[r][d] = x[(size_t)(bt0+r)*64 + d]; }
  __syncthreads();
  const int r = tid>>4, j = tid&15;
  float s = b1[j];
  #pragma unroll
  for(int d=0; d<64; d++) s += xs[r][d]*w1s[d][j];
  ax[(size_t)(bt0+r)*16 + j] = s;
}

// ---------------------------------------------------------------- LSTM scan
// ONE WAVE per batch. Layout: lane l -> j = l>>2 (KAN hidden idx),
// g = l&3 (d-quarter). Phase-A reduce = quad DPP (xor1/xor2). Phase B:
// v2f packed FMAs, w2 resident as v2f[64] (128 VGPR), g1 broadcast via
// v_readlane. h exchange through 512B LDS; no barriers (wave-synchronous).
__global__ __launch_bounds__(64, 1) void lstm_kernel(
    const float* __restrict__ ax, const float* __restrict__ w1,
    const float* __restrict__ w2, const float* __restrict__ b2,
    float* __restrict__ hidden)
{
  __shared__ float hs[128];
  const int b = blockIdx.x, l = threadIdx.x;
  const int j = l >> 2, g = l & 3;

  // w1 h-part, packed over d-pairs: w1hv[q] = {w1[64+g*32+2q][j], w1[64+g*32+2q+1][j]}
  v2f w1hv[16];
  #pragma unroll
  for(int q=0;q<16;q++){
    w1hv[q].x = w1[(64 + g*32 + 2*q)*KH_ + j];
    w1hv[q].y = w1[(64 + g*32 + 2*q + 1)*KH_ + j];
  }

  // w2 packed: w2r[k*4+u] = {w2[k][u*128+2l], w2[k][u*128+2l+1]}  (u: i,f,g,o)
  const v2f* w2v = (const v2f*)w2;
  const v2f* b2v = (const v2f*)b2;
  v2f w2r[64];
  #pragma unroll
  for(int k=0;k<16;k++){
    #pragma unroll
    for(int u=0;u<4;u++)
      w2r[k*4+u] = w2v[k*256 + u*64 + l];
  }
  v2f b2r[4];
  #pragma unroll
  for(int u=0;u<4;u++) b2r[u] = b2v[u*64 + l];

  ((v2f*)hs)[l] = (v2f)(0.f);
  v2f c = (v2f)(0.f);
  const float* axb = ax + (size_t)b*T_*KH_;
  float* hb = hidden + (size_t)b*T_*H_;
  float ax_cur = axb[j];
  __builtin_amdgcn_wave_barrier();

  for(int t=0;t<T_;t++){
    const float ax_next = (t<T_-1) ? axb[(size_t)(t+1)*KH_ + j] : 0.f;  // prefetch
    // phase A: partial a over d in [g*32, g*32+32), packed pairs
    v2f ap = (v2f)(0.f);
    #pragma unroll
    for(int q4=0;q4<8;q4++){
      const float4 hv = *(const float4*)&hs[g*32 + q4*4];
      v2f h01; h01.x=hv.x; h01.y=hv.y;
      v2f h23; h23.x=hv.z; h23.y=hv.w;
      ap += h01 * w1hv[q4*2];
      ap += h23 * w1hv[q4*2+1];
    }
    float a = ap.x + ap.y;
    a += QPERM_XOR1(a);
    a += QPERM_XOR2(a);
    a += ax_cur;
    const float g1 = a * sig_(a);       // silu
    // phase B: gates = g1 @ w2 + b2 (registers only, packed)
    v2f accB[4];
    #pragma unroll
    for(int u=0;u<4;u++) accB[u]=b2r[u];
    #pragma unroll
    for(int k=0;k<16;k++){
      const float gk = __int_as_float(__builtin_amdgcn_readlane(__float_as_int(g1), 4*k));
      v2f gk2; gk2.x=gk; gk2.y=gk;
      #pragma unroll
      for(int u=0;u<4;u++) accB[u] += gk2 * w2r[k*4+u];
    }
    // activations + state update (2 h per lane, packed where possible)
    const v2f si = sig2_(accB[0]);
    const v2f sf = sig2_(accB[1]);
    const v2f tg = tanh2_(accB[2]);
    const v2f so = sig2_(accB[3]);
    c = sf*c + si*tg;
    const v2f h = so * tanh2_(c);
    ((v2f*)hs)[l] = h;
    __builtin_amdgcn_wave_barrier();    // pin the LDS write before next iter's reads
    *(float2*)&hb[(size_t)t*H_ + 2*l] = make_float2(h.x, h.y);
    ax_cur = ax_next;
  }
}

// ---------------------------------------------------------------- row norms
__global__ __launch_bounds__(256) void norm_kernel(const float* __restrict__ hidden, float* __restrict__ norms)
{
  const int row = blockIdx.x*8 + (threadIdx.x>>5);
  const int l = threadIdx.x&31;
  const float* hr = hidden + (size_t)row*H_;
  float s = 0.f;
  for(int k=l;k<H_;k+=32){ float v=hr[k]; s+=v*v; }
  #pragma unroll
  for(int m=16;m>=1;m>>=1) s += __shfl_xor(s, m, 64);
  if(l==0) norms[row] = fmaxf(sqrtf(s), 1e-8f);
}

// ---------------------------------------------------------------- S rowsums (symmetric trick)
__global__ __launch_bounds__(256) void s_kernel(
    const float* __restrict__ hidden, const float* __restrict__ norms,
    double* __restrict__ rowsum, double* __restrict__ psum)
{
  __shared__ float As[128][68];
  __shared__ float Bs[64][68];
  __shared__ double red[64][17];
  const int b = blockIdx.x >> 4;
  const int i0 = (blockIdx.x & 15) * 64;
  const int tid = threadIdx.x;
  const float* hb = hidden + (size_t)b*T_*H_;
  const float* nb = norms + (size_t)b*T_;
  for(int idx=tid; idx<64*32; idx+=256){
    const int i = idx>>5, k4 = idx&31;
    float4 v = ((const float4*)(hb + (size_t)(i0+i)*H_))[k4];
    const float inv = 1.f/nb[i0+i];
    As[k4*4+0][i]=v.x*inv; As[k4*4+1][i]=v.y*inv; As[k4*4+2][i]=v.z*inv; As[k4*4+3][i]=v.w*inv;
  }
  double rs[4]={0,0,0,0}, ps[4]={0,0,0,0};
  const int tj = tid&15, ti = tid>>4;
  for(int jt=0;jt<16;jt++){
    const int j0 = jt*64;
    float acc[4][4];
    #pragma unroll
    for(int a=0;a<4;a++){
      #pragma unroll
      for(int cc=0;cc<4;cc++) acc[a][cc]=0.f;
    }
    for(int kh=0;kh<2;kh++){
      __syncthreads();
      for(int idx=tid; idx<64*16; idx+=256){
        const int jj = idx>>4, k4 = idx&15;
        float4 v = ((const float4*)(hb + (size_t)(j0+jj)*H_))[kh*16+k4];
        const float inv = 1.f/nb[j0+jj];
        Bs[k4*4+0][jj]=v.x*inv; Bs[k4*4+1][jj]=v.y*inv; Bs[k4*4+2][jj]=v.z*inv; Bs[k4*4+3][jj]=v.w*inv;
      }
      __syncthreads();
      for(int k=0;k<64;k++){
        const float4 a4 = *(const float4*)&As[kh*64+k][ti*4];
        const float4 b4 = *(const float4*)&Bs[k][tj*4];
        acc[0][0]+=a4.x*b4.x; acc[0][1]+=a4.x*b4.y; acc[0][2]+=a4.x*b4.z; acc[0][3]+=a4.x*b4.w;
        acc[1][0]+=a4.y*b4.x; acc[1][1]+=a4.y*b4.y; acc[1][2]+=a4.y*b4.z; acc[1][3]+=a4.y*b4.w;
        acc[2][0]+=a4.z*b4.x; acc[2][1]+=a4.z*b4.y; acc[2][2]+=a4.z*b4.z; acc[2][3]+=a4.z*b4.w;
        acc[3][0]+=a4.w*b4.x; acc[3][1]+=a4.w*b4.y; acc[3][2]+=a4.w*b4.z; acc[3][3]+=a4.w*b4.w;
      }
    }
    #pragma unroll
    for(int a=0;a<4;a++){
      const int gi = i0 + ti*4 + a;
      #pragma unroll
      for(int cc=0;cc<4;cc++){
        const int gj = j0 + tj*4 + cc;
        if(gi==gj) continue;
        const float sv = __expf(-5.5f*(1.f-acc[a][cc]));
        rs[a]+=(double)sv; if(gj<gi) ps[a]+=(double)sv;
      }
    }
  }
  __syncthreads();
  #pragma unroll
  for(int a=0;a<4;a++) red[ti*4+a][tj] = rs[a];
  __syncthreads();
  if(tid<64){ double v=0; for(int q=0;q<16;q++) v+=red[tid][q]; rowsum[(size_t)b*T_ + i0 + tid]=v; }
  __syncthreads();
  #pragma unroll
  for(int a=0;a<4;a++) red[ti*4+a][tj] = ps[a];
  __syncthreads();
  if(tid<64){ double v=0; for(int q=0;q<16;q++) v+=red[tid][q]; psum[(size_t)b*T_ + i0 + tid]=v; }
}

// ---------------------------------------------------------------- cluster: prefix+dist+argmax+corr
__global__ __launch_bounds__(256) void cluster_kernel(
    const double* __restrict__ rowsum, const double* __restrict__ psum,
    const float* __restrict__ hidden, float* __restrict__ corr, int* __restrict__ cuts)
{
  const int b = blockIdx.x, tid = threadIdx.x;
  const double* r = rowsum + (size_t)b*T_;
  const double* p = psum + (size_t)b*T_;
  __shared__ double sr[256], sp[256];
  __shared__ double totR_s;
  __shared__ double bd[256]; __shared__ int bidx[256];
  __shared__ int cut_s;
  double r4[4], p4[4];
  #pragma unroll
  for(int q=0;q<4;q++){ r4[q]=r[tid*4+q]; p4[q]=p[tid*4+q]; }
  sr[tid]=r4[0]+r4[1]+r4[2]+r4[3];
  sp[tid]=p4[0]+p4[1]+p4[2]+p4[3];
  __syncthreads();
  if(tid==0){
    double ar=0, ap=0;
    for(int i=0;i<256;i++){ double tr=sr[i], tp=sp[i]; sr[i]=ar; sp[i]=ap; ar+=tr; ap+=tp; }
    totR_s = ar;
  }
  __syncthreads();
  double cr = sr[tid], cp = sp[tid];
  const double full = totR_s;
  double best = -1e308; int bi = 1;
  #pragma unroll
  for(int q=0;q<4;q++){
    cr += r4[q]; cp += p4[q];
    const int i = 4*tid + q + 1;
    if(i < T_){
      const double TL = 2.0*cp;
      const double TRv = cr - TL;
      const double BR = full - TL - 2.0*TRv;
      const double di = (double)i, dn = (double)(T_-i);
      const double dist = TL/(di*di) + BR/(dn*dn) - (2.0*TRv)/(di*dn);
      if(dist > best){ best=dist; bi=i; }
    }
  }
  bd[tid]=best; bidx[tid]=bi;
  __syncthreads();
  if(tid==0){
    double bb=-1e308; int ii=1;
    for(int q=0;q<256;q++){ if(bd[q]>bb){ bb=bd[q]; ii=bidx[q]; } }
    cut_s=ii; cuts[b]=ii;
  }
  __syncthreads();
  const int cut = cut_s;
  const int h = tid&127, half = tid>>7;
  float s=0.f;
  const float* hb = hidden + (size_t)b*T_*H_;
  for(int t=half; t<cut; t+=2) s += hb[(size_t)t*H_ + h];
  __shared__ float c2[2][128];
  c2[half][h]=s;
  __syncthreads();
  if(tid<128) corr[b*H_+tid] = (c2[0][tid]+c2[1][tid])/(float)cut;
}

// ---------------------------------------------------------------- VAE heads
__global__ __launch_bounds__(128) void head1_kernel(
    const float* __restrict__ corr, const float* __restrict__ hidden,
    const float* __restrict__ eps_z, const float* __restrict__ eps_cat,
    const float* __restrict__ mu_w, const float* __restrict__ mu_b,
    const float* __restrict__ std_w, const float* __restrict__ std_b,
    const float* __restrict__ muc_w, const float* __restrict__ muc_b,
    const float* __restrict__ stdc_w, const float* __restrict__ stdc_b,
    float* __restrict__ out_mu, float* __restrict__ out_std,
    float* __restrict__ out_muc, float* __restrict__ out_stdc, float* __restrict__ x1)
{
  const int b=blockIdx.x, h=threadIdx.x;
  __shared__ float cs[128], xz[256];
  cs[h]=corr[b*H_+h];
  xz[h]=hidden[((size_t)b*T_ + (T_-1))*H_ + h];
  __syncthreads();
  float m=mu_b[h], sdv=std_b[h];
  for(int k=0;k<H_;k++){ const float cv=cs[k]; m+=cv*mu_w[k*H_+h]; sdv+=cv*std_w[k*H_+h]; }
  const float stdv = softplus_(sdv);
  out_mu[b*H_+h]=m; out_std[b*H_+h]=stdv;
  xz[128+h] = m + stdv*eps_z[b*H_+h];
  __syncthreads();
  float mc=muc_b[h], sc=stdc_b[h];
  for(int k=0;k<256;k++){ const float v=xz[k]; mc+=v*muc_w[k*H_+h]; sc+=v*stdc_w[k*H_+h]; }
  const float stdc = softplus_(sc);
  out_muc[b*H_+h]=mc; out_stdc[b*H_+h]=stdc;
  x1[b*H_+h]=mc + stdc*eps_cat[b*H_+h];
}

// ---------------------------------------------------------------- transpose x (B,T,F)->(B,F,T)
__global__ __launch_bounds__(256) void transpose_kernel(const float* __restrict__ x, float* __restrict__ xT)
{
  __shared__ float tile[64][65];
  const int b = blockIdx.x>>4, t0 = (blockIdx.x&15)*64;
  const int tid=threadIdx.x;
  const int f = tid&63, r0 = tid>>6;
  for(int q=0;q<16;q++){
    const int tt = r0*16+q;
    tile[tt][f] = x[((size_t)b*T_ + t0+tt)*F_ + f];
  }
  __syncthreads();
  const int tl = tid&63, fr = tid>>6;
  for(int q=0;q<16;q++){
    const int ff = fr*16+q;
    xT[((size_t)b*F_ + ff)*T_ + t0 + tl] = tile[tl][ff];
  }
}

// ---------------------------------------------------------------- causal conv (implicit gemm) + bias + BN partials
__global__ __launch_bounds__(256) void conv_kernel(
    const float* __restrict__ in, const float* __restrict__ w, const float* __restrict__ bias,
    const float* __restrict__ scale, float* __restrict__ y, float* __restrict__ bnacc,
    int Cin, int Cout, int Kw, int TWP)
{
  extern __shared__ float lds[];
  float* xs = lds;
  float* wsl = lds + 16*TWP;
  const int b = blockIdx.z, co0 = blockIdx.y*64, t0 = blockIdx.x*64;
  const int tid = threadIdx.x, tj = tid&15, ti = tid>>4;
  const float* inb = in + (size_t)b*Cin*T_;
  const int TW = 64 + Kw - 1;
  float acc[4][4];
  #pragma unroll
  for(int a=0;a<4;a++){
    #pragma unroll
    for(int cc=0;cc<4;cc++) acc[a][cc]=0.f;
  }
  for(int c0=0;c0<Cin;c0+=16){
    __syncthreads();
    for(int idx=tid; idx<16*TW; idx+=256){
      const int ci = idx/TW, tt = idx - ci*TW;
      const int tg = t0 - (Kw-1) + tt;
      float v = (tg>=0) ? inb[(size_t)(c0+ci)*T_ + tg] : 0.f;
      if(scale) v *= scale[b*Cin + c0 + ci];
      xs[ci*TWP + tt] = v;
    }
    const int WR = 16*Kw;
    for(int idx=tid; idx<WR*64; idx+=256){
      const int rr = idx>>6, co = idx&63;
      const int ci = rr/Kw, kw = rr - ci*Kw;
      wsl[rr*64+co] = w[((size_t)(co0+co)*Cin + (c0+ci))*(size_t)Kw + kw];
    }
    __syncthreads();
    for(int ci=0;ci<16;ci++){
      const float* xrow = &xs[ci*TWP + ti*4];
      for(int kw=0; kw<Kw; kw++){
        const float4 b4 = *(const float4*)&wsl[(ci*Kw+kw)*64 + tj*4];
        const float a0=xrow[kw], a1=xrow[kw+1], a2=xrow[kw+2], a3=xrow[kw+3];
        acc[0][0]+=a0*b4.x; acc[0][1]+=a0*b4.y; acc[0][2]+=a0*b4.z; acc[0][3]+=a0*b4.w;
        acc[1][0]+=a1*b4.x; acc[1][1]+=a1*b4.y; acc[1][2]+=a1*b4.z; acc[1][3]+=a1*b4.w;
        acc[2][0]+=a2*b4.x; acc[2][1]+=a2*b4.y; acc[2][2]+=a2*b4.z; acc[2][3]+=a2*b4.w;
        acc[3][0]+=a3*b4.x; acc[3][1]+=a3*b4.y; acc[3][2]+=a3*b4.z; acc[3][3]+=a3*b4.w;
      }
    }
  }
  float psum[4], psq[4];
  #pragma unroll
  for(int cc=0;cc<4;cc++){
    const int co = co0 + tj*4 + cc;
    const float bv = bias[co];
    psum[cc]=0.f; psq[cc]=0.f;
    #pragma unroll
    for(int a=0;a<4;a++){
      const float v = acc[a][cc] + bv;
      y[((size_t)b*Cout + co)*T_ + t0 + ti*4 + a] = v;
      psum[cc]+=v; psq[cc]+=v*v;
    }
  }
  __syncthreads();
  float* red = lds;
  #pragma unroll
  for(int cc=0;cc<4;cc++) red[(tj*4+cc)*17 + ti] = psum[cc];
  __syncthreads();
  if(tid<64){ float s=0; for(int q=0;q<16;q++) s+=red[tid*17+q]; atomicAdd(&bnacc[co0+tid], s); }
  __syncthreads();
  #pragma unroll
  for(int cc=0;cc<4;cc++) red[(tj*4+cc)*17 + ti] = psq[cc];
  __syncthreads();
  if(tid<64){ float s=0; for(int q=0;q<16;q++) s+=red[tid*17+q]; atomicAdd(&bnacc[Cout+co0+tid], s); }
}

// ---------------------------------------------------------------- BN + gelu (in place) + time-mean
__global__ __launch_bounds__(256) void bn_act_kernel(
    float* __restrict__ y, const float* __restrict__ bnacc,
    const float* __restrict__ gw, const float* __restrict__ bw,
    float* __restrict__ mean_out, int C)
{
  const int c = blockIdx.x, b = blockIdx.y, tid = threadIdx.x;
  const float cnt = (float)(B_*T_);
  const float m = bnacc[c]/cnt;
  const float var = bnacc[C+c]/cnt - m*m;
  const float sc = gw[c]/sqrtf(var+1e-3f);
  const float sh = bw[c] - m*sc;
  float4* yr = (float4*)(y + ((size_t)b*C + c)*T_);
  float4 v = yr[tid];
  v.x = gelu_(v.x*sc+sh); v.y = gelu_(v.y*sc+sh); v.z = gelu_(v.z*sc+sh); v.w = gelu_(v.w*sc+sh);
  yr[tid] = v;
  float s = v.x+v.y+v.z+v.w;
  #pragma unroll
  for(int m2=32;m2>=1;m2>>=1) s += __shfl_xor(s, m2, 64);
  __shared__ float wsum[4];
  if((tid&63)==0) wsum[tid>>6]=s;
  __syncthreads();
  if(tid==0) mean_out[(size_t)b*C + c] = (wsum[0]+wsum[1]+wsum[2]+wsum[3]) * (1.f/T_);
}

// ---------------------------------------------------------------- SE
__global__ __launch_bounds__(256) void se_kernel(
    const float* __restrict__ mean_in, const float* __restrict__ w1, const float* __restrict__ w2,
    float* __restrict__ scale, int C, int R)
{
  __shared__ float ms[256], hs[16];
  const int b=blockIdx.x, tid=threadIdx.x;
  if(tid<C) ms[tid]=mean_in[b*C+tid];
  __syncthreads();
  if(tid<R){ float s=0; for(int k=0;k<C;k++) s+=ms[k]*w1[k*R+tid]; hs[tid]=fmaxf(s,0.f); }
  __syncthreads();
  if(tid<C){ float s=0; for(int k=0;k<R;k++) s+=hs[k]*w2[k*C+tid]; scale[b*C+tid]=sig_(s); }
}

// ---------------------------------------------------------------- final fc + log_softmax
__global__ __launch_bounds__(64) void head2_kernel(
    const float* __restrict__ x1, const float* __restrict__ x2,
    const float* __restrict__ fcw, const float* __restrict__ fcb, float* __restrict__ outls)
{
  const int b=blockIdx.x, tid=threadIdx.x;
  __shared__ float xa[256]; __shared__ float lg[NC_];
  for(int k=tid;k<256;k+=64) xa[k] = (k<128)? x1[b*128+k] : x2[b*128+(k-128)];
  __syncthreads();
  if(tid<NC_){
    float s = fcb[tid];
    for(int k=0;k<256;k++) s += xa[k]*fcw[k*NC_+tid];
    lg[tid]=s;
  }
  __syncthreads();
  if(tid==0){
    float mx=lg[0];
    for(int q=1;q<NC_;q++) mx=fmaxf(mx,lg[q]);
    float se=0;
    for(int q=0;q<NC_;q++) se += __expf(lg[q]-mx);
    const float lse = logf(se)+mx;
    for(int q=0;q<NC_;q++) outls[b*NC_+q] = lg[q]-lse;
  }
}

// ---------------------------------------------------------------- launch
extern "C" void kernel_launch(void* const* d_in, const int* in_sizes, int n_in,
                              void* d_out, int out_size, void* d_ws, size_t ws_size,
                              hipStream_t stream) {
  (void)in_sizes; (void)n_in; (void)out_size; (void)ws_size;
  const float* x        = (const float*)d_in[0];
  const float* eps_z    = (const float*)d_in[1];
  const float* eps_cat  = (const float*)d_in[2];
  const float* kan_w1   = (const float*)d_in[3];
  const float* kan_b1   = (const float*)d_in[4];
  const float* kan_w2   = (const float*)d_in[5];
  const float* kan_b2   = (const float*)d_in[6];
  const float* conv1_w  = (const float*)d_in[7];
  const float* conv1_b  = (const float*)d_in[8];
  const float* conv2_w  = (const float*)d_in[9];
  const float* conv2_b  = (const float*)d_in[10];
  const float* conv3_w  = (const float*)d_in[11];
  const float* conv3_b  = (const float*)d_in[12];
  const float* bn1_g    = (const float*)d_in[13];
  const float* bn1_b    = (const float*)d_in[14];
  const float* bn2_g    = (const float*)d_in[15];
  const float* bn2_b    = (const float*)d_in[16];
  const float* bn3_g    = (const float*)d_in[17];
  const float* bn3_b    = (const float*)d_in[18];
  const float* se1_w1   = (const float*)d_in[19];
  const float* se1_w2   = (const float*)d_in[20];
  const float* se2_w1   = (const float*)d_in[21];
  const float* se2_w2   = (const float*)d_in[22];
  const float* fc_mu_w  = (const float*)d_in[23];
  const float* fc_mu_b  = (const float*)d_in[24];
  const float* fc_std_w = (const float*)d_in[25];
  const float* fc_std_b = (const float*)d_in[26];
  const float* fc_muc_w = (const float*)d_in[27];
  const float* fc_muc_b = (const float*)d_in[28];
  const float* fc_stdc_w= (const float*)d_in[29];
  const float* fc_stdc_b= (const float*)d_in[30];
  const float* fc_w     = (const float*)d_in[31];
  const float* fc_b     = (const float*)d_in[32];

  float* out = (float*)d_out;
  float* out_ls   = out;
  float* out_mu   = out + 320;
  float* out_std  = out + 320 + 4096;
  float* out_muc  = out + 320 + 2*4096;
  float* out_stdc = out + 320 + 3*4096;

  float* ws = (float*)d_ws;
  const size_t SZ_HID = (size_t)B_*T_*H_;
  const size_t SZ_XT  = (size_t)B_*F_*T_;
  const size_t SZ_Y1  = (size_t)B_*C1_*T_;
  const size_t SZ_Y2  = (size_t)B_*C2_*T_;
  float*  hidden = ws;
  float*  xT     = hidden + SZ_HID;
  float*  y1     = xT + SZ_XT;
  float*  y2     = y1 + SZ_Y1;
  float*  norms  = y2 + SZ_Y2;
  float*  after_norms = norms + (size_t)B_*T_;
  double* rowsum = (double*)(after_norms);
  double* psum   = rowsum + (size_t)B_*T_;
  float*  corr   = (float*)(psum + (size_t)B_*T_);
  float*  x1     = corr + (size_t)B_*H_;
  float*  bnbuf  = x1 + (size_t)B_*H_;
  float*  bn1    = bnbuf;
  float*  bn2    = bnbuf + 2*C1_;
  float*  bn3    = bnbuf + 2*C1_ + 2*C2_;
  float*  se1_in = bnbuf + 1024;
  float*  se1_sc = se1_in + (size_t)B_*C1_;
  float*  se2_in = se1_sc + (size_t)B_*C1_;
  float*  se2_sc = se2_in + (size_t)B_*C2_;
  float*  x2     = se2_sc + (size_t)B_*C2_;
  int*    cuts   = (int*)(x2 + (size_t)B_*C3_);
  float*  axbuf  = (float*)(cuts + B_);             // B*T*KH = 512K floats
  float*  y3     = hidden;

  hipMemsetAsync(bnbuf, 0, 1024*sizeof(float), stream);

  // ---- recurrent branch
  ax_kernel<<<(B_*T_)/16, 256, 0, stream>>>(x, kan_w1, kan_b1, axbuf);
  lstm_kernel<<<B_, 64, 0, stream>>>(axbuf, kan_w1, kan_w2, kan_b2, hidden);
  norm_kernel<<<(B_*T_)/8, 256, 0, stream>>>(hidden, norms);
  s_kernel<<<B_*16, 256, 0, stream>>>(hidden, norms, rowsum, psum);
  cluster_kernel<<<B_, 256, 0, stream>>>(rowsum, psum, hidden, corr, cuts);
  head1_kernel<<<B_, 128, 0, stream>>>(corr, hidden, eps_z, eps_cat,
      fc_mu_w, fc_mu_b, fc_std_w, fc_std_b, fc_muc_w, fc_muc_b, fc_stdc_w, fc_stdc_b,
      out_mu, out_std, out_muc, out_stdc, x1);

  // ---- conv branch
  transpose_kernel<<<B_*16, 256, 0, stream>>>(x, xT);
  {
    const int Kw=8, TWP=72, Cin=F_, Cout=C1_;
    const size_t shmem = (size_t)(16*TWP + 16*Kw*64)*sizeof(float);
    conv_kernel<<<dim3(16, Cout/64, B_), 256, shmem, stream>>>(xT, conv1_w, conv1_b, nullptr, y1, bn1, Cin, Cout, Kw, TWP);
  }
  bn_act_kernel<<<dim3(C1_, B_), 256, 0, stream>>>(y1, bn1, bn1_g, bn1_b, se1_in, C1_);
  se_kernel<<<B_, 256, 0, stream>>>(se1_in, se1_w1, se1_w2, se1_sc, C1_, C1_/16);
  {
    const int Kw=5, TWP=68, Cin=C1_, Cout=C2_;
    const size_t shmem = (size_t)(16*TWP + 16*Kw*64)*sizeof(float);
    conv_kernel<<<dim3(16, Cout/64, B_), 256, shmem, stream>>>(y1, conv2_w, conv2_b, se1_sc, y2, bn2, Cin, Cout, Kw, TWP);
  }
  bn_act_kernel<<<dim3(C2_, B_), 256, 0, stream>>>(y2, bn2, bn2_g, bn2_b, se2_in, C2_);
  se_kernel<<<B_, 256, 0, stream>>>(se2_in, se2_w1, se2_w2, se2_sc, C2_, C2_/16);
  {
    const int Kw=3, TWP=68, Cin=C2_, Cout=C3_;
    const size_t shmem = (size_t)(16*TWP + 16*Kw*64)*sizeof(float);
    conv_kernel<<<dim3(16, Cout/64, B_), 256, shmem, stream>>>(y2, conv3_w, conv3_b, se2_sc, y3, bn3, Cin, Cout, Kw, TWP);
  }
  bn_act_kernel<<<dim3(C3_, B_), 256, 0, stream>>>(y3, bn3, bn3_g, bn3_b, x2, C3_);

  // ---- final head
  head2_kernel<<<B_, 64, 0, stream>>>(x1, x2, fc_w, fc_b, out_ls);
}

// Round 4
// 1339.165 us; speedup vs baseline: 1.7692x; 1.2124x over previous
//
#include <hip/hip_runtime.h>
#include <math.h>

#define B_ 32
#define T_ 1024
#define F_ 64
#define H_ 128
#define D_ 192
#define KH_ 16
#define C1_ 128
#define C2_ 256
#define C3_ 128
#define NC_ 10

typedef float v2f __attribute__((ext_vector_type(2)));
typedef float f32x4 __attribute__((ext_vector_type(4)));
typedef __bf16 bfrag __attribute__((ext_vector_type(8)));

__device__ __forceinline__ float sig_(float x){ return 1.f/(1.f+__expf(-x)); }
__device__ __forceinline__ float tanh_(float x){ return 1.f - 2.f/(__expf(2.f*x)+1.f); }
__device__ __forceinline__ float gelu_(float x){ return 0.5f*x*(1.f+erff(x*0.70710678118654752f)); }
__device__ __forceinline__ float softplus_(float x){ return fmaxf(x,0.f) + log1pf(__expf(-fabsf(x))); }
__device__ __forceinline__ v2f sig2_(v2f x){ v2f r; r.x=sig_(x.x); r.y=sig_(x.y); return r; }
__device__ __forceinline__ v2f tanh2_(v2f x){ v2f r; r.x=tanh_(x.x); r.y=tanh_(x.y); return r; }

__device__ __forceinline__ unsigned bfpack(float a, float b){
  unsigned ua = __float_as_uint(a), ub = __float_as_uint(b);
  ua = ua + 0x7FFFu + ((ua>>16)&1u);
  ub = ub + 0x7FFFu + ((ub>>16)&1u);
  return (ua>>16) | (ub & 0xFFFF0000u);
}
__device__ __forceinline__ unsigned short bf1(float a){
  unsigned ua = __float_as_uint(a);
  ua = ua + 0x7FFFu + ((ua>>16)&1u);
  return (unsigned short)(ua>>16);
}

#define QPERM_XOR1(x) __int_as_float(__builtin_amdgcn_mov_dpp(__float_as_int(x), 0xB1, 0xF, 0xF, true))
#define QPERM_XOR2(x) __int_as_float(__builtin_amdgcn_mov_dpp(__float_as_int(x), 0x4E, 0xF, 0xF, true))

// ---------------------------------------------------------------- ax precompute (transposed out: axT[b][j][t])
__global__ __launch_bounds__(256) void ax_kernel(
    const float* __restrict__ x, const float* __restrict__ w1, const float* __restrict__ b1,
    float* __restrict__ axT)
{
  __shared__ float xs[16][68];
  __shared__ float w1s[64][16];
  const int bt0 = blockIdx.x*16;
  const int tid = threadIdx.x;
  for(int i=tid;i<64*16;i+=256){ w1s[i>>4][i&15] = w1[i]; }
  for(int i=tid;i<16*64;i+=256){ const int r=i>>6, d=i&63; xs[r][d] = x[(size_t)(bt0+r)*64 + d]; }
  __syncthreads();
  const int r = tid>>4, j = tid&15;
  float s = b1[j];
  #pragma unroll
  for(int d=0; d<64; d++) s += xs[r][d]*w1s[d][j];
  const int bt = bt0 + r;
  axT[((size_t)(bt>>10)*16 + j)*1024 + (bt&1023)] = s;
}

// ---------------------------------------------------------------- LSTM scan
// ONE WAVE per batch; lane l: j=l>>2 (KAN idx), g=l&3 (d-quarter).
// hs chunk stride padded 32->36 floats: phase-A b128 reads bank-conflict-free.
// ax read via transposed layout, float4 covers 4 steps, 2-deep prefetch pipeline.
__global__ __launch_bounds__(64, 1) void lstm_kernel(
    const float* __restrict__ axT, const float* __restrict__ w1,
    const float* __restrict__ w2, const float* __restrict__ b2,
    float* __restrict__ hidden)
{
  __shared__ float hs[144];   // 4 chunks x 36 (32 used + 4 pad)
  const int b = blockIdx.x, l = threadIdx.x;
  const int j = l >> 2, g = l & 3;

  v2f w1hv[16];
  #pragma unroll
  for(int q=0;q<16;q++){
    w1hv[q].x = w1[(64 + g*32 + 2*q)*KH_ + j];
    w1hv[q].y = w1[(64 + g*32 + 2*q + 1)*KH_ + j];
  }
  const v2f* w2v = (const v2f*)w2;
  const v2f* b2v = (const v2f*)b2;
  v2f w2r[64];
  #pragma unroll
  for(int k=0;k<16;k++){
    #pragma unroll
    for(int u=0;u<4;u++)
      w2r[k*4+u] = w2v[k*256 + u*64 + l];
  }
  v2f b2r[4];
  #pragma unroll
  for(int u=0;u<4;u++) b2r[u] = b2v[u*64 + l];

  for(int i=l;i<144;i+=64) hs[i]=0.f;
  v2f c = (v2f)(0.f);
  const float* axr = axT + ((size_t)b*16 + j)*1024;
  float* hb = hidden + (size_t)b*T_*H_;
  const int hwi = (l>>4)*36 + ((2*l)&31);     // h write index (padded layout)
  float4 axA = *(const float4*)&axr[0];
  float4 axB = *(const float4*)&axr[4];
  __builtin_amdgcn_wave_barrier();

#define LSTM_STEP(tt, axv) { \
    v2f ap0=(v2f)(0.f), ap1=(v2f)(0.f), ap2=(v2f)(0.f), ap3=(v2f)(0.f); \
    { const float4 hv = *(const float4*)&hs[g*36 + 0];  ap0 += ((v2f){hv.x,hv.y})*w1hv[0]  + ((v2f){hv.z,hv.w})*w1hv[1]; } \
    { const float4 hv = *(const float4*)&hs[g*36 + 4];  ap1 += ((v2f){hv.x,hv.y})*w1hv[2]  + ((v2f){hv.z,hv.w})*w1hv[3]; } \
    { const float4 hv = *(const float4*)&hs[g*36 + 8];  ap2 += ((v2f){hv.x,hv.y})*w1hv[4]  + ((v2f){hv.z,hv.w})*w1hv[5]; } \
    { const float4 hv = *(const float4*)&hs[g*36 + 12]; ap3 += ((v2f){hv.x,hv.y})*w1hv[6]  + ((v2f){hv.z,hv.w})*w1hv[7]; } \
    { const float4 hv = *(const float4*)&hs[g*36 + 16]; ap0 += ((v2f){hv.x,hv.y})*w1hv[8]  + ((v2f){hv.z,hv.w})*w1hv[9]; } \
    { const float4 hv = *(const float4*)&hs[g*36 + 20]; ap1 += ((v2f){hv.x,hv.y})*w1hv[10] + ((v2f){hv.z,hv.w})*w1hv[11]; } \
    { const float4 hv = *(const float4*)&hs[g*36 + 24]; ap2 += ((v2f){hv.x,hv.y})*w1hv[12] + ((v2f){hv.z,hv.w})*w1hv[13]; } \
    { const float4 hv = *(const float4*)&hs[g*36 + 28]; ap3 += ((v2f){hv.x,hv.y})*w1hv[14] + ((v2f){hv.z,hv.w})*w1hv[15]; } \
    const v2f apt = (ap0+ap1)+(ap2+ap3); \
    float a = apt.x + apt.y; \
    a += QPERM_XOR1(a); \
    a += QPERM_XOR2(a); \
    a += (axv); \
    const float g1 = a * sig_(a); \
    v2f accB[4]; \
    accB[0]=b2r[0]; accB[1]=b2r[1]; accB[2]=b2r[2]; accB[3]=b2r[3]; \
    _Pragma("unroll") \
    for(int k=0;k<16;k++){ \
      const float gk = __int_as_float(__builtin_amdgcn_readlane(__float_as_int(g1), 4*k)); \
      v2f gk2; gk2.x=gk; gk2.y=gk; \
      accB[0] += gk2 * w2r[k*4+0]; \
      accB[1] += gk2 * w2r[k*4+1]; \
      accB[2] += gk2 * w2r[k*4+2]; \
      accB[3] += gk2 * w2r[k*4+3]; \
    } \
    const v2f si = sig2_(accB[0]); \
    const v2f sf = sig2_(accB[1]); \
    const v2f tg = tanh2_(accB[2]); \
    const v2f so = sig2_(accB[3]); \
    c = sf*c + si*tg; \
    const v2f h = so * tanh2_(c); \
    *(v2f*)&hs[hwi] = h; \
    __builtin_amdgcn_wave_barrier(); \
    *(float2*)&hb[(size_t)(tt)*H_ + 2*l] = make_float2(h.x, h.y); \
  }

  for(int t0=0;t0<T_;t0+=4){
    const int tl = (t0+8 < 1020) ? (t0+8) : 1020;
    const float4 axC = *(const float4*)&axr[tl];
    LSTM_STEP(t0+0, axA.x)
    LSTM_STEP(t0+1, axA.y)
    LSTM_STEP(t0+2, axA.z)
    LSTM_STEP(t0+3, axA.w)
    axA = axB; axB = axC;
  }
#undef LSTM_STEP
}

// ---------------------------------------------------------------- row norms
__global__ __launch_bounds__(256) void norm_kernel(const float* __restrict__ hidden, float* __restrict__ norms)
{
  const int row = blockIdx.x*8 + (threadIdx.x>>5);
  const int l = threadIdx.x&31;
  const float* hr = hidden + (size_t)row*H_;
  float s = 0.f;
  for(int k=l;k<H_;k+=32){ float v=hr[k]; s+=v*v; }
  #pragma unroll
  for(int m=16;m>=1;m>>=1) s += __shfl_xor(s, m, 64);
  if(l==0) norms[row] = fmaxf(sqrtf(s), 1e-8f);
}

// ---------------------------------------------------------------- S rowsums (symmetric trick)
__global__ __launch_bounds__(256) void s_kernel(
    const float* __restrict__ hidden, const float* __restrict__ norms,
    double* __restrict__ rowsum, double* __restrict__ psum)
{
  __shared__ float As[128][68];
  __shared__ float Bs[64][68];
  __shared__ double red[64][17];
  const int b = blockIdx.x >> 4;
  const int i0 = (blockIdx.x & 15) * 64;
  const int tid = threadIdx.x;
  const float* hb = hidden + (size_t)b*T_*H_;
  const float* nb = norms + (size_t)b*T_;
  for(int idx=tid; idx<64*32; idx+=256){
    const int i = idx>>5, k4 = idx&31;
    float4 v = ((const float4*)(hb + (size_t)(i0+i)*H_))[k4];
    const float inv = 1.f/nb[i0+i];
    As[k4*4+0][i]=v.x*inv; As[k4*4+1][i]=v.y*inv; As[k4*4+2][i]=v.z*inv; As[k4*4+3][i]=v.w*inv;
  }
  double rs[4]={0,0,0,0}, ps[4]={0,0,0,0};
  const int tj = tid&15, ti = tid>>4;
  for(int jt=0;jt<16;jt++){
    const int j0 = jt*64;
    float acc[4][4];
    #pragma unroll
    for(int a=0;a<4;a++){
      #pragma unroll
      for(int cc=0;cc<4;cc++) acc[a][cc]=0.f;
    }
    for(int kh=0;kh<2;kh++){
      __syncthreads();
      for(int idx=tid; idx<64*16; idx+=256){
        const int jj = idx>>4, k4 = idx&15;
        float4 v = ((const float4*)(hb + (size_t)(j0+jj)*H_))[kh*16+k4];
        const float inv = 1.f/nb[j0+jj];
        Bs[k4*4+0][jj]=v.x*inv; Bs[k4*4+1][jj]=v.y*inv; Bs[k4*4+2][jj]=v.z*inv; Bs[k4*4+3][jj]=v.w*inv;
      }
      __syncthreads();
      for(int k=0;k<64;k++){
        const float4 a4 = *(const float4*)&As[kh*64+k][ti*4];
        const float4 b4 = *(const float4*)&Bs[k][tj*4];
        acc[0][0]+=a4.x*b4.x; acc[0][1]+=a4.x*b4.y; acc[0][2]+=a4.x*b4.z; acc[0][3]+=a4.x*b4.w;
        acc[1][0]+=a4.y*b4.x; acc[1][1]+=a4.y*b4.y; acc[1][2]+=a4.y*b4.z; acc[1][3]+=a4.y*b4.w;
        acc[2][0]+=a4.z*b4.x; acc[2][1]+=a4.z*b4.y; acc[2][2]+=a4.z*b4.z; acc[2][3]+=a4.z*b4.w;
        acc[3][0]+=a4.w*b4.x; acc[3][1]+=a4.w*b4.y; acc[3][2]+=a4.w*b4.z; acc[3][3]+=a4.w*b4.w;
      }
    }
    #pragma unroll
    for(int a=0;a<4;a++){
      const int gi = i0 + ti*4 + a;
      #pragma unroll
      for(int cc=0;cc<4;cc++){
        const int gj = j0 + tj*4 + cc;
        if(gi==gj) continue;
        const float sv = __expf(-5.5f*(1.f-acc[a][cc]));
        rs[a]+=(double)sv; if(gj<gi) ps[a]+=(double)sv;
      }
    }
  }
  __syncthreads();
  #pragma unroll
  for(int a=0;a<4;a++) red[ti*4+a][tj] = rs[a];
  __syncthreads();
  if(tid<64){ double v=0; for(int q=0;q<16;q++) v+=red[tid][q]; rowsum[(size_t)b*T_ + i0 + tid]=v; }
  __syncthreads();
  #pragma unroll
  for(int a=0;a<4;a++) red[ti*4+a][tj] = ps[a];
  __syncthreads();
  if(tid<64){ double v=0; for(int q=0;q<16;q++) v+=red[tid][q]; psum[(size_t)b*T_ + i0 + tid]=v; }
}

// ---------------------------------------------------------------- cluster: prefix+dist+argmax+corr
__global__ __launch_bounds__(256) void cluster_kernel(
    const double* __restrict__ rowsum, const double* __restrict__ psum,
    const float* __restrict__ hidden, float* __restrict__ corr, int* __restrict__ cuts)
{
  const int b = blockIdx.x, tid = threadIdx.x;
  const double* r = rowsum + (size_t)b*T_;
  const double* p = psum + (size_t)b*T_;
  __shared__ double sr[256], sp[256];
  __shared__ double totR_s;
  __shared__ double bd[256]; __shared__ int bidx[256];
  __shared__ int cut_s;
  double r4[4], p4[4];
  #pragma unroll
  for(int q=0;q<4;q++){ r4[q]=r[tid*4+q]; p4[q]=p[tid*4+q]; }
  sr[tid]=r4[0]+r4[1]+r4[2]+r4[3];
  sp[tid]=p4[0]+p4[1]+p4[2]+p4[3];
  __syncthreads();
  if(tid==0){
    double ar=0, ap=0;
    for(int i=0;i<256;i++){ double tr=sr[i], tp=sp[i]; sr[i]=ar; sp[i]=ap; ar+=tr; ap+=tp; }
    totR_s = ar;
  }
  __syncthreads();
  double cr = sr[tid], cp = sp[tid];
  const double full = totR_s;
  double best = -1e308; int bi = 1;
  #pragma unroll
  for(int q=0;q<4;q++){
    cr += r4[q]; cp += p4[q];
    const int i = 4*tid + q + 1;
    if(i < T_){
      const double TL = 2.0*cp;
      const double TRv = cr - TL;
      const double BR = full - TL - 2.0*TRv;
      const double di = (double)i, dn = (double)(T_-i);
      const double dist = TL/(di*di) + BR/(dn*dn) - (2.0*TRv)/(di*dn);
      if(dist > best){ best=dist; bi=i; }
    }
  }
  bd[tid]=best; bidx[tid]=bi;
  __syncthreads();
  if(tid==0){
    double bb=-1e308; int ii=1;
    for(int q=0;q<256;q++){ if(bd[q]>bb){ bb=bd[q]; ii=bidx[q]; } }
    cut_s=ii; cuts[b]=ii;
  }
  __syncthreads();
  const int cut = cut_s;
  const int h = tid&127, half = tid>>7;
  float s=0.f;
  const float* hb = hidden + (size_t)b*T_*H_;
  for(int t=half; t<cut; t+=2) s += hb[(size_t)t*H_ + h];
  __shared__ float c2[2][128];
  c2[half][h]=s;
  __syncthreads();
  if(tid<128) corr[b*H_+tid] = (c2[0][tid]+c2[1][tid])/(float)cut;
}

// ---------------------------------------------------------------- VAE heads
__global__ __launch_bounds__(128) void head1_kernel(
    const float* __restrict__ corr, const float* __restrict__ hidden,
    const float* __restrict__ eps_z, const float* __restrict__ eps_cat,
    const float* __restrict__ mu_w, const float* __restrict__ mu_b,
    const float* __restrict__ std_w, const float* __restrict__ std_b,
    const float* __restrict__ muc_w, const float* __restrict__ muc_b,
    const float* __restrict__ stdc_w, const float* __restrict__ stdc_b,
    float* __restrict__ out_mu, float* __restrict__ out_std,
    float* __restrict__ out_muc, float* __restrict__ out_stdc, float* __restrict__ x1)
{
  const int b=blockIdx.x, h=threadIdx.x;
  __shared__ float cs[128], xz[256];
  cs[h]=corr[b*H_+h];
  xz[h]=hidden[((size_t)b*T_ + (T_-1))*H_ + h];
  __syncthreads();
  float m=mu_b[h], sdv=std_b[h];
  for(int k=0;k<H_;k++){ const float cv=cs[k]; m+=cv*mu_w[k*H_+h]; sdv+=cv*std_w[k*H_+h]; }
  const float stdv = softplus_(sdv);
  out_mu[b*H_+h]=m; out_std[b*H_+h]=stdv;
  xz[128+h] = m + stdv*eps_z[b*H_+h];
  __syncthreads();
  float mc=muc_b[h], sc=stdc_b[h];
  for(int k=0;k<256;k++){ const float v=xz[k]; mc+=v*muc_w[k*H_+h]; sc+=v*stdc_w[k*H_+h]; }
  const float stdc = softplus_(sc);
  out_muc[b*H_+h]=mc; out_stdc[b*H_+h]=stdc;
  x1[b*H_+h]=mc + stdc*eps_cat[b*H_+h];
}

// ---------------------------------------------------------------- weight prepack to bf16 MFMA B-fragment blocks
// wp block (cc, kw, coTile16): 512 elems; elem ((co&15)*4 + ((ci>>3)&3))*8 + (ci&7)
__global__ __launch_bounds__(256) void prepack_kernel(
    const float* __restrict__ w, unsigned short* __restrict__ wp, int Cout, int Cin, int Kw)
{
  const int e = blockIdx.x*256 + threadIdx.x;
  if(e >= Cout*Cin*Kw) return;
  const int co = e/(Cin*Kw);
  const int rem = e - co*(Cin*Kw);
  const int ci = rem/Kw, kw = rem - ci*Kw;
  const int off = (((ci>>5)*Kw + kw)*(Cout>>4) + (co>>4))*512 + ((co&15)*4 + ((ci>>3)&3))*8 + (ci&7);
  wp[off] = bf1(w[e]);
}

// ---------------------------------------------------------------- causal conv via bf16 MFMA implicit GEMM
// in: [b][t][Cin] fp32; y: [b][t][Cout] fp32. Block: 64t x 64co, 4 waves (16t each).
__global__ __launch_bounds__(256) void convmf_kernel(
    const float* __restrict__ in, const unsigned short* __restrict__ wp,
    const float* __restrict__ bias, const float* __restrict__ scale,
    float* __restrict__ y, int Cin, int Cout, int Kw)
{
  __shared__ unsigned short xs[72*40];   // [row t][32 ci + 8 pad] bf16, row stride 80B
  const int b = blockIdx.z, t0 = blockIdx.x*64;
  const int tid = threadIdx.x, l = tid&63, wv = tid>>6;
  const int q = l>>4, m = l&15;
  const int TW = 64 + Kw - 1;
  const int abase = (wv*16 + m)*40 + q*8;
  const int boff = (m*4 + q)*8;
  f32x4 acc[4];
  #pragma unroll
  for(int nt=0;nt<4;nt++) acc[nt] = (f32x4)(0.f);

  const int nchunks = Cin >> 5;
  for(int cc=0; cc<nchunks; cc++){
    __syncthreads();
    for(int idx=tid; idx<TW*8; idx+=256){
      const int r = idx>>3, c4 = (idx&7)*4;
      const int tg = t0 - (Kw-1) + r;
      uint2 pk = make_uint2(0u, 0u);
      if(tg >= 0){
        float4 v = *(const float4*)&in[((size_t)b*T_ + tg)*Cin + cc*32 + c4];
        if(scale){
          const float4 s4 = *(const float4*)&scale[b*Cin + cc*32 + c4];
          v.x*=s4.x; v.y*=s4.y; v.z*=s4.z; v.w*=s4.w;
        }
        pk.x = bfpack(v.x, v.y); pk.y = bfpack(v.z, v.w);
      }
      *(uint2*)&xs[r*40 + c4] = pk;
    }
    __syncthreads();
    for(int kw=0; kw<Kw; kw++){
      const bfrag Af = *(const bfrag*)&xs[abase + kw*40];
      #pragma unroll
      for(int nt=0; nt<4; nt++){
        const unsigned short* wpp = wp + ((size_t)((cc*Kw + kw)*(Cout>>4) + (blockIdx.y*4 + nt)))*512 + boff;
        const bfrag Bf = *(const bfrag*)wpp;
        acc[nt] = __builtin_amdgcn_mfma_f32_16x16x32_bf16(Af, Bf, acc[nt], 0, 0, 0);
      }
    }
  }
  const int t_base = t0 + wv*16 + q*4;
  #pragma unroll
  for(int nt=0; nt<4; nt++){
    const int co = blockIdx.y*64 + nt*16 + m;
    const float bv = bias[co];
    #pragma unroll
    for(int r=0;r<4;r++){
      y[((size_t)b*T_ + t_base + r)*Cout + co] = acc[nt][r] + bv;
    }
  }
}

// ---------------------------------------------------------------- BN batch stats (sum, sumsq per channel)
__global__ __launch_bounds__(256) void bn_stats_kernel(
    const float* __restrict__ y, float* __restrict__ bnacc, int C)
{
  const int b = blockIdx.x, t0 = blockIdx.y*128, tid = threadIdx.x;
  const int c = tid & (C-1), part = tid / C, np = 256 / C;
  float s=0.f, sq=0.f;
  for(int t=t0+part; t<t0+128; t+=np){
    const float v = y[((size_t)b*T_ + t)*C + c];
    s += v; sq += v*v;
  }
  __shared__ float rs[256], rq[256];
  if(np > 1){
    rs[tid]=s; rq[tid]=sq;
    __syncthreads();
    if(part==0){ s += rs[tid+C]; sq += rq[tid+C]; }
  }
  if(part==0){
    atomicAdd(&bnacc[c], s);
    atomicAdd(&bnacc[C+c], sq);
  }
}

// ---------------------------------------------------------------- BN + gelu (in place) + per-(b,c) t-sum accum
__global__ __launch_bounds__(256) void bn_act_kernel(
    float* __restrict__ y, const float* __restrict__ bnacc,
    const float* __restrict__ gw, const float* __restrict__ bw,
    float* __restrict__ mean_acc, int C)
{
  const int b = blockIdx.x, t0 = blockIdx.y*128, tid = threadIdx.x;
  const int c = tid & (C-1), part = tid / C, np = 256 / C;
  const float cnt = (float)(B_*T_);
  const float mm = bnacc[c]/cnt;
  const float var = bnacc[C+c]/cnt - mm*mm;
  const float sc = gw[c]/sqrtf(var+1e-3f);
  const float sh = bw[c] - mm*sc;
  float s = 0.f;
  for(int t=t0+part; t<t0+128; t+=np){
    const size_t off = ((size_t)b*T_ + t)*C + c;
    float v = y[off];
    v = gelu_(v*sc + sh);
    y[off] = v;
    s += v;
  }
  __shared__ float rs[256];
  if(np > 1){
    rs[tid]=s;
    __syncthreads();
    if(part==0) s += rs[tid+C];
  }
  if(part==0) atomicAdd(&mean_acc[b*C+c], s);
}

// ---------------------------------------------------------------- SE (mean_in holds t-SUMS; scale by 1/T here)
__global__ __launch_bounds__(256) void se_kernel(
    const float* __restrict__ mean_in, const float* __restrict__ w1, const float* __restrict__ w2,
    float* __restrict__ scale, int C, int R)
{
  __shared__ float ms[256], hs[16];
  const int b=blockIdx.x, tid=threadIdx.x;
  if(tid<C) ms[tid]=mean_in[b*C+tid]*(1.f/(float)T_);
  __syncthreads();
  if(tid<R){ float s=0; for(int k=0;k<C;k++) s+=ms[k]*w1[k*R+tid]; hs[tid]=fmaxf(s,0.f); }
  __syncthreads();
  if(tid<C){ float s=0; for(int k=0;k<R;k++) s+=hs[k]*w2[k*C+tid]; scale[b*C+tid]=sig_(s); }
}

// ---------------------------------------------------------------- final fc + log_softmax (x2 holds t-sums)
__global__ __launch_bounds__(64) void head2_kernel(
    const float* __restrict__ x1, const float* __restrict__ x2,
    const float* __restrict__ fcw, const float* __restrict__ fcb, float* __restrict__ outls)
{
  const int b=blockIdx.x, tid=threadIdx.x;
  __shared__ float xa[256]; __shared__ float lg[NC_];
  for(int k=tid;k<256;k+=64) xa[k] = (k<128)? x1[b*128+k] : x2[b*128+(k-128)]*(1.f/(float)T_);
  __syncthreads();
  if(tid<NC_){
    float s = fcb[tid];
    for(int k=0;k<256;k++) s += xa[k]*fcw[k*NC_+tid];
    lg[tid]=s;
  }
  __syncthreads();
  if(tid==0){
    float mx=lg[0];
    for(int q=1;q<NC_;q++) mx=fmaxf(mx,lg[q]);
    float se=0;
    for(int q=0;q<NC_;q++) se += __expf(lg[q]-mx);
    const float lse = logf(se)+mx;
    for(int q=0;q<NC_;q++) outls[b*NC_+q] = lg[q]-lse;
  }
}

// ---------------------------------------------------------------- launch
extern "C" void kernel_launch(void* const* d_in, const int* in_sizes, int n_in,
                              void* d_out, int out_size, void* d_ws, size_t ws_size,
                              hipStream_t stream) {
  (void)in_sizes; (void)n_in; (void)out_size; (void)ws_size;
  const float* x        = (const float*)d_in[0];
  const float* eps_z    = (const float*)d_in[1];
  const float* eps_cat  = (const float*)d_in[2];
  const float* kan_w1   = (const float*)d_in[3];
  const float* kan_b1   = (const float*)d_in[4];
  const float* kan_w2   = (const float*)d_in[5];
  const float* kan_b2   = (const float*)d_in[6];
  const float* conv1_w  = (const float*)d_in[7];
  const float* conv1_b  = (const float*)d_in[8];
  const float* conv2_w  = (const float*)d_in[9];
  const float* conv2_b  = (const float*)d_in[10];
  const float* conv3_w  = (const float*)d_in[11];
  const float* conv3_b  = (const float*)d_in[12];
  const float* bn1_g    = (const float*)d_in[13];
  const float* bn1_b    = (const float*)d_in[14];
  const float* bn2_g    = (const float*)d_in[15];
  const float* bn2_b    = (const float*)d_in[16];
  const float* bn3_g    = (const float*)d_in[17];
  const float* bn3_b    = (const float*)d_in[18];
  const float* se1_w1   = (const float*)d_in[19];
  const float* se1_w2   = (const float*)d_in[20];
  const float* se2_w1   = (const float*)d_in[21];
  const float* se2_w2   = (const float*)d_in[22];
  const float* fc_mu_w  = (const float*)d_in[23];
  const float* fc_mu_b  = (const float*)d_in[24];
  const float* fc_std_w = (const float*)d_in[25];
  const float* fc_std_b = (const float*)d_in[26];
  const float* fc_muc_w = (const float*)d_in[27];
  const float* fc_muc_b = (const float*)d_in[28];
  const float* fc_stdc_w= (const float*)d_in[29];
  const float* fc_stdc_b= (const float*)d_in[30];
  const float* fc_w     = (const float*)d_in[31];
  const float* fc_b     = (const float*)d_in[32];

  float* out = (float*)d_out;
  float* out_ls   = out;
  float* out_mu   = out + 320;
  float* out_std  = out + 320 + 4096;
  float* out_muc  = out + 320 + 2*4096;
  float* out_stdc = out + 320 + 3*4096;

  float* ws = (float*)d_ws;
  const size_t SZ_HID = (size_t)B_*T_*H_;
  const size_t SZ_Y1  = (size_t)B_*T_*C1_;
  const size_t SZ_Y2  = (size_t)B_*T_*C2_;
  float*  hidden = ws;                      // [b][t][H]; reused as y3 [b][t][C3]
  float*  y1     = hidden + SZ_HID;         // [b][t][C1]
  float*  y2     = y1 + SZ_Y1;              // [b][t][C2]
  float*  norms  = y2 + SZ_Y2;
  double* rowsum = (double*)(norms + (size_t)B_*T_);
  double* psum   = rowsum + (size_t)B_*T_;
  float*  corr   = (float*)(psum + (size_t)B_*T_);
  float*  x1     = corr + (size_t)B_*H_;
  float*  bnbuf  = x1 + (size_t)B_*H_;      // 1024 floats (bn acc for all three)
  float*  bn1    = bnbuf;
  float*  bn2    = bnbuf + 2*C1_;
  float*  bn3    = bnbuf + 2*C1_ + 2*C2_;
  float*  se1_in = bnbuf + 1024;            // B*C1 (t-sums)
  float*  se1_sc = se1_in + (size_t)B_*C1_;
  float*  se2_in = se1_sc + (size_t)B_*C1_; // B*C2
  float*  se2_sc = se2_in + (size_t)B_*C2_;
  float*  x2     = se2_sc + (size_t)B_*C2_; // B*C3 (t-sums)
  int*    cuts   = (int*)(x2 + (size_t)B_*C3_);
  float*  axbuf  = (float*)(cuts + B_);     // axT: B*16*T
  unsigned short* wp1 = (unsigned short*)(axbuf + (size_t)B_*16*T_);
  unsigned short* wp2 = wp1 + (size_t)C1_*F_*8;
  unsigned short* wp3 = wp2 + (size_t)C2_*C1_*5;
  float*  y3     = hidden;

  // zero bnacc + se/x2 accumulators (29696 floats contiguous)
  hipMemsetAsync(bnbuf, 0, (size_t)(1024 + 2*B_*C1_ + 2*B_*C2_ + B_*C3_)*sizeof(float), stream);

  // ---- weight prepack (bf16 fragments)
  prepack_kernel<<<(C1_*F_*8 + 255)/256, 256, 0, stream>>>(conv1_w, wp1, C1_, F_, 8);
  prepack_kernel<<<(C2_*C1_*5 + 255)/256, 256, 0, stream>>>(conv2_w, wp2, C2_, C1_, 5);
  prepack_kernel<<<(C3_*C2_*3 + 255)/256, 256, 0, stream>>>(conv3_w, wp3, C3_, C2_, 3);

  // ---- recurrent branch
  ax_kernel<<<(B_*T_)/16, 256, 0, stream>>>(x, kan_w1, kan_b1, axbuf);
  lstm_kernel<<<B_, 64, 0, stream>>>(axbuf, kan_w1, kan_w2, kan_b2, hidden);
  norm_kernel<<<(B_*T_)/8, 256, 0, stream>>>(hidden, norms);
  s_kernel<<<B_*16, 256, 0, stream>>>(hidden, norms, rowsum, psum);
  cluster_kernel<<<B_, 256, 0, stream>>>(rowsum, psum, hidden, corr, cuts);
  head1_kernel<<<B_, 128, 0, stream>>>(corr, hidden, eps_z, eps_cat,
      fc_mu_w, fc_mu_b, fc_std_w, fc_std_b, fc_muc_w, fc_muc_b, fc_stdc_w, fc_stdc_b,
      out_mu, out_std, out_muc, out_stdc, x1);

  // ---- conv branch (bf16 MFMA implicit GEMM; all tensors [b][t][c])
  convmf_kernel<<<dim3(16, C1_/64, B_), 256, 0, stream>>>(x,  wp1, conv1_b, nullptr, y1, F_,  C1_, 8);
  bn_stats_kernel<<<dim3(B_, 8), 256, 0, stream>>>(y1, bn1, C1_);
  bn_act_kernel<<<dim3(B_, 8), 256, 0, stream>>>(y1, bn1, bn1_g, bn1_b, se1_in, C1_);
  se_kernel<<<B_, 256, 0, stream>>>(se1_in, se1_w1, se1_w2, se1_sc, C1_, C1_/16);
  convmf_kernel<<<dim3(16, C2_/64, B_), 256, 0, stream>>>(y1, wp2, conv2_b, se1_sc, y2, C1_, C2_, 5);
  bn_stats_kernel<<<dim3(B_, 8), 256, 0, stream>>>(y2, bn2, C2_);
  bn_act_kernel<<<dim3(B_, 8), 256, 0, stream>>>(y2, bn2, bn2_g, bn2_b, se2_in, C2_);
  se_kernel<<<B_, 256, 0, stream>>>(se2_in, se2_w1, se2_w2, se2_sc, C2_, C2_/16);
  convmf_kernel<<<dim3(16, C3_/64, B_), 256, 0, stream>>>(y2, wp3, conv3_b, se2_sc, y3, C2_, C3_, 3);
  bn_stats_kernel<<<dim3(B_, 8), 256, 0, stream>>>(y3, bn3, C3_);
  bn_act_kernel<<<dim3(B_, 8), 256, 0, stream>>>(y3, bn3, bn3_g, bn3_b, x2, C3_);

  // ---- final head
  head2_kernel<<<B_, 64, 0, stream>>>(x1, x2, fc_w, fc_b, out_ls);
}

// Round 5
// 1187.819 us; speedup vs baseline: 1.9947x; 1.1274x over previous
//
#include <hip/hip_runtime.h>
#include <math.h>

#define B_ 32
#define T_ 1024
#define F_ 64
#define H_ 128
#define D_ 192
#define KH_ 16
#define C1_ 128
#define C2_ 256
#define C3_ 128
#define NC_ 10

typedef float v2f __attribute__((ext_vector_type(2)));
typedef float f32x4 __attribute__((ext_vector_type(4)));
typedef __bf16 bfrag __attribute__((ext_vector_type(8)));

__device__ __forceinline__ float sig_(float x){ return 1.f/(1.f+__expf(-x)); }
__device__ __forceinline__ float tanh_(float x){ return 1.f - 2.f/(__expf(2.f*x)+1.f); }
__device__ __forceinline__ float gelu_(float x){ return 0.5f*x*(1.f+erff(x*0.70710678118654752f)); }
__device__ __forceinline__ float softplus_(float x){ return fmaxf(x,0.f) + log1pf(__expf(-fabsf(x))); }

__device__ __forceinline__ unsigned bfpack(float a, float b){
  unsigned ua = __float_as_uint(a), ub = __float_as_uint(b);
  ua = ua + 0x7FFFu + ((ua>>16)&1u);
  ub = ub + 0x7FFFu + ((ub>>16)&1u);
  return (ua>>16) | (ub & 0xFFFF0000u);
}
__device__ __forceinline__ unsigned short bf1(float a){
  unsigned ua = __float_as_uint(a);
  ua = ua + 0x7FFFu + ((ua>>16)&1u);
  return (unsigned short)(ua>>16);
}

#define QPERM_XOR1(x) __int_as_float(__builtin_amdgcn_mov_dpp(__float_as_int(x), 0xB1, 0xF, 0xF, true))
#define QPERM_XOR2(x) __int_as_float(__builtin_amdgcn_mov_dpp(__float_as_int(x), 0x4E, 0xF, 0xF, true))

// LDS-only barrier: waits ds ops (lgkm) but lets global stores stay in flight
// (__syncthreads would drain vmcnt(0) each step — per-step HBM store stall).
#define LDS_BARRIER() asm volatile("s_waitcnt lgkmcnt(0)\n\ts_barrier" ::: "memory")

// ---------------------------------------------------------------- ax precompute (transposed out: axT[b][j][t])
__global__ __launch_bounds__(256) void ax_kernel(
    const float* __restrict__ x, const float* __restrict__ w1, const float* __restrict__ b1,
    float* __restrict__ axT)
{
  __shared__ float xs[16][68];
  __shared__ float w1s[64][16];
  const int bt0 = blockIdx.x*16;
  const int tid = threadIdx.x;
  for(int i=tid;i<64*16;i+=256){ w1s[i>>4][i&15] = w1[i]; }
  for(int i=tid;i<16*64;i+=256){ const int r=i>>6, d=i&63; xs[r][d] = x[(size_t)(bt0+r)*64 + d]; }
  __syncthreads();
  const int r = tid>>4, j = tid&15;
  float s = b1[j];
  #pragma unroll
  for(int d=0; d<64; d++) s += xs[r][d]*w1s[d][j];
  const int bt = bt0 + r;
  axT[((size_t)(bt>>10)*16 + j)*1024 + (bt&1023)] = s;
}

// ---------------------------------------------------------------- LSTM scan
// TWO WAVES per batch (128 thr). Lane layout: l=tid&63, wv=tid>>6.
// Phase A (h->16 KAN) computed redundantly by both waves (j=l>>2, g=l&3,
// quad-DPP reduce). Phase B split by h: each lane owns h[wv*64+l]:
// 2 packed gate chains (i,f)/(g,o) = 32 pk_fma, 5 transc/lane.
// h exchange: double-buffered LDS (chunk stride 36 -> conflict-free b128),
// ONE LDS-only barrier per step.
__global__ __launch_bounds__(128, 1) void lstm_kernel(
    const float* __restrict__ axT, const float* __restrict__ w1,
    const float* __restrict__ w2, const float* __restrict__ b2,
    float* __restrict__ hidden)
{
  __shared__ float hs[2][148];   // [parity][4 chunks x 36]
  const int b = blockIdx.x, tid = threadIdx.x;
  const int l = tid & 63, wv = tid >> 6;
  const int j = l >> 2, g = l & 3;
  const int hi = wv*64 + l;

  v2f w1hv[16];
  #pragma unroll
  for(int q=0;q<16;q++){
    w1hv[q].x = w1[(64 + g*32 + 2*q)*KH_ + j];
    w1hv[q].y = w1[(64 + g*32 + 2*q + 1)*KH_ + j];
  }
  v2f w2if[16], w2go[16];
  #pragma unroll
  for(int k=0;k<16;k++){
    w2if[k].x = w2[k*512 + hi];       w2if[k].y = w2[k*512 + 128 + hi];
    w2go[k].x = w2[k*512 + 256 + hi]; w2go[k].y = w2[k*512 + 384 + hi];
  }
  v2f bif, bgo;
  bif.x = b2[hi]; bif.y = b2[128+hi]; bgo.x = b2[256+hi]; bgo.y = b2[384+hi];

  for(int i=tid;i<2*148;i+=128) ((float*)hs)[i]=0.f;
  float c = 0.f;
  const float* axr = axT + ((size_t)b*16 + j)*1024;
  float* hb = hidden + (size_t)b*T_*H_;
  const int hwi = (hi>>5)*36 + (hi&31);
  float4 axA = *(const float4*)&axr[0];
  float4 axB = *(const float4*)&axr[4];
  __syncthreads();

#define LSTM_STEP(tt, axv, RB) { \
    const float* hsr = hs[RB]; \
    v2f ap0=(v2f)(0.f), ap1=(v2f)(0.f), ap2=(v2f)(0.f), ap3=(v2f)(0.f); \
    { const float4 hv = *(const float4*)&hsr[g*36 + 0];  ap0 += ((v2f){hv.x,hv.y})*w1hv[0]  + ((v2f){hv.z,hv.w})*w1hv[1]; } \
    { const float4 hv = *(const float4*)&hsr[g*36 + 4];  ap1 += ((v2f){hv.x,hv.y})*w1hv[2]  + ((v2f){hv.z,hv.w})*w1hv[3]; } \
    { const float4 hv = *(const float4*)&hsr[g*36 + 8];  ap2 += ((v2f){hv.x,hv.y})*w1hv[4]  + ((v2f){hv.z,hv.w})*w1hv[5]; } \
    { const float4 hv = *(const float4*)&hsr[g*36 + 12]; ap3 += ((v2f){hv.x,hv.y})*w1hv[6]  + ((v2f){hv.z,hv.w})*w1hv[7]; } \
    { const float4 hv = *(const float4*)&hsr[g*36 + 16]; ap0 += ((v2f){hv.x,hv.y})*w1hv[8]  + ((v2f){hv.z,hv.w})*w1hv[9]; } \
    { const float4 hv = *(const float4*)&hsr[g*36 + 20]; ap1 += ((v2f){hv.x,hv.y})*w1hv[10] + ((v2f){hv.z,hv.w})*w1hv[11]; } \
    { const float4 hv = *(const float4*)&hsr[g*36 + 24]; ap2 += ((v2f){hv.x,hv.y})*w1hv[12] + ((v2f){hv.z,hv.w})*w1hv[13]; } \
    { const float4 hv = *(const float4*)&hsr[g*36 + 28]; ap3 += ((v2f){hv.x,hv.y})*w1hv[14] + ((v2f){hv.z,hv.w})*w1hv[15]; } \
    const v2f apt = (ap0+ap1)+(ap2+ap3); \
    float a = apt.x + apt.y; \
    a += QPERM_XOR1(a); \
    a += QPERM_XOR2(a); \
    a += (axv); \
    const float g1 = a * sig_(a); \
    v2f aIF = bif, aGO = bgo; \
    _Pragma("unroll") \
    for(int k=0;k<16;k++){ \
      const float gk = __int_as_float(__builtin_amdgcn_readlane(__float_as_int(g1), 4*k)); \
      v2f gk2; gk2.x=gk; gk2.y=gk; \
      aIF += gk2 * w2if[k]; \
      aGO += gk2 * w2go[k]; \
    } \
    const float si = sig_(aIF.x); \
    const float sf = sig_(aIF.y); \
    const float tg = tanh_(aGO.x); \
    const float so = sig_(aGO.y); \
    c = sf*c + si*tg; \
    const float h = so * tanh_(c); \
    hs[1-(RB)][hwi] = h; \
    hb[(size_t)(tt)*H_ + hi] = h; \
    LDS_BARRIER(); \
  }

  for(int t0=0;t0<T_;t0+=4){
    const int tl = (t0+8 < 1020) ? (t0+8) : 1020;
    const float4 axC = *(const float4*)&axr[tl];
    LSTM_STEP(t0+0, axA.x, 0)
    LSTM_STEP(t0+1, axA.y, 1)
    LSTM_STEP(t0+2, axA.z, 0)
    LSTM_STEP(t0+3, axA.w, 1)
    axA = axB; axB = axC;
  }
#undef LSTM_STEP
}

// ---------------------------------------------------------------- row norms
__global__ __launch_bounds__(256) void norm_kernel(const float* __restrict__ hidden, float* __restrict__ norms)
{
  const int row = blockIdx.x*8 + (threadIdx.x>>5);
  const int l = threadIdx.x&31;
  const float* hr = hidden + (size_t)row*H_;
  float s = 0.f;
  for(int k=l;k<H_;k+=32){ float v=hr[k]; s+=v*v; }
  #pragma unroll
  for(int m=16;m>=1;m>>=1) s += __shfl_xor(s, m, 64);
  if(l==0) norms[row] = fmaxf(sqrtf(s), 1e-8f);
}

// ---------------------------------------------------------------- S rowsums (symmetric trick)
__global__ __launch_bounds__(256) void s_kernel(
    const float* __restrict__ hidden, const float* __restrict__ norms,
    double* __restrict__ rowsum, double* __restrict__ psum)
{
  __shared__ float As[128][68];
  __shared__ float Bs[64][68];
  __shared__ double red[64][17];
  const int b = blockIdx.x >> 4;
  const int i0 = (blockIdx.x & 15) * 64;
  const int tid = threadIdx.x;
  const float* hb = hidden + (size_t)b*T_*H_;
  const float* nb = norms + (size_t)b*T_;
  for(int idx=tid; idx<64*32; idx+=256){
    const int i = idx>>5, k4 = idx&31;
    float4 v = ((const float4*)(hb + (size_t)(i0+i)*H_))[k4];
    const float inv = 1.f/nb[i0+i];
    As[k4*4+0][i]=v.x*inv; As[k4*4+1][i]=v.y*inv; As[k4*4+2][i]=v.z*inv; As[k4*4+3][i]=v.w*inv;
  }
  double rs[4]={0,0,0,0}, ps[4]={0,0,0,0};
  const int tj = tid&15, ti = tid>>4;
  for(int jt=0;jt<16;jt++){
    const int j0 = jt*64;
    float acc[4][4];
    #pragma unroll
    for(int a=0;a<4;a++){
      #pragma unroll
      for(int cc=0;cc<4;cc++) acc[a][cc]=0.f;
    }
    for(int kh=0;kh<2;kh++){
      __syncthreads();
      for(int idx=tid; idx<64*16; idx+=256){
        const int jj = idx>>4, k4 = idx&15;
        float4 v = ((const float4*)(hb + (size_t)(j0+jj)*H_))[kh*16+k4];
        const float inv = 1.f/nb[j0+jj];
        Bs[k4*4+0][jj]=v.x*inv; Bs[k4*4+1][jj]=v.y*inv; Bs[k4*4+2][jj]=v.z*inv; Bs[k4*4+3][jj]=v.w*inv;
      }
      __syncthreads();
      for(int k=0;k<64;k++){
        const float4 a4 = *(const float4*)&As[kh*64+k][ti*4];
        const float4 b4 = *(const float4*)&Bs[k][tj*4];
        acc[0][0]+=a4.x*b4.x; acc[0][1]+=a4.x*b4.y; acc[0][2]+=a4.x*b4.z; acc[0][3]+=a4.x*b4.w;
        acc[1][0]+=a4.y*b4.x; acc[1][1]+=a4.y*b4.y; acc[1][2]+=a4.y*b4.z; acc[1][3]+=a4.y*b4.w;
        acc[2][0]+=a4.z*b4.x; acc[2][1]+=a4.z*b4.y; acc[2][2]+=a4.z*b4.z; acc[2][3]+=a4.z*b4.w;
        acc[3][0]+=a4.w*b4.x; acc[3][1]+=a4.w*b4.y; acc[3][2]+=a4.w*b4.z; acc[3][3]+=a4.w*b4.w;
      }
    }
    #pragma unroll
    for(int a=0;a<4;a++){
      const int gi = i0 + ti*4 + a;
      #pragma unroll
      for(int cc=0;cc<4;cc++){
        const int gj = j0 + tj*4 + cc;
        if(gi==gj) continue;
        const float sv = __expf(-5.5f*(1.f-acc[a][cc]));
        rs[a]+=(double)sv; if(gj<gi) ps[a]+=(double)sv;
      }
    }
  }
  __syncthreads();
  #pragma unroll
  for(int a=0;a<4;a++) red[ti*4+a][tj] = rs[a];
  __syncthreads();
  if(tid<64){ double v=0; for(int q=0;q<16;q++) v+=red[tid][q]; rowsum[(size_t)b*T_ + i0 + tid]=v; }
  __syncthreads();
  #pragma unroll
  for(int a=0;a<4;a++) red[ti*4+a][tj] = ps[a];
  __syncthreads();
  if(tid<64){ double v=0; for(int q=0;q<16;q++) v+=red[tid][q]; psum[(size_t)b*T_ + i0 + tid]=v; }
}

// ---------------------------------------------------------------- cluster: prefix+dist+argmax+corr
__global__ __launch_bounds__(256) void cluster_kernel(
    const double* __restrict__ rowsum, const double* __restrict__ psum,
    const float* __restrict__ hidden, float* __restrict__ corr, int* __restrict__ cuts)
{
  const int b = blockIdx.x, tid = threadIdx.x;
  const double* r = rowsum + (size_t)b*T_;
  const double* p = psum + (size_t)b*T_;
  __shared__ double sr[256], sp[256];
  __shared__ double totR_s;
  __shared__ double bd[256]; __shared__ int bidx[256];
  __shared__ int cut_s;
  double r4[4], p4[4];
  #pragma unroll
  for(int q=0;q<4;q++){ r4[q]=r[tid*4+q]; p4[q]=p[tid*4+q]; }
  sr[tid]=r4[0]+r4[1]+r4[2]+r4[3];
  sp[tid]=p4[0]+p4[1]+p4[2]+p4[3];
  __syncthreads();
  if(tid==0){
    double ar=0, ap=0;
    for(int i=0;i<256;i++){ double tr=sr[i], tp=sp[i]; sr[i]=ar; sp[i]=ap; ar+=tr; ap+=tp; }
    totR_s = ar;
  }
  __syncthreads();
  double cr = sr[tid], cp = sp[tid];
  const double full = totR_s;
  double best = -1e308; int bi = 1;
  #pragma unroll
  for(int q=0;q<4;q++){
    cr += r4[q]; cp += p4[q];
    const int i = 4*tid + q + 1;
    if(i < T_){
      const double TL = 2.0*cp;
      const double TRv = cr - TL;
      const double BR = full - TL - 2.0*TRv;
      const double di = (double)i, dn = (double)(T_-i);
      const double dist = TL/(di*di) + BR/(dn*dn) - (2.0*TRv)/(di*dn);
      if(dist > best){ best=dist; bi=i; }
    }
  }
  bd[tid]=best; bidx[tid]=bi;
  __syncthreads();
  if(tid==0){
    double bb=-1e308; int ii=1;
    for(int q=0;q<256;q++){ if(bd[q]>bb){ bb=bd[q]; ii=bidx[q]; } }
    cut_s=ii; cuts[b]=ii;
  }
  __syncthreads();
  const int cut = cut_s;
  const int h = tid&127, half = tid>>7;
  float s=0.f;
  const float* hb = hidden + (size_t)b*T_*H_;
  for(int t=half; t<cut; t+=2) s += hb[(size_t)t*H_ + h];
  __shared__ float c2[2][128];
  c2[half][h]=s;
  __syncthreads();
  if(tid<128) corr[b*H_+tid] = (c2[0][tid]+c2[1][tid])/(float)cut;
}

// ---------------------------------------------------------------- VAE heads
__global__ __launch_bounds__(128) void head1_kernel(
    const float* __restrict__ corr, const float* __restrict__ hidden,
    const float* __restrict__ eps_z, const float* __restrict__ eps_cat,
    const float* __restrict__ mu_w, const float* __restrict__ mu_b,
    const float* __restrict__ std_w, const float* __restrict__ std_b,
    const float* __restrict__ muc_w, const float* __restrict__ muc_b,
    const float* __restrict__ stdc_w, const float* __restrict__ stdc_b,
    float* __restrict__ out_mu, float* __restrict__ out_std,
    float* __restrict__ out_muc, float* __restrict__ out_stdc, float* __restrict__ x1)
{
  const int b=blockIdx.x, h=threadIdx.x;
  __shared__ float cs[128], xz[256];
  cs[h]=corr[b*H_+h];
  xz[h]=hidden[((size_t)b*T_ + (T_-1))*H_ + h];
  __syncthreads();
  float m=mu_b[h], sdv=std_b[h];
  for(int k=0;k<H_;k++){ const float cv=cs[k]; m+=cv*mu_w[k*H_+h]; sdv+=cv*std_w[k*H_+h]; }
  const float stdv = softplus_(sdv);
  out_mu[b*H_+h]=m; out_std[b*H_+h]=stdv;
  xz[128+h] = m + stdv*eps_z[b*H_+h];
  __syncthreads();
  float mc=muc_b[h], sc=stdc_b[h];
  for(int k=0;k<256;k++){ const float v=xz[k]; mc+=v*muc_w[k*H_+h]; sc+=v*stdc_w[k*H_+h]; }
  const float stdc = softplus_(sc);
  out_muc[b*H_+h]=mc; out_stdc[b*H_+h]=stdc;
  x1[b*H_+h]=mc + stdc*eps_cat[b*H_+h];
}

// ---------------------------------------------------------------- weight prepack to bf16 MFMA B-fragment blocks
__global__ __launch_bounds__(256) void prepack_kernel(
    const float* __restrict__ w, unsigned short* __restrict__ wp, int Cout, int Cin, int Kw)
{
  const int e = blockIdx.x*256 + threadIdx.x;
  if(e >= Cout*Cin*Kw) return;
  const int co = e/(Cin*Kw);
  const int rem = e - co*(Cin*Kw);
  const int ci = rem/Kw, kw = rem - ci*Kw;
  const int off = (((ci>>5)*Kw + kw)*(Cout>>4) + (co>>4))*512 + ((co&15)*4 + ((ci>>3)&3))*8 + (ci&7);
  wp[off] = bf1(w[e]);
}

// ---------------------------------------------------------------- causal conv via bf16 MFMA implicit GEMM
__global__ __launch_bounds__(256) void convmf_kernel(
    const float* __restrict__ in, const unsigned short* __restrict__ wp,
    const float* __restrict__ bias, const float* __restrict__ scale,
    float* __restrict__ y, int Cin, int Cout, int Kw)
{
  __shared__ unsigned short xs[72*40];   // [row t][32 ci + 8 pad] bf16, row stride 80B
  const int b = blockIdx.z, t0 = blockIdx.x*64;
  const int tid = threadIdx.x, l = tid&63, wv = tid>>6;
  const int q = l>>4, m = l&15;
  const int TW = 64 + Kw - 1;
  const int abase = (wv*16 + m)*40 + q*8;
  const int boff = (m*4 + q)*8;
  f32x4 acc[4];
  #pragma unroll
  for(int nt=0;nt<4;nt++) acc[nt] = (f32x4)(0.f);

  const int nchunks = Cin >> 5;
  for(int cc=0; cc<nchunks; cc++){
    __syncthreads();
    for(int idx=tid; idx<TW*8; idx+=256){
      const int r = idx>>3, c4 = (idx&7)*4;
      const int tg = t0 - (Kw-1) + r;
      uint2 pk = make_uint2(0u, 0u);
      if(tg >= 0){
        float4 v = *(const float4*)&in[((size_t)b*T_ + tg)*Cin + cc*32 + c4];
        if(scale){
          const float4 s4 = *(const float4*)&scale[b*Cin + cc*32 + c4];
          v.x*=s4.x; v.y*=s4.y; v.z*=s4.z; v.w*=s4.w;
        }
        pk.x = bfpack(v.x, v.y); pk.y = bfpack(v.z, v.w);
      }
      *(uint2*)&xs[r*40 + c4] = pk;
    }
    __syncthreads();
    for(int kw=0; kw<Kw; kw++){
      const bfrag Af = *(const bfrag*)&xs[abase + kw*40];
      #pragma unroll
      for(int nt=0; nt<4; nt++){
        const unsigned short* wpp = wp + ((size_t)((cc*Kw + kw)*(Cout>>4) + (blockIdx.y*4 + nt)))*512 + boff;
        const bfrag Bf = *(const bfrag*)wpp;
        acc[nt] = __builtin_amdgcn_mfma_f32_16x16x32_bf16(Af, Bf, acc[nt], 0, 0, 0);
      }
    }
  }
  const int t_base = t0 + wv*16 + q*4;
  #pragma unroll
  for(int nt=0; nt<4; nt++){
    const int co = blockIdx.y*64 + nt*16 + m;
    const float bv = bias[co];
    #pragma unroll
    for(int r=0;r<4;r++){
      y[((size_t)b*T_ + t_base + r)*Cout + co] = acc[nt][r] + bv;
    }
  }
}

// ---------------------------------------------------------------- BN batch stats (sum, sumsq per channel)
__global__ __launch_bounds__(256) void bn_stats_kernel(
    const float* __restrict__ y, float* __restrict__ bnacc, int C)
{
  const int b = blockIdx.x, t0 = blockIdx.y*128, tid = threadIdx.x;
  const int c = tid & (C-1), part = tid / C, np = 256 / C;
  float s=0.f, sq=0.f;
  for(int t=t0+part; t<t0+128; t+=np){
    const float v = y[((size_t)b*T_ + t)*C + c];
    s += v; sq += v*v;
  }
  __shared__ float rs[256], rq[256];
  if(np > 1){
    rs[tid]=s; rq[tid]=sq;
    __syncthreads();
    if(part==0){ s += rs[tid+C]; sq += rq[tid+C]; }
  }
  if(part==0){
    atomicAdd(&bnacc[c], s);
    atomicAdd(&bnacc[C+c], sq);
  }
}

// ---------------------------------------------------------------- BN + gelu (in place) + per-(b,c) t-sum accum
__global__ __launch_bounds__(256) void bn_act_kernel(
    float* __restrict__ y, const float* __restrict__ bnacc,
    const float* __restrict__ gw, const float* __restrict__ bw,
    float* __restrict__ mean_acc, int C)
{
  const int b = blockIdx.x, t0 = blockIdx.y*128, tid = threadIdx.x;
  const int c = tid & (C-1), part = tid / C, np = 256 / C;
  const float cnt = (float)(B_*T_);
  const float mm = bnacc[c]/cnt;
  const float var = bnacc[C+c]/cnt - mm*mm;
  const float sc = gw[c]/sqrtf(var+1e-3f);
  const float sh = bw[c] - mm*sc;
  float s = 0.f;
  for(int t=t0+part; t<t0+128; t+=np){
    const size_t off = ((size_t)b*T_ + t)*C + c;
    float v = y[off];
    v = gelu_(v*sc + sh);
    y[off] = v;
    s += v;
  }
  __shared__ float rs[256];
  if(np > 1){
    rs[tid]=s;
    __syncthreads();
    if(part==0) s += rs[tid+C];
  }
  if(part==0) atomicAdd(&mean_acc[b*C+c], s);
}

// ---------------------------------------------------------------- SE (mean_in holds t-SUMS; scale by 1/T here)
__global__ __launch_bounds__(256) void se_kernel(
    const float* __restrict__ mean_in, const float* __restrict__ w1, const float* __restrict__ w2,
    float* __restrict__ scale, int C, int R)
{
  __shared__ float ms[256], hs[16];
  const int b=blockIdx.x, tid=threadIdx.x;
  if(tid<C) ms[tid]=mean_in[b*C+tid]*(1.f/(float)T_);
  __syncthreads();
  if(tid<R){ float s=0; for(int k=0;k<C;k++) s+=ms[k]*w1[k*R+tid]; hs[tid]=fmaxf(s,0.f); }
  __syncthreads();
  if(tid<C){ float s=0; for(int k=0;k<R;k++) s+=hs[k]*w2[k*C+tid]; scale[b*C+tid]=sig_(s); }
}

// ---------------------------------------------------------------- final fc + log_softmax (x2 holds t-sums)
__global__ __launch_bounds__(64) void head2_kernel(
    const float* __restrict__ x1, const float* __restrict__ x2,
    const float* __restrict__ fcw, const float* __restrict__ fcb, float* __restrict__ outls)
{
  const int b=blockIdx.x, tid=threadIdx.x;
  __shared__ float xa[256]; __shared__ float lg[NC_];
  for(int k=tid;k<256;k+=64) xa[k] = (k<128)? x1[b*128+k] : x2[b*128+(k-128)]*(1.f/(float)T_);
  __syncthreads();
  if(tid<NC_){
    float s = fcb[tid];
    for(int k=0;k<256;k++) s += xa[k]*fcw[k*NC_+tid];
    lg[tid]=s;
  }
  __syncthreads();
  if(tid==0){
    float mx=lg[0];
    for(int q=1;q<NC_;q++) mx=fmaxf(mx,lg[q]);
    float se=0;
    for(int q=0;q<NC_;q++) se += __expf(lg[q]-mx);
    const float lse = logf(se)+mx;
    for(int q=0;q<NC_;q++) outls[b*NC_+q] = lg[q]-lse;
  }
}

// ---------------------------------------------------------------- launch
extern "C" void kernel_launch(void* const* d_in, const int* in_sizes, int n_in,
                              void* d_out, int out_size, void* d_ws, size_t ws_size,
                              hipStream_t stream) {
  (void)in_sizes; (void)n_in; (void)out_size; (void)ws_size;
  const float* x        = (const float*)d_in[0];
  const float* eps_z    = (const float*)d_in[1];
  const float* eps_cat  = (const float*)d_in[2];
  const float* kan_w1   = (const float*)d_in[3];
  const float* kan_b1   = (const float*)d_in[4];
  const float* kan_w2   = (const float*)d_in[5];
  const float* kan_b2   = (const float*)d_in[6];
  const float* conv1_w  = (const float*)d_in[7];
  const float* conv1_b  = (const float*)d_in[8];
  const float* conv2_w  = (const float*)d_in[9];
  const float* conv2_b  = (const float*)d_in[10];
  const float* conv3_w  = (const float*)d_in[11];
  const float* conv3_b  = (const float*)d_in[12];
  const float* bn1_g    = (const float*)d_in[13];
  const float* bn1_b    = (const float*)d_in[14];
  const float* bn2_g    = (const float*)d_in[15];
  const float* bn2_b    = (const float*)d_in[16];
  const float* bn3_g    = (const float*)d_in[17];
  const float* bn3_b    = (const float*)d_in[18];
  const float* se1_w1   = (const float*)d_in[19];
  const float* se1_w2   = (const float*)d_in[20];
  const float* se2_w1   = (const float*)d_in[21];
  const float* se2_w2   = (const float*)d_in[22];
  const float* fc_mu_w  = (const float*)d_in[23];
  const float* fc_mu_b  = (const float*)d_in[24];
  const float* fc_std_w = (const float*)d_in[25];
  const float* fc_std_b = (const float*)d_in[26];
  const float* fc_muc_w = (const float*)d_in[27];
  const float* fc_muc_b = (const float*)d_in[28];
  const float* fc_stdc_w= (const float*)d_in[29];
  const float* fc_stdc_b= (const float*)d_in[30];
  const float* fc_w     = (const float*)d_in[31];
  const float* fc_b     = (const float*)d_in[32];

  float* out = (float*)d_out;
  float* out_ls   = out;
  float* out_mu   = out + 320;
  float* out_std  = out + 320 + 4096;
  float* out_muc  = out + 320 + 2*4096;
  float* out_stdc = out + 320 + 3*4096;

  float* ws = (float*)d_ws;
  const size_t SZ_HID = (size_t)B_*T_*H_;
  const size_t SZ_Y1  = (size_t)B_*T_*C1_;
  const size_t SZ_Y2  = (size_t)B_*T_*C2_;
  float*  hidden = ws;                      // [b][t][H]; reused as y3 [b][t][C3]
  float*  y1     = hidden + SZ_HID;         // [b][t][C1]
  float*  y2     = y1 + SZ_Y1;              // [b][t][C2]
  float*  norms  = y2 + SZ_Y2;
  double* rowsum = (double*)(norms + (size_t)B_*T_);
  double* psum   = rowsum + (size_t)B_*T_;
  float*  corr   = (float*)(psum + (size_t)B_*T_);
  float*  x1     = corr + (size_t)B_*H_;
  float*  bnbuf  = x1 + (size_t)B_*H_;      // 1024 floats
  float*  bn1    = bnbuf;
  float*  bn2    = bnbuf + 2*C1_;
  float*  bn3    = bnbuf + 2*C1_ + 2*C2_;
  float*  se1_in = bnbuf + 1024;
  float*  se1_sc = se1_in + (size_t)B_*C1_;
  float*  se2_in = se1_sc + (size_t)B_*C1_;
  float*  se2_sc = se2_in + (size_t)B_*C2_;
  float*  x2     = se2_sc + (size_t)B_*C2_;
  int*    cuts   = (int*)(x2 + (size_t)B_*C3_);
  float*  axbuf  = (float*)(cuts + B_);     // axT: B*16*T
  unsigned short* wp1 = (unsigned short*)(axbuf + (size_t)B_*16*T_);
  unsigned short* wp2 = wp1 + (size_t)C1_*F_*8;
  unsigned short* wp3 = wp2 + (size_t)C2_*C1_*5;
  float*  y3     = hidden;

  hipMemsetAsync(bnbuf, 0, (size_t)(1024 + 2*B_*C1_ + 2*B_*C2_ + B_*C3_)*sizeof(float), stream);

  // ---- weight prepack (bf16 fragments)
  prepack_kernel<<<(C1_*F_*8 + 255)/256, 256, 0, stream>>>(conv1_w, wp1, C1_, F_, 8);
  prepack_kernel<<<(C2_*C1_*5 + 255)/256, 256, 0, stream>>>(conv2_w, wp2, C2_, C1_, 5);
  prepack_kernel<<<(C3_*C2_*3 + 255)/256, 256, 0, stream>>>(conv3_w, wp3, C3_, C2_, 3);

  // ---- recurrent branch
  ax_kernel<<<(B_*T_)/16, 256, 0, stream>>>(x, kan_w1, kan_b1, axbuf);
  lstm_kernel<<<B_, 128, 0, stream>>>(axbuf, kan_w1, kan_w2, kan_b2, hidden);
  norm_kernel<<<(B_*T_)/8, 256, 0, stream>>>(hidden, norms);
  s_kernel<<<B_*16, 256, 0, stream>>>(hidden, norms, rowsum, psum);
  cluster_kernel<<<B_, 256, 0, stream>>>(rowsum, psum, hidden, corr, cuts);
  head1_kernel<<<B_, 128, 0, stream>>>(corr, hidden, eps_z, eps_cat,
      fc_mu_w, fc_mu_b, fc_std_w, fc_std_b, fc_muc_w, fc_muc_b, fc_stdc_w, fc_stdc_b,
      out_mu, out_std, out_muc, out_stdc, x1);

  // ---- conv branch (bf16 MFMA implicit GEMM; all tensors [b][t][c])
  convmf_kernel<<<dim3(16, C1_/64, B_), 256, 0, stream>>>(x,  wp1, conv1_b, nullptr, y1, F_,  C1_, 8);
  bn_stats_kernel<<<dim3(B_, 8), 256, 0, stream>>>(y1, bn1, C1_);
  bn_act_kernel<<<dim3(B_, 8), 256, 0, stream>>>(y1, bn1, bn1_g, bn1_b, se1_in, C1_);
  se_kernel<<<B_, 256, 0, stream>>>(se1_in, se1_w1, se1_w2, se1_sc, C1_, C1_/16);
  convmf_kernel<<<dim3(16, C2_/64, B_), 256, 0, stream>>>(y1, wp2, conv2_b, se1_sc, y2, C1_, C2_, 5);
  bn_stats_kernel<<<dim3(B_, 8), 256, 0, stream>>>(y2, bn2, C2_);
  bn_act_kernel<<<dim3(B_, 8), 256, 0, stream>>>(y2, bn2, bn2_g, bn2_b, se2_in, C2_);
  se_kernel<<<B_, 256, 0, stream>>>(se2_in, se2_w1, se2_w2, se2_sc, C2_, C2_/16);
  convmf_kernel<<<dim3(16, C3_/64, B_), 256, 0, stream>>>(y2, wp3, conv3_b, se2_sc, y3, C2_, C3_, 3);
  bn_stats_kernel<<<dim3(B_, 8), 256, 0, stream>>>(y3, bn3, C3_);
  bn_act_kernel<<<dim3(B_, 8), 256, 0, stream>>>(y3, bn3, bn3_g, bn3_b, x2, C3_);

  // ---- final head
  head2_kernel<<<B_, 64, 0, stream>>>(x1, x2, fc_w, fc_b, out_ls);
}

// Round 6
// 1084.985 us; speedup vs baseline: 2.1837x; 1.0948x over previous
//
#include <hip/hip_runtime.h>
#include <math.h>

#define B_ 32
#define T_ 1024
#define F_ 64
#define H_ 128
#define D_ 192
#define KH_ 16
#define C1_ 128
#define C2_ 256
#define C3_ 128
#define NC_ 10

typedef float v2f __attribute__((ext_vector_type(2)));
typedef float f32x4 __attribute__((ext_vector_type(4)));
typedef __bf16 bfrag __attribute__((ext_vector_type(8)));

__device__ __forceinline__ float sig_(float x){ return 1.f/(1.f+__expf(-x)); }
__device__ __forceinline__ float tanh_(float x){ return 1.f - 2.f/(__expf(2.f*x)+1.f); }
__device__ __forceinline__ float gelu_(float x){ return 0.5f*x*(1.f+erff(x*0.70710678118654752f)); }
__device__ __forceinline__ float softplus_(float x){ return fmaxf(x,0.f) + log1pf(__expf(-fabsf(x))); }

__device__ __forceinline__ unsigned bfpack(float a, float b){
  unsigned ua = __float_as_uint(a), ub = __float_as_uint(b);
  ua = ua + 0x7FFFu + ((ua>>16)&1u);
  ub = ub + 0x7FFFu + ((ub>>16)&1u);
  return (ua>>16) | (ub & 0xFFFF0000u);
}
__device__ __forceinline__ unsigned short bf1(float a){
  unsigned ua = __float_as_uint(a);
  ua = ua + 0x7FFFu + ((ua>>16)&1u);
  return (unsigned short)(ua>>16);
}
__device__ __forceinline__ float bf2f(unsigned short h){
  return __uint_as_float(((unsigned)h)<<16);
}

#define QPERM_XOR1(x) __int_as_float(__builtin_amdgcn_mov_dpp(__float_as_int(x), 0xB1, 0xF, 0xF, true))
#define QPERM_XOR2(x) __int_as_float(__builtin_amdgcn_mov_dpp(__float_as_int(x), 0x4E, 0xF, 0xF, true))

// LDS-only barrier: waits ds ops (lgkm) but lets global stores stay in flight
#define LDS_BARRIER() asm volatile("s_waitcnt lgkmcnt(0)\n\ts_barrier" ::: "memory")

// ---------------------------------------------------------------- ax precompute (transposed out: axT[b][j][t])
__global__ __launch_bounds__(256) void ax_kernel(
    const float* __restrict__ x, const float* __restrict__ w1, const float* __restrict__ b1,
    float* __restrict__ axT)
{
  __shared__ float xs[16][68];
  __shared__ float w1s[64][16];
  const int bt0 = blockIdx.x*16;
  const int tid = threadIdx.x;
  for(int i=tid;i<64*16;i+=256){ w1s[i>>4][i&15] = w1[i]; }
  for(int i=tid;i<16*64;i+=256){ const int r=i>>6, d=i&63; xs[r][d] = x[(size_t)(bt0+r)*64 + d]; }
  __syncthreads();
  const int r = tid>>4, j = tid&15;
  float s = b1[j];
  #pragma unroll
  for(int d=0; d<64; d++) s += xs[r][d]*w1s[d][j];
  const int bt = bt0 + r;
  axT[((size_t)(bt>>10)*16 + j)*1024 + (bt&1023)] = s;
}

// ---------------------------------------------------------------- LSTM scan (2 waves/batch, unchanged from R5)
__global__ __launch_bounds__(128, 1) void lstm_kernel(
    const float* __restrict__ axT, const float* __restrict__ w1,
    const float* __restrict__ w2, const float* __restrict__ b2,
    float* __restrict__ hidden)
{
  __shared__ float hs[2][148];   // [parity][4 chunks x 36]
  const int b = blockIdx.x, tid = threadIdx.x;
  const int l = tid & 63, wv = tid >> 6;
  const int j = l >> 2, g = l & 3;
  const int hi = wv*64 + l;

  v2f w1hv[16];
  #pragma unroll
  for(int q=0;q<16;q++){
    w1hv[q].x = w1[(64 + g*32 + 2*q)*KH_ + j];
    w1hv[q].y = w1[(64 + g*32 + 2*q + 1)*KH_ + j];
  }
  v2f w2if[16], w2go[16];
  #pragma unroll
  for(int k=0;k<16;k++){
    w2if[k].x = w2[k*512 + hi];       w2if[k].y = w2[k*512 + 128 + hi];
    w2go[k].x = w2[k*512 + 256 + hi]; w2go[k].y = w2[k*512 + 384 + hi];
  }
  v2f bif, bgo;
  bif.x = b2[hi]; bif.y = b2[128+hi]; bgo.x = b2[256+hi]; bgo.y = b2[384+hi];

  for(int i=tid;i<2*148;i+=128) ((float*)hs)[i]=0.f;
  float c = 0.f;
  const float* axr = axT + ((size_t)b*16 + j)*1024;
  float* hb = hidden + (size_t)b*T_*H_;
  const int hwi = (hi>>5)*36 + (hi&31);
  float4 axA = *(const float4*)&axr[0];
  float4 axB = *(const float4*)&axr[4];
  __syncthreads();

#define LSTM_STEP(tt, axv, RB) { \
    const float* hsr = hs[RB]; \
    v2f ap0=(v2f)(0.f), ap1=(v2f)(0.f), ap2=(v2f)(0.f), ap3=(v2f)(0.f); \
    { const float4 hv = *(const float4*)&hsr[g*36 + 0];  ap0 += ((v2f){hv.x,hv.y})*w1hv[0]  + ((v2f){hv.z,hv.w})*w1hv[1]; } \
    { const float4 hv = *(const float4*)&hsr[g*36 + 4];  ap1 += ((v2f){hv.x,hv.y})*w1hv[2]  + ((v2f){hv.z,hv.w})*w1hv[3]; } \
    { const float4 hv = *(const float4*)&hsr[g*36 + 8];  ap2 += ((v2f){hv.x,hv.y})*w1hv[4]  + ((v2f){hv.z,hv.w})*w1hv[5]; } \
    { const float4 hv = *(const float4*)&hsr[g*36 + 12]; ap3 += ((v2f){hv.x,hv.y})*w1hv[6]  + ((v2f){hv.z,hv.w})*w1hv[7]; } \
    { const float4 hv = *(const float4*)&hsr[g*36 + 16]; ap0 += ((v2f){hv.x,hv.y})*w1hv[8]  + ((v2f){hv.z,hv.w})*w1hv[9]; } \
    { const float4 hv = *(const float4*)&hsr[g*36 + 20]; ap1 += ((v2f){hv.x,hv.y})*w1hv[10] + ((v2f){hv.z,hv.w})*w1hv[11]; } \
    { const float4 hv = *(const float4*)&hsr[g*36 + 24]; ap2 += ((v2f){hv.x,hv.y})*w1hv[12] + ((v2f){hv.z,hv.w})*w1hv[13]; } \
    { const float4 hv = *(const float4*)&hsr[g*36 + 28]; ap3 += ((v2f){hv.x,hv.y})*w1hv[14] + ((v2f){hv.z,hv.w})*w1hv[15]; } \
    const v2f apt = (ap0+ap1)+(ap2+ap3); \
    float a = apt.x + apt.y; \
    a += QPERM_XOR1(a); \
    a += QPERM_XOR2(a); \
    a += (axv); \
    const float g1 = a * sig_(a); \
    v2f aIF = bif, aGO = bgo; \
    _Pragma("unroll") \
    for(int k=0;k<16;k++){ \
      const float gk = __int_as_float(__builtin_amdgcn_readlane(__float_as_int(g1), 4*k)); \
      v2f gk2; gk2.x=gk; gk2.y=gk; \
      aIF += gk2 * w2if[k]; \
      aGO += gk2 * w2go[k]; \
    } \
    const float si = sig_(aIF.x); \
    const float sf = sig_(aIF.y); \
    const float tg = tanh_(aGO.x); \
    const float so = sig_(aGO.y); \
    c = sf*c + si*tg; \
    const float h = so * tanh_(c); \
    hs[1-(RB)][hwi] = h; \
    hb[(size_t)(tt)*H_ + hi] = h; \
    LDS_BARRIER(); \
  }

  for(int t0=0;t0<T_;t0+=4){
    const int tl = (t0+8 < 1020) ? (t0+8) : 1020;
    const float4 axC = *(const float4*)&axr[tl];
    LSTM_STEP(t0+0, axA.x, 0)
    LSTM_STEP(t0+1, axA.y, 1)
    LSTM_STEP(t0+2, axA.z, 0)
    LSTM_STEP(t0+3, axA.w, 1)
    axA = axB; axB = axC;
  }
#undef LSTM_STEP
}

// ---------------------------------------------------------------- row norms
__global__ __launch_bounds__(256) void norm_kernel(const float* __restrict__ hidden, float* __restrict__ norms)
{
  const int row = blockIdx.x*8 + (threadIdx.x>>5);
  const int l = threadIdx.x&31;
  const float* hr = hidden + (size_t)row*H_;
  float s = 0.f;
  for(int k=l;k<H_;k+=32){ float v=hr[k]; s+=v*v; }
  #pragma unroll
  for(int m=16;m>=1;m>>=1) s += __shfl_xor(s, m, 64);
  if(l==0) norms[row] = fmaxf(sqrtf(s), 1e-8f);
}

// ---------------------------------------------------------------- S rowsums via bf16 MFMA (hi/lo split Gram)
// dot(hn_i,hn_j) ~ hi_i.hi_j + hi_i.lo_j + lo_i.hi_j  (error ~1e-4 rel)
// block: (b, i-block of 64). 4 waves: wave wv -> rows [wv*16,wv*16+16).
// sweep 16 j-tiles of 64; per jt: 4 kc x 4 nt x 3 MFMA.
__global__ __launch_bounds__(256) void s_kernel(
    const float* __restrict__ hidden, const float* __restrict__ norms,
    double* __restrict__ rowsum, double* __restrict__ psum)
{
  __shared__ unsigned short Ahi[64*136], Alo[64*136];   // 17.4 KB each (stride 136 shorts)
  __shared__ unsigned short Bhi[64*136], Blo[64*136];
  __shared__ double red[64][17];
  const int b = blockIdx.x >> 4;
  const int i0 = (blockIdx.x & 15) * 64;
  const int tid = threadIdx.x, l = tid & 63, wv = tid >> 6;
  const int m = l & 15, q = l >> 4;
  const float* hb = hidden + (size_t)b*T_*H_;
  const float* nb = norms + (size_t)b*T_;

  // stage A rows (normalized, hi/lo bf16)
  for(int idx=tid; idx<64*32; idx+=256){
    const int r = idx>>5, k4 = (idx&31)*4;
    float4 v = *(const float4*)&hb[(size_t)(i0+r)*H_ + k4];
    const float inv = 1.f/nb[i0+r];
    const float f0=v.x*inv, f1=v.y*inv, f2=v.z*inv, f3=v.w*inv;
    const unsigned short h0=bf1(f0), h1=bf1(f1), h2=bf1(f2), h3=bf1(f3);
    uint2 phi; phi.x = (unsigned)h0 | ((unsigned)h1<<16); phi.y = (unsigned)h2 | ((unsigned)h3<<16);
    *(uint2*)&Ahi[r*136 + k4] = phi;
    const unsigned short g0=bf1(f0-bf2f(h0)), g1=bf1(f1-bf2f(h1)), g2=bf1(f2-bf2f(h2)), g3=bf1(f3-bf2f(h3));
    uint2 plo; plo.x = (unsigned)g0 | ((unsigned)g1<<16); plo.y = (unsigned)g2 | ((unsigned)g3<<16);
    *(uint2*)&Alo[r*136 + k4] = plo;
  }

  double rs[4]={0,0,0,0}, ps[4]={0,0,0,0};
  const int arow = (wv*16 + m)*136;

  for(int jt=0;jt<16;jt++){
    const int j0 = jt*64;
    __syncthreads();
    for(int idx=tid; idx<64*32; idx+=256){
      const int r = idx>>5, k4 = (idx&31)*4;
      float4 v = *(const float4*)&hb[(size_t)(j0+r)*H_ + k4];
      const float inv = 1.f/nb[j0+r];
      const float f0=v.x*inv, f1=v.y*inv, f2=v.z*inv, f3=v.w*inv;
      const unsigned short h0=bf1(f0), h1=bf1(f1), h2=bf1(f2), h3=bf1(f3);
      uint2 phi; phi.x = (unsigned)h0 | ((unsigned)h1<<16); phi.y = (unsigned)h2 | ((unsigned)h3<<16);
      *(uint2*)&Bhi[r*136 + k4] = phi;
      const unsigned short g0=bf1(f0-bf2f(h0)), g1=bf1(f1-bf2f(h1)), g2=bf1(f2-bf2f(h2)), g3=bf1(f3-bf2f(h3));
      uint2 plo; plo.x = (unsigned)g0 | ((unsigned)g1<<16); plo.y = (unsigned)g2 | ((unsigned)g3<<16);
      *(uint2*)&Blo[r*136 + k4] = plo;
    }
    __syncthreads();

    f32x4 acc[4];
    #pragma unroll
    for(int nt=0;nt<4;nt++) acc[nt] = (f32x4)(0.f);
    #pragma unroll
    for(int kc=0;kc<4;kc++){
      const bfrag Ah = *(const bfrag*)&Ahi[arow + kc*32 + q*8];
      const bfrag Al = *(const bfrag*)&Alo[arow + kc*32 + q*8];
      #pragma unroll
      for(int nt=0;nt<4;nt++){
        const int brow = (nt*16 + m)*136 + kc*32 + q*8;
        const bfrag Bh = *(const bfrag*)&Bhi[brow];
        const bfrag Bl = *(const bfrag*)&Blo[brow];
        acc[nt] = __builtin_amdgcn_mfma_f32_16x16x32_bf16(Ah, Bh, acc[nt], 0, 0, 0);
        acc[nt] = __builtin_amdgcn_mfma_f32_16x16x32_bf16(Al, Bh, acc[nt], 0, 0, 0);
        acc[nt] = __builtin_amdgcn_mfma_f32_16x16x32_bf16(Ah, Bl, acc[nt], 0, 0, 0);
      }
    }
    // epilogue: exp + accumulate (C/D: col=lane&15, row=q*4+r)
    #pragma unroll
    for(int nt=0;nt<4;nt++){
      const int gj = j0 + nt*16 + m;
      #pragma unroll
      for(int r=0;r<4;r++){
        const int gi = i0 + wv*16 + q*4 + r;
        if(gi == gj) continue;
        const float sv = __expf(-5.5f*(1.f - acc[nt][r]));
        rs[r] += (double)sv;
        if(gj < gi) ps[r] += (double)sv;
      }
    }
  }
  __syncthreads();
  #pragma unroll
  for(int r=0;r<4;r++) red[wv*16 + q*4 + r][m] = rs[r];
  __syncthreads();
  if(tid<64){ double v=0; for(int k=0;k<16;k++) v+=red[tid][k]; rowsum[(size_t)b*T_ + i0 + tid]=v; }
  __syncthreads();
  #pragma unroll
  for(int r=0;r<4;r++) red[wv*16 + q*4 + r][m] = ps[r];
  __syncthreads();
  if(tid<64){ double v=0; for(int k=0;k<16;k++) v+=red[tid][k]; psum[(size_t)b*T_ + i0 + tid]=v; }
}

// ---------------------------------------------------------------- cluster: prefix+dist+argmax+corr
__global__ __launch_bounds__(256) void cluster_kernel(
    const double* __restrict__ rowsum, const double* __restrict__ psum,
    const float* __restrict__ hidden, float* __restrict__ corr, int* __restrict__ cuts)
{
  const int b = blockIdx.x, tid = threadIdx.x;
  const double* r = rowsum + (size_t)b*T_;
  const double* p = psum + (size_t)b*T_;
  __shared__ double sr[256], sp[256];
  __shared__ double totR_s;
  __shared__ double bd[256]; __shared__ int bidx[256];
  __shared__ int cut_s;
  double r4[4], p4[4];
  #pragma unroll
  for(int q=0;q<4;q++){ r4[q]=r[tid*4+q]; p4[q]=p[tid*4+q]; }
  sr[tid]=r4[0]+r4[1]+r4[2]+r4[3];
  sp[tid]=p4[0]+p4[1]+p4[2]+p4[3];
  __syncthreads();
  if(tid==0){
    double ar=0, ap=0;
    for(int i=0;i<256;i++){ double tr=sr[i], tp=sp[i]; sr[i]=ar; sp[i]=ap; ar+=tr; ap+=tp; }
    totR_s = ar;
  }
  __syncthreads();
  double cr = sr[tid], cp = sp[tid];
  const double full = totR_s;
  double best = -1e308; int bi = 1;
  #pragma unroll
  for(int q=0;q<4;q++){
    cr += r4[q]; cp += p4[q];
    const int i = 4*tid + q + 1;
    if(i < T_){
      const double TL = 2.0*cp;
      const double TRv = cr - TL;
      const double BR = full - TL - 2.0*TRv;
      const double di = (double)i, dn = (double)(T_-i);
      const double dist = TL/(di*di) + BR/(dn*dn) - (2.0*TRv)/(di*dn);
      if(dist > best){ best=dist; bi=i; }
    }
  }
  bd[tid]=best; bidx[tid]=bi;
  __syncthreads();
  if(tid==0){
    double bb=-1e308; int ii=1;
    for(int q=0;q<256;q++){ if(bd[q]>bb){ bb=bd[q]; ii=bidx[q]; } }
    cut_s=ii; cuts[b]=ii;
  }
  __syncthreads();
  const int cut = cut_s;
  const int h = tid&127, half = tid>>7;
  float s=0.f;
  const float* hb = hidden + (size_t)b*T_*H_;
  for(int t=half; t<cut; t+=2) s += hb[(size_t)t*H_ + h];
  __shared__ float c2[2][128];
  c2[half][h]=s;
  __syncthreads();
  if(tid<128) corr[b*H_+tid] = (c2[0][tid]+c2[1][tid])/(float)cut;
}

// ---------------------------------------------------------------- VAE heads
__global__ __launch_bounds__(128) void head1_kernel(
    const float* __restrict__ corr, const float* __restrict__ hidden,
    const float* __restrict__ eps_z, const float* __restrict__ eps_cat,
    const float* __restrict__ mu_w, const float* __restrict__ mu_b,
    const float* __restrict__ std_w, const float* __restrict__ std_b,
    const float* __restrict__ muc_w, const float* __restrict__ muc_b,
    const float* __restrict__ stdc_w, const float* __restrict__ stdc_b,
    float* __restrict__ out_mu, float* __restrict__ out_std,
    float* __restrict__ out_muc, float* __restrict__ out_stdc, float* __restrict__ x1)
{
  const int b=blockIdx.x, h=threadIdx.x;
  __shared__ float cs[128], xz[256];
  cs[h]=corr[b*H_+h];
  xz[h]=hidden[((size_t)b*T_ + (T_-1))*H_ + h];
  __syncthreads();
  float m=mu_b[h], sdv=std_b[h];
  for(int k=0;k<H_;k++){ const float cv=cs[k]; m+=cv*mu_w[k*H_+h]; sdv+=cv*std_w[k*H_+h]; }
  const float stdv = softplus_(sdv);
  out_mu[b*H_+h]=m; out_std[b*H_+h]=stdv;
  xz[128+h] = m + stdv*eps_z[b*H_+h];
  __syncthreads();
  float mc=muc_b[h], sc=stdc_b[h];
  for(int k=0;k<256;k++){ const float v=xz[k]; mc+=v*muc_w[k*H_+h]; sc+=v*stdc_w[k*H_+h]; }
  const float stdc = softplus_(sc);
  out_muc[b*H_+h]=mc; out_stdc[b*H_+h]=stdc;
  x1[b*H_+h]=mc + stdc*eps_cat[b*H_+h];
}

// ---------------------------------------------------------------- fused weight prepack (all 3 convs)
__global__ __launch_bounds__(256) void prepack3_kernel(
    const float* __restrict__ w1s, const float* __restrict__ w2s, const float* __restrict__ w3s,
    unsigned short* __restrict__ wp1, unsigned short* __restrict__ wp2, unsigned short* __restrict__ wp3)
{
  int e = blockIdx.x*256 + threadIdx.x;
  const float* w; unsigned short* wp; int Cout, Cin, Kw;
  if(e < 65536){ w=w1s; wp=wp1; Cout=C1_; Cin=F_;  Kw=8; }
  else if(e < 65536+163840){ e-=65536; w=w2s; wp=wp2; Cout=C2_; Cin=C1_; Kw=5; }
  else { e-=229376; w=w3s; wp=wp3; Cout=C3_; Cin=C2_; Kw=3; }
  const int co = e/(Cin*Kw);
  const int rem = e - co*(Cin*Kw);
  const int ci = rem/Kw, kw = rem - ci*Kw;
  const int off = (((ci>>5)*Kw + kw)*(Cout>>4) + (co>>4))*512 + ((co&15)*4 + ((ci>>3)&3))*8 + (ci&7);
  wp[off] = bf1(w[e]);
}

// ---------------------------------------------------------------- causal conv via bf16 MFMA + fused BN partials
__global__ __launch_bounds__(256) void convmf_kernel(
    const float* __restrict__ in, const unsigned short* __restrict__ wp,
    const float* __restrict__ bias, const float* __restrict__ scale,
    float* __restrict__ y, float* __restrict__ bnacc, int Cin, int Cout, int Kw)
{
  __shared__ unsigned short xs[72*40];   // [row t][32 ci + 8 pad] bf16 (also reused as f32 reduce buf)
  const int b = blockIdx.z, t0 = blockIdx.x*64, co0 = blockIdx.y*64;
  const int tid = threadIdx.x, l = tid&63, wv = tid>>6;
  const int q = l>>4, m = l&15;
  const int TW = 64 + Kw - 1;
  const int abase = (wv*16 + m)*40 + q*8;
  const int boff = (m*4 + q)*8;
  f32x4 acc[4];
  #pragma unroll
  for(int nt=0;nt<4;nt++) acc[nt] = (f32x4)(0.f);

  const int nchunks = Cin >> 5;
  for(int cc=0; cc<nchunks; cc++){
    __syncthreads();
    for(int idx=tid; idx<TW*8; idx+=256){
      const int r = idx>>3, c4 = (idx&7)*4;
      const int tg = t0 - (Kw-1) + r;
      uint2 pk = make_uint2(0u, 0u);
      if(tg >= 0){
        float4 v = *(const float4*)&in[((size_t)b*T_ + tg)*Cin + cc*32 + c4];
        if(scale){
          const float4 s4 = *(const float4*)&scale[b*Cin + cc*32 + c4];
          v.x*=s4.x; v.y*=s4.y; v.z*=s4.z; v.w*=s4.w;
        }
        pk.x = bfpack(v.x, v.y); pk.y = bfpack(v.z, v.w);
      }
      *(uint2*)&xs[r*40 + c4] = pk;
    }
    __syncthreads();
    for(int kw=0; kw<Kw; kw++){
      const bfrag Af = *(const bfrag*)&xs[abase + kw*40];
      #pragma unroll
      for(int nt=0; nt<4; nt++){
        const unsigned short* wpp = wp + ((size_t)((cc*Kw + kw)*(Cout>>4) + (blockIdx.y*4 + nt)))*512 + boff;
        const bfrag Bf = *(const bfrag*)wpp;
        acc[nt] = __builtin_amdgcn_mfma_f32_16x16x32_bf16(Af, Bf, acc[nt], 0, 0, 0);
      }
    }
  }
  __syncthreads();   // xs reuse safety
  float* part = (float*)xs;          // [4 wv][64 co][2]
  const int t_base = t0 + wv*16 + q*4;
  #pragma unroll
  for(int nt=0; nt<4; nt++){
    const int co = co0 + nt*16 + m;
    const float bv = bias[co];
    float s1 = 0.f, s2 = 0.f;
    #pragma unroll
    for(int r=0;r<4;r++){
      const float v = acc[nt][r] + bv;
      y[((size_t)b*T_ + t_base + r)*Cout + co] = v;
      s1 += v; s2 += v*v;
    }
    s1 += __shfl_xor(s1, 16); s1 += __shfl_xor(s1, 32);
    s2 += __shfl_xor(s2, 16); s2 += __shfl_xor(s2, 32);
    if(q==0){ part[(wv*64 + nt*16 + m)*2+0] = s1; part[(wv*64 + nt*16 + m)*2+1] = s2; }
  }
  __syncthreads();
  if(tid < 64){
    float a1=0.f, a2=0.f;
    #pragma unroll
    for(int w2i=0; w2i<4; w2i++){ a1 += part[(w2i*64+tid)*2+0]; a2 += part[(w2i*64+tid)*2+1]; }
    atomicAdd(&bnacc[co0 + tid], a1);
    atomicAdd(&bnacc[Cout + co0 + tid], a2);
  }
}

// ---------------------------------------------------------------- BN + gelu + per-(b,c) t-sum accum
__global__ __launch_bounds__(256) void bn_act_kernel(
    float* __restrict__ y, const float* __restrict__ bnacc,
    const float* __restrict__ gw, const float* __restrict__ bw,
    float* __restrict__ mean_acc, int C, int write_y)
{
  const int b = blockIdx.x, t0 = blockIdx.y*128, tid = threadIdx.x;
  const int c = tid & (C-1), part = tid / C, np = 256 / C;
  const float cnt = (float)(B_*T_);
  const float mm = bnacc[c]/cnt;
  const float var = bnacc[C+c]/cnt - mm*mm;
  const float sc = gw[c]/sqrtf(var+1e-3f);
  const float sh = bw[c] - mm*sc;
  float s = 0.f;
  for(int t=t0+part; t<t0+128; t+=np){
    const size_t off = ((size_t)b*T_ + t)*C + c;
    float v = y[off];
    v = gelu_(v*sc + sh);
    if(write_y) y[off] = v;
    s += v;
  }
  __shared__ float rs[256];
  if(np > 1){
    rs[tid]=s;
    __syncthreads();
    if(part==0) s += rs[tid+C];
  }
  if(part==0) atomicAdd(&mean_acc[b*C+c], s);
}

// ---------------------------------------------------------------- SE (mean_in holds t-SUMS; scale by 1/T here)
__global__ __launch_bounds__(256) void se_kernel(
    const float* __restrict__ mean_in, const float* __restrict__ w1, const float* __restrict__ w2,
    float* __restrict__ scale, int C, int R)
{
  __shared__ float ms[256], hs[16];
  const int b=blockIdx.x, tid=threadIdx.x;
  if(tid<C) ms[tid]=mean_in[b*C+tid]*(1.f/(float)T_);
  __syncthreads();
  if(tid<R){ float s=0; for(int k=0;k<C;k++) s+=ms[k]*w1[k*R+tid]; hs[tid]=fmaxf(s,0.f); }
  __syncthreads();
  if(tid<C){ float s=0; for(int k=0;k<R;k++) s+=hs[k]*w2[k*C+tid]; scale[b*C+tid]=sig_(s); }
}

// ---------------------------------------------------------------- final fc + log_softmax (x2 holds t-sums)
__global__ __launch_bounds__(64) void head2_kernel(
    const float* __restrict__ x1, const float* __restrict__ x2,
    const float* __restrict__ fcw, const float* __restrict__ fcb, float* __restrict__ outls)
{
  const int b=blockIdx.x, tid=threadIdx.x;
  __shared__ float xa[256]; __shared__ float lg[NC_];
  for(int k=tid;k<256;k+=64) xa[k] = (k<128)? x1[b*128+k] : x2[b*128+(k-128)]*(1.f/(float)T_);
  __syncthreads();
  if(tid<NC_){
    float s = fcb[tid];
    for(int k=0;k<256;k++) s += xa[k]*fcw[k*NC_+tid];
    lg[tid]=s;
  }
  __syncthreads();
  if(tid==0){
    float mx=lg[0];
    for(int q=1;q<NC_;q++) mx=fmaxf(mx,lg[q]);
    float se=0;
    for(int q=0;q<NC_;q++) se += __expf(lg[q]-mx);
    const float lse = logf(se)+mx;
    for(int q=0;q<NC_;q++) outls[b*NC_+q] = lg[q]-lse;
  }
}

// ---------------------------------------------------------------- launch
extern "C" void kernel_launch(void* const* d_in, const int* in_sizes, int n_in,
                              void* d_out, int out_size, void* d_ws, size_t ws_size,
                              hipStream_t stream) {
  (void)in_sizes; (void)n_in; (void)out_size; (void)ws_size;
  const float* x        = (const float*)d_in[0];
  const float* eps_z    = (const float*)d_in[1];
  const float* eps_cat  = (const float*)d_in[2];
  const float* kan_w1   = (const float*)d_in[3];
  const float* kan_b1   = (const float*)d_in[4];
  const float* kan_w2   = (const float*)d_in[5];
  const float* kan_b2   = (const float*)d_in[6];
  const float* conv1_w  = (const float*)d_in[7];
  const float* conv1_b  = (const float*)d_in[8];
  const float* conv2_w  = (const float*)d_in[9];
  const float* conv2_b  = (const float*)d_in[10];
  const float* conv3_w  = (const float*)d_in[11];
  const float* conv3_b  = (const float*)d_in[12];
  const float* bn1_g    = (const float*)d_in[13];
  const float* bn1_b    = (const float*)d_in[14];
  const float* bn2_g    = (const float*)d_in[15];
  const float* bn2_b    = (const float*)d_in[16];
  const float* bn3_g    = (const float*)d_in[17];
  const float* bn3_b    = (const float*)d_in[18];
  const float* se1_w1   = (const float*)d_in[19];
  const float* se1_w2   = (const float*)d_in[20];
  const float* se2_w1   = (const float*)d_in[21];
  const float* se2_w2   = (const float*)d_in[22];
  const float* fc_mu_w  = (const float*)d_in[23];
  const float* fc_mu_b  = (const float*)d_in[24];
  const float* fc_std_w = (const float*)d_in[25];
  const float* fc_std_b = (const float*)d_in[26];
  const float* fc_muc_w = (const float*)d_in[27];
  const float* fc_muc_b = (const float*)d_in[28];
  const float* fc_stdc_w= (const float*)d_in[29];
  const float* fc_stdc_b= (const float*)d_in[30];
  const float* fc_w     = (const float*)d_in[31];
  const float* fc_b     = (const float*)d_in[32];

  float* out = (float*)d_out;
  float* out_ls   = out;
  float* out_mu   = out + 320;
  float* out_std  = out + 320 + 4096;
  float* out_muc  = out + 320 + 2*4096;
  float* out_stdc = out + 320 + 3*4096;

  float* ws = (float*)d_ws;
  const size_t SZ_HID = (size_t)B_*T_*H_;
  const size_t SZ_Y1  = (size_t)B_*T_*C1_;
  const size_t SZ_Y2  = (size_t)B_*T_*C2_;
  float*  hidden = ws;                      // [b][t][H]; reused as y3 [b][t][C3]
  float*  y1     = hidden + SZ_HID;
  float*  y2     = y1 + SZ_Y1;
  float*  norms  = y2 + SZ_Y2;
  double* rowsum = (double*)(norms + (size_t)B_*T_);
  double* psum   = rowsum + (size_t)B_*T_;
  float*  corr   = (float*)(psum + (size_t)B_*T_);
  float*  x1     = corr + (size_t)B_*H_;
  float*  bnbuf  = x1 + (size_t)B_*H_;      // 1024 floats
  float*  bn1    = bnbuf;
  float*  bn2    = bnbuf + 2*C1_;
  float*  bn3    = bnbuf + 2*C1_ + 2*C2_;
  float*  se1_in = bnbuf + 1024;
  float*  se1_sc = se1_in + (size_t)B_*C1_;
  float*  se2_in = se1_sc + (size_t)B_*C1_;
  float*  se2_sc = se2_in + (size_t)B_*C2_;
  float*  x2     = se2_sc + (size_t)B_*C2_;
  int*    cuts   = (int*)(x2 + (size_t)B_*C3_);
  float*  axbuf  = (float*)(cuts + B_);     // axT: B*16*T
  unsigned short* wp1 = (unsigned short*)(axbuf + (size_t)B_*16*T_);
  unsigned short* wp2 = wp1 + (size_t)C1_*F_*8;
  unsigned short* wp3 = wp2 + (size_t)C2_*C1_*5;
  float*  y3     = hidden;

  hipMemsetAsync(bnbuf, 0, (size_t)(1024 + 2*B_*C1_ + 2*B_*C2_ + B_*C3_)*sizeof(float), stream);

  // ---- weight prepack (bf16 fragments, single dispatch)
  prepack3_kernel<<<1280, 256, 0, stream>>>(conv1_w, conv2_w, conv3_w, wp1, wp2, wp3);

  // ---- recurrent branch
  ax_kernel<<<(B_*T_)/16, 256, 0, stream>>>(x, kan_w1, kan_b1, axbuf);
  lstm_kernel<<<B_, 128, 0, stream>>>(axbuf, kan_w1, kan_w2, kan_b2, hidden);
  norm_kernel<<<(B_*T_)/8, 256, 0, stream>>>(hidden, norms);
  s_kernel<<<B_*16, 256, 0, stream>>>(hidden, norms, rowsum, psum);
  cluster_kernel<<<B_, 256, 0, stream>>>(rowsum, psum, hidden, corr, cuts);
  head1_kernel<<<B_, 128, 0, stream>>>(corr, hidden, eps_z, eps_cat,
      fc_mu_w, fc_mu_b, fc_std_w, fc_std_b, fc_muc_w, fc_muc_b, fc_stdc_w, fc_stdc_b,
      out_mu, out_std, out_muc, out_stdc, x1);

  // ---- conv branch (bf16 MFMA implicit GEMM; BN stats fused into conv epilogue)
  convmf_kernel<<<dim3(16, C1_/64, B_), 256, 0, stream>>>(x,  wp1, conv1_b, nullptr, y1, bn1, F_,  C1_, 8);
  bn_act_kernel<<<dim3(B_, 8), 256, 0, stream>>>(y1, bn1, bn1_g, bn1_b, se1_in, C1_, 1);
  se_kernel<<<B_, 256, 0, stream>>>(se1_in, se1_w1, se1_w2, se1_sc, C1_, C1_/16);
  convmf_kernel<<<dim3(16, C2_/64, B_), 256, 0, stream>>>(y1, wp2, conv2_b, se1_sc, y2, bn2, C1_, C2_, 5);
  bn_act_kernel<<<dim3(B_, 8), 256, 0, stream>>>(y2, bn2, bn2_g, bn2_b, se2_in, C2_, 1);
  se_kernel<<<B_, 256, 0, stream>>>(se2_in, se2_w1, se2_w2, se2_sc, C2_, C2_/16);
  convmf_kernel<<<dim3(16, C3_/64, B_), 256, 0, stream>>>(y2, wp3, conv3_b, se2_sc, y3, bn3, C2_, C3_, 3);
  bn_act_kernel<<<dim3(B_, 8), 256, 0, stream>>>(y3, bn3, bn3_g, bn3_b, x2, C3_, 0);

  // ---- final head
  head2_kernel<<<B_, 64, 0, stream>>>(x1, x2, fc_w, fc_b, out_ls);
}

// Round 7
// 1064.449 us; speedup vs baseline: 2.2258x; 1.0193x over previous
//
#include <hip/hip_runtime.h>
#include <math.h>

#define B_ 32
#define T_ 1024
#define F_ 64
#define H_ 128
#define D_ 192
#define KH_ 16
#define C1_ 128
#define C2_ 256
#define C3_ 128
#define NC_ 10

typedef float v2f __attribute__((ext_vector_type(2)));
typedef float f32x4 __attribute__((ext_vector_type(4)));
typedef __bf16 bfrag __attribute__((ext_vector_type(8)));

__device__ __forceinline__ float sig_(float x){ return 1.f/(1.f+__expf(-x)); }
__device__ __forceinline__ float tanh_(float x){ return 1.f - 2.f/(__expf(2.f*x)+1.f); }
__device__ __forceinline__ float gelu_(float x){ return 0.5f*x*(1.f+erff(x*0.70710678118654752f)); }
__device__ __forceinline__ float softplus_(float x){ return fmaxf(x,0.f) + log1pf(__expf(-fabsf(x))); }

__device__ __forceinline__ unsigned bfpack(float a, float b){
  unsigned ua = __float_as_uint(a), ub = __float_as_uint(b);
  ua = ua + 0x7FFFu + ((ua>>16)&1u);
  ub = ub + 0x7FFFu + ((ub>>16)&1u);
  return (ua>>16) | (ub & 0xFFFF0000u);
}
__device__ __forceinline__ unsigned short bf1(float a){
  unsigned ua = __float_as_uint(a);
  ua = ua + 0x7FFFu + ((ua>>16)&1u);
  return (unsigned short)(ua>>16);
}
__device__ __forceinline__ float bf2f(unsigned short h){
  return __uint_as_float(((unsigned)h)<<16);
}

#define QPERM_XOR1(x) __int_as_float(__builtin_amdgcn_mov_dpp(__float_as_int(x), 0xB1, 0xF, 0xF, true))
#define QPERM_XOR2(x) __int_as_float(__builtin_amdgcn_mov_dpp(__float_as_int(x), 0x4E, 0xF, 0xF, true))

// LDS-only barrier: waits ds ops (lgkm) but lets global stores stay in flight
#define LDS_BARRIER() asm volatile("s_waitcnt lgkmcnt(0)\n\ts_barrier" ::: "memory")

// ================================================================ bodies

// ---- ax precompute (transposed out: axT[b][j][t])
__device__ __forceinline__ void ax_body(int blk, char* smemraw,
    const float* __restrict__ x, const float* __restrict__ w1, const float* __restrict__ b1,
    float* __restrict__ axT)
{
  struct AxS { float xs[16][68]; float w1s[64][16]; };
  AxS* sm = (AxS*)smemraw;
  const int bt0 = blk*16;
  const int tid = threadIdx.x;
  for(int i=tid;i<64*16;i+=256){ sm->w1s[i>>4][i&15] = w1[i]; }
  for(int i=tid;i<16*64;i+=256){ const int r=i>>6, d=i&63; sm->xs[r][d] = x[(size_t)(bt0+r)*64 + d]; }
  __syncthreads();
  const int r = tid>>4, j = tid&15;
  float s = b1[j];
  #pragma unroll
  for(int d=0; d<64; d++) s += sm->xs[r][d]*sm->w1s[d][j];
  const int bt = bt0 + r;
  axT[((size_t)(bt>>10)*16 + j)*1024 + (bt&1023)] = s;
}

// ---- weight prepack (bf16 MFMA B-fragment blocks, all 3 convs)
__device__ __forceinline__ void prepack_body(int blk,
    const float* __restrict__ w1s, const float* __restrict__ w2s, const float* __restrict__ w3s,
    unsigned short* __restrict__ wp1, unsigned short* __restrict__ wp2, unsigned short* __restrict__ wp3)
{
  int e = blk*256 + threadIdx.x;
  if(e >= 65536+163840+98304) return;
  const float* w; unsigned short* wp; int Cout, Cin, Kw;
  if(e < 65536){ w=w1s; wp=wp1; Cout=C1_; Cin=F_;  Kw=8; }
  else if(e < 65536+163840){ e-=65536; w=w2s; wp=wp2; Cout=C2_; Cin=C1_; Kw=5; }
  else { e-=229376; w=w3s; wp=wp3; Cout=C3_; Cin=C2_; Kw=3; }
  const int co = e/(Cin*Kw);
  const int rem = e - co*(Cin*Kw);
  const int ci = rem/Kw, kw = rem - ci*Kw;
  const int off = (((ci>>5)*Kw + kw)*(Cout>>4) + (co>>4))*512 + ((co&15)*4 + ((ci>>3)&3))*8 + (ci&7);
  wp[off] = bf1(w[e]);
}

// ---- LSTM scan: 4 waves / batch, gate-split lane pairs.
// lane pair p=tid&1 owns h[hi=tid>>1]; p0 computes gates (i,f), p1 (g,o);
// tg/so cross pair via quad-DPP. Phase A redundant per wave (broadcast LDS reads).
__device__ __forceinline__ void lstm_body(int b, char* smemraw,
    const float* __restrict__ axT, const float* __restrict__ w1,
    const float* __restrict__ w2, const float* __restrict__ b2,
    float* __restrict__ hidden)
{
  float* hsall = (float*)smemraw;   // [2][148] double-buffered, chunk stride 36
  const int tid = threadIdx.x;
  const int l = tid & 63;
  const int j = l >> 2, g = l & 3;
  const int p = tid & 1;
  const int hi = tid >> 1;

  v2f w1hv[16];
  #pragma unroll
  for(int q=0;q<16;q++){
    w1hv[q].x = w1[(64 + g*32 + 2*q)*KH_ + j];
    w1hv[q].y = w1[(64 + g*32 + 2*q + 1)*KH_ + j];
  }
  const int go = p ? 256 : 0;   // p0 -> (i,f) at 0/128 ; p1 -> (g,o) at 256/384
  v2f w2r[16];
  #pragma unroll
  for(int k=0;k<16;k++){
    w2r[k].x = w2[k*512 + go + hi];
    w2r[k].y = w2[k*512 + go + 128 + hi];
  }
  v2f bp; bp.x = b2[go + hi]; bp.y = b2[go + 128 + hi];

  for(int i=tid;i<2*148;i+=256) hsall[i]=0.f;
  float c = 0.f;   // meaningful on p0 only
  const float* axr = axT + ((size_t)b*16 + j)*1024;
  float* hb = hidden + (size_t)b*T_*H_;
  const int hwi = (hi>>5)*36 + (hi&31);
  float4 axA = *(const float4*)&axr[0];
  float4 axB = *(const float4*)&axr[4];
  __syncthreads();

#define LSTM_STEP(tt, axv, RB) { \
    const float* hsr = hsall + (RB)*148; \
    float* hsw = hsall + (1-(RB))*148; \
    v2f ap0=(v2f)(0.f), ap1=(v2f)(0.f), ap2=(v2f)(0.f), ap3=(v2f)(0.f); \
    { const float4 hv = *(const float4*)&hsr[g*36 + 0];  ap0 += ((v2f){hv.x,hv.y})*w1hv[0]  + ((v2f){hv.z,hv.w})*w1hv[1]; } \
    { const float4 hv = *(const float4*)&hsr[g*36 + 4];  ap1 += ((v2f){hv.x,hv.y})*w1hv[2]  + ((v2f){hv.z,hv.w})*w1hv[3]; } \
    { const float4 hv = *(const float4*)&hsr[g*36 + 8];  ap2 += ((v2f){hv.x,hv.y})*w1hv[4]  + ((v2f){hv.z,hv.w})*w1hv[5]; } \
    { const float4 hv = *(const float4*)&hsr[g*36 + 12]; ap3 += ((v2f){hv.x,hv.y})*w1hv[6]  + ((v2f){hv.z,hv.w})*w1hv[7]; } \
    { const float4 hv = *(const float4*)&hsr[g*36 + 16]; ap0 += ((v2f){hv.x,hv.y})*w1hv[8]  + ((v2f){hv.z,hv.w})*w1hv[9]; } \
    { const float4 hv = *(const float4*)&hsr[g*36 + 20]; ap1 += ((v2f){hv.x,hv.y})*w1hv[10] + ((v2f){hv.z,hv.w})*w1hv[11]; } \
    { const float4 hv = *(const float4*)&hsr[g*36 + 24]; ap2 += ((v2f){hv.x,hv.y})*w1hv[12] + ((v2f){hv.z,hv.w})*w1hv[13]; } \
    { const float4 hv = *(const float4*)&hsr[g*36 + 28]; ap3 += ((v2f){hv.x,hv.y})*w1hv[14] + ((v2f){hv.z,hv.w})*w1hv[15]; } \
    const v2f apt = (ap0+ap1)+(ap2+ap3); \
    float a = apt.x + apt.y; \
    a += QPERM_XOR1(a); \
    a += QPERM_XOR2(a); \
    a += (axv); \
    const float g1v = a * sig_(a); \
    v2f aP = bp; \
    _Pragma("unroll") \
    for(int k=0;k<16;k++){ \
      const float gk = __int_as_float(__builtin_amdgcn_readlane(__float_as_int(g1v), 4*k)); \
      v2f gk2; gk2.x=gk; gk2.y=gk; \
      aP += gk2 * w2r[k]; \
    } \
    const float A0 = aP.x, A1 = aP.y; \
    const float arg0 = p ? (A0+A0) : A0; \
    const float s0 = sig_(arg0); \
    const float v0 = p ? (s0+s0-1.f) : s0;   /* p0: si ; p1: tg */ \
    const float v1 = sig_(A1);               /* p0: sf ; p1: so */ \
    const float tgx = QPERM_XOR1(v0);        /* p0 <- tg */ \
    const float sox = QPERM_XOR1(v1);        /* p0 <- so */ \
    c = v1*c + v0*tgx; \
    const float t2 = tanh_(c); \
    const float h = sox * t2; \
    if(!p){ hsw[hwi] = h; hb[(size_t)(tt)*H_ + hi] = h; } \
    LDS_BARRIER(); \
  }

  for(int t0=0;t0<T_;t0+=4){
    const int tl = (t0+8 < 1020) ? (t0+8) : 1020;
    const float4 axC = *(const float4*)&axr[tl];
    LSTM_STEP(t0+0, axA.x, 0)
    LSTM_STEP(t0+1, axA.y, 1)
    LSTM_STEP(t0+2, axA.z, 0)
    LSTM_STEP(t0+3, axA.w, 1)
    axA = axB; axB = axC;
  }
#undef LSTM_STEP
}

// ---- row norms
__device__ __forceinline__ void norm_body(int blk,
    const float* __restrict__ hidden, float* __restrict__ norms)
{
  const int row = blk*8 + (threadIdx.x>>5);
  const int l = threadIdx.x&31;
  const float* hr = hidden + (size_t)row*H_;
  float s = 0.f;
  for(int k=l;k<H_;k+=32){ float v=hr[k]; s+=v*v; }
  #pragma unroll
  for(int m=16;m>=1;m>>=1) s += __shfl_xor(s, m, 64);
  if(l==0) norms[row] = fmaxf(sqrtf(s), 1e-8f);
}

// ---- S rowsums via bf16 MFMA (hi/lo split Gram)
struct SS {
  unsigned short Ahi[64*136];
  unsigned short Alo[64*136];
  unsigned short Bhi[64*136];
  unsigned short Blo[64*136];
  double red[64][17];
};
__device__ __forceinline__ void s_body(int blk, char* smemraw,
    const float* __restrict__ hidden, const float* __restrict__ norms,
    double* __restrict__ rowsum, double* __restrict__ psum)
{
  SS* sm = (SS*)smemraw;
  const int b = blk >> 4;
  const int i0 = (blk & 15) * 64;
  const int tid = threadIdx.x, l = tid & 63, wv = tid >> 6;
  const int m = l & 15, q = l >> 4;
  const float* hb = hidden + (size_t)b*T_*H_;
  const float* nb = norms + (size_t)b*T_;

  for(int idx=tid; idx<64*32; idx+=256){
    const int r = idx>>5, k4 = (idx&31)*4;
    float4 v = *(const float4*)&hb[(size_t)(i0+r)*H_ + k4];
    const float inv = 1.f/nb[i0+r];
    const float f0=v.x*inv, f1=v.y*inv, f2=v.z*inv, f3=v.w*inv;
    const unsigned short h0=bf1(f0), h1=bf1(f1), h2=bf1(f2), h3=bf1(f3);
    uint2 phi; phi.x = (unsigned)h0 | ((unsigned)h1<<16); phi.y = (unsigned)h2 | ((unsigned)h3<<16);
    *(uint2*)&sm->Ahi[r*136 + k4] = phi;
    const unsigned short g0=bf1(f0-bf2f(h0)), g1=bf1(f1-bf2f(h1)), g2=bf1(f2-bf2f(h2)), g3=bf1(f3-bf2f(h3));
    uint2 plo; plo.x = (unsigned)g0 | ((unsigned)g1<<16); plo.y = (unsigned)g2 | ((unsigned)g3<<16);
    *(uint2*)&sm->Alo[r*136 + k4] = plo;
  }

  double rs[4]={0,0,0,0}, ps[4]={0,0,0,0};
  const int arow = (wv*16 + m)*136;

  for(int jt=0;jt<16;jt++){
    const int j0 = jt*64;
    __syncthreads();
    for(int idx=tid; idx<64*32; idx+=256){
      const int r = idx>>5, k4 = (idx&31)*4;
      float4 v = *(const float4*)&hb[(size_t)(j0+r)*H_ + k4];
      const float inv = 1.f/nb[j0+r];
      const float f0=v.x*inv, f1=v.y*inv, f2=v.z*inv, f3=v.w*inv;
      const unsigned short h0=bf1(f0), h1=bf1(f1), h2=bf1(f2), h3=bf1(f3);
      uint2 phi; phi.x = (unsigned)h0 | ((unsigned)h1<<16); phi.y = (unsigned)h2 | ((unsigned)h3<<16);
      *(uint2*)&sm->Bhi[r*136 + k4] = phi;
      const unsigned short g0=bf1(f0-bf2f(h0)), g1=bf1(f1-bf2f(h1)), g2=bf1(f2-bf2f(h2)), g3=bf1(f3-bf2f(h3));
      uint2 plo; plo.x = (unsigned)g0 | ((unsigned)g1<<16); plo.y = (unsigned)g2 | ((unsigned)g3<<16);
      *(uint2*)&sm->Blo[r*136 + k4] = plo;
    }
    __syncthreads();

    f32x4 acc[4];
    #pragma unroll
    for(int nt=0;nt<4;nt++) acc[nt] = (f32x4)(0.f);
    #pragma unroll
    for(int kc=0;kc<4;kc++){
      const bfrag Ah = *(const bfrag*)&sm->Ahi[arow + kc*32 + q*8];
      const bfrag Al = *(const bfrag*)&sm->Alo[arow + kc*32 + q*8];
      #pragma unroll
      for(int nt=0;nt<4;nt++){
        const int brow = (nt*16 + m)*136 + kc*32 + q*8;
        const bfrag Bh = *(const bfrag*)&sm->Bhi[brow];
        const bfrag Bl = *(const bfrag*)&sm->Blo[brow];
        acc[nt] = __builtin_amdgcn_mfma_f32_16x16x32_bf16(Ah, Bh, acc[nt], 0, 0, 0);
        acc[nt] = __builtin_amdgcn_mfma_f32_16x16x32_bf16(Al, Bh, acc[nt], 0, 0, 0);
        acc[nt] = __builtin_amdgcn_mfma_f32_16x16x32_bf16(Ah, Bl, acc[nt], 0, 0, 0);
      }
    }
    #pragma unroll
    for(int nt=0;nt<4;nt++){
      const int gj = j0 + nt*16 + m;
      #pragma unroll
      for(int r=0;r<4;r++){
        const int gi = i0 + wv*16 + q*4 + r;
        if(gi == gj) continue;
        const float sv = __expf(-5.5f*(1.f - acc[nt][r]));
        rs[r] += (double)sv;
        if(gj < gi) ps[r] += (double)sv;
      }
    }
  }
  __syncthreads();
  #pragma unroll
  for(int r=0;r<4;r++) sm->red[wv*16 + q*4 + r][m] = rs[r];
  __syncthreads();
  if(tid<64){ double v=0; for(int k=0;k<16;k++) v+=sm->red[tid][k]; rowsum[(size_t)b*T_ + i0 + tid]=v; }
  __syncthreads();
  #pragma unroll
  for(int r=0;r<4;r++) sm->red[wv*16 + q*4 + r][m] = ps[r];
  __syncthreads();
  if(tid<64){ double v=0; for(int k=0;k<16;k++) v+=sm->red[tid][k]; psum[(size_t)b*T_ + i0 + tid]=v; }
}

// ---- cluster: prefix+dist+argmax+corr
struct CS {
  double sr[256]; double sp[256]; double bd[256]; double totR;
  float c2[2][128]; int bidx[256]; int cut;
};
__device__ __forceinline__ void cluster_body(int b, char* smemraw,
    const double* __restrict__ rowsum, const double* __restrict__ psum,
    const float* __restrict__ hidden, float* __restrict__ corr, int* __restrict__ cuts)
{
  CS* sm = (CS*)smemraw;
  const int tid = threadIdx.x;
  const double* r = rowsum + (size_t)b*T_;
  const double* p = psum + (size_t)b*T_;
  double r4[4], p4[4];
  #pragma unroll
  for(int q=0;q<4;q++){ r4[q]=r[tid*4+q]; p4[q]=p[tid*4+q]; }
  sm->sr[tid]=r4[0]+r4[1]+r4[2]+r4[3];
  sm->sp[tid]=p4[0]+p4[1]+p4[2]+p4[3];
  __syncthreads();
  if(tid==0){
    double ar=0, ap=0;
    for(int i=0;i<256;i++){ double tr=sm->sr[i], tp=sm->sp[i]; sm->sr[i]=ar; sm->sp[i]=ap; ar+=tr; ap+=tp; }
    sm->totR = ar;
  }
  __syncthreads();
  double cr = sm->sr[tid], cp = sm->sp[tid];
  const double full = sm->totR;
  double best = -1e308; int bi = 1;
  #pragma unroll
  for(int q=0;q<4;q++){
    cr += r4[q]; cp += p4[q];
    const int i = 4*tid + q + 1;
    if(i < T_){
      const double TL = 2.0*cp;
      const double TRv = cr - TL;
      const double BR = full - TL - 2.0*TRv;
      const double di = (double)i, dn = (double)(T_-i);
      const double dist = TL/(di*di) + BR/(dn*dn) - (2.0*TRv)/(di*dn);
      if(dist > best){ best=dist; bi=i; }
    }
  }
  sm->bd[tid]=best; sm->bidx[tid]=bi;
  __syncthreads();
  if(tid==0){
    double bb=-1e308; int ii=1;
    for(int q=0;q<256;q++){ if(sm->bd[q]>bb){ bb=sm->bd[q]; ii=sm->bidx[q]; } }
    sm->cut=ii; cuts[b]=ii;
  }
  __syncthreads();
  const int cut = sm->cut;
  const int h = tid&127, half = tid>>7;
  float s=0.f;
  const float* hb = hidden + (size_t)b*T_*H_;
  for(int t=half; t<cut; t+=2) s += hb[(size_t)t*H_ + h];
  sm->c2[half][h]=s;
  __syncthreads();
  if(tid<128) corr[b*H_+tid] = (sm->c2[0][tid]+sm->c2[1][tid])/(float)cut;
}

// ---- VAE heads (256 threads, upper half idles through syncs)
__device__ __forceinline__ void head1_body(int b, char* smemraw,
    const float* __restrict__ corr, const float* __restrict__ hidden,
    const float* __restrict__ eps_z, const float* __restrict__ eps_cat,
    const float* __restrict__ mu_w, const float* __restrict__ mu_b,
    const float* __restrict__ std_w, const float* __restrict__ std_b,
    const float* __restrict__ muc_w, const float* __restrict__ muc_b,
    const float* __restrict__ stdc_w, const float* __restrict__ stdc_b,
    float* __restrict__ out_mu, float* __restrict__ out_std,
    float* __restrict__ out_muc, float* __restrict__ out_stdc, float* __restrict__ x1)
{
  struct H1 { float cs[128]; float xz[256]; };
  H1* sm = (H1*)smemraw;
  const int h = threadIdx.x;
  if(h<128){
    sm->cs[h]=corr[b*H_+h];
    sm->xz[h]=hidden[((size_t)b*T_ + (T_-1))*H_ + h];
  }
  __syncthreads();
  if(h<128){
    float m=mu_b[h], sdv=std_b[h];
    for(int k=0;k<H_;k++){ const float cv=sm->cs[k]; m+=cv*mu_w[k*H_+h]; sdv+=cv*std_w[k*H_+h]; }
    const float stdv = softplus_(sdv);
    out_mu[b*H_+h]=m; out_std[b*H_+h]=stdv;
    sm->xz[128+h] = m + stdv*eps_z[b*H_+h];
  }
  __syncthreads();
  if(h<128){
    float mc=muc_b[h], sc=stdc_b[h];
    for(int k=0;k<256;k++){ const float v=sm->xz[k]; mc+=v*muc_w[k*H_+h]; sc+=v*stdc_w[k*H_+h]; }
    const float stdc = softplus_(sc);
    out_muc[b*H_+h]=mc; out_stdc[b*H_+h]=stdc;
    x1[b*H_+h]=mc + stdc*eps_cat[b*H_+h];
  }
}

// ---- causal conv via bf16 MFMA + fused BN partials
__device__ __forceinline__ void conv_body(int bx, int by, int bz, char* smemraw,
    const float* __restrict__ in, const unsigned short* __restrict__ wp,
    const float* __restrict__ bias, const float* __restrict__ scale,
    float* __restrict__ y, float* __restrict__ bnacc, int Cin, int Cout, int Kw)
{
  unsigned short* xs = (unsigned short*)smemraw;   // [72][40] bf16; reused as float part[]
  const int b = bz, t0 = bx*64, co0 = by*64;
  const int tid = threadIdx.x, l = tid&63, wv = tid>>6;
  const int q = l>>4, m = l&15;
  const int TW = 64 + Kw - 1;
  const int abase = (wv*16 + m)*40 + q*8;
  const int boff = (m*4 + q)*8;
  f32x4 acc[4];
  #pragma unroll
  for(int nt=0;nt<4;nt++) acc[nt] = (f32x4)(0.f);

  const int nchunks = Cin >> 5;
  for(int cc=0; cc<nchunks; cc++){
    __syncthreads();
    for(int idx=tid; idx<TW*8; idx+=256){
      const int r = idx>>3, c4 = (idx&7)*4;
      const int tg = t0 - (Kw-1) + r;
      uint2 pk = make_uint2(0u, 0u);
      if(tg >= 0){
        float4 v = *(const float4*)&in[((size_t)b*T_ + tg)*Cin + cc*32 + c4];
        if(scale){
          const float4 s4 = *(const float4*)&scale[b*Cin + cc*32 + c4];
          v.x*=s4.x; v.y*=s4.y; v.z*=s4.z; v.w*=s4.w;
        }
        pk.x = bfpack(v.x, v.y); pk.y = bfpack(v.z, v.w);
      }
      *(uint2*)&xs[r*40 + c4] = pk;
    }
    __syncthreads();
    for(int kw=0; kw<Kw; kw++){
      const bfrag Af = *(const bfrag*)&xs[abase + kw*40];
      #pragma unroll
      for(int nt=0; nt<4; nt++){
        const unsigned short* wpp = wp + ((size_t)((cc*Kw + kw)*(Cout>>4) + (by*4 + nt)))*512 + boff;
        const bfrag Bf = *(const bfrag*)wpp;
        acc[nt] = __builtin_amdgcn_mfma_f32_16x16x32_bf16(Af, Bf, acc[nt], 0, 0, 0);
      }
    }
  }
  __syncthreads();
  float* part = (float*)xs;   // [4 wv][64 co][2]
  const int t_base = t0 + wv*16 + q*4;
  #pragma unroll
  for(int nt=0; nt<4; nt++){
    const int co = co0 + nt*16 + m;
    const float bv = bias[co];
    float s1 = 0.f, s2 = 0.f;
    #pragma unroll
    for(int r=0;r<4;r++){
      const float v = acc[nt][r] + bv;
      y[((size_t)b*T_ + t_base + r)*Cout + co] = v;
      s1 += v; s2 += v*v;
    }
    s1 += __shfl_xor(s1, 16); s1 += __shfl_xor(s1, 32);
    s2 += __shfl_xor(s2, 16); s2 += __shfl_xor(s2, 32);
    if(q==0){ part[(wv*64 + nt*16 + m)*2+0] = s1; part[(wv*64 + nt*16 + m)*2+1] = s2; }
  }
  __syncthreads();
  if(tid < 64){
    float a1=0.f, a2=0.f;
    #pragma unroll
    for(int w2i=0; w2i<4; w2i++){ a1 += part[(w2i*64+tid)*2+0]; a2 += part[(w2i*64+tid)*2+1]; }
    atomicAdd(&bnacc[co0 + tid], a1);
    atomicAdd(&bnacc[Cout + co0 + tid], a2);
  }
}

// ---- BN + gelu + per-(b,c) t-sum accum
__device__ __forceinline__ void bn_act_body(int b, int chunk, char* smemraw,
    float* __restrict__ y, const float* __restrict__ bnacc,
    const float* __restrict__ gw, const float* __restrict__ bw,
    float* __restrict__ mean_acc, int C, int write_y)
{
  const int t0 = chunk*128, tid = threadIdx.x;
  const int c = tid & (C-1), part = tid / C, np = 256 / C;
  const float cnt = (float)(B_*T_);
  const float mm = bnacc[c]/cnt;
  const float var = bnacc[C+c]/cnt - mm*mm;
  const float sc = gw[c]/sqrtf(var+1e-3f);
  const float sh = bw[c] - mm*sc;
  float s = 0.f;
  for(int t=t0+part; t<t0+128; t+=np){
    const size_t off = ((size_t)b*T_ + t)*C + c;
    float v = y[off];
    v = gelu_(v*sc + sh);
    if(write_y) y[off] = v;
    s += v;
  }
  float* rs = (float*)smemraw;
  if(np > 1){
    rs[tid]=s;
    __syncthreads();
    if(part==0) s += rs[tid+C];
  }
  if(part==0) atomicAdd(&mean_acc[b*C+c], s);
}

// ---- SE (mean_in holds t-SUMS; scaled by 1/T here)
__device__ __forceinline__ void se_body(int b, char* smemraw,
    const float* __restrict__ mean_in, const float* __restrict__ w1, const float* __restrict__ w2,
    float* __restrict__ scale, int C, int R)
{
  struct SE { float ms[256]; float hs2[16]; };
  SE* sm = (SE*)smemraw;
  const int tid=threadIdx.x;
  if(tid<C) sm->ms[tid]=mean_in[b*C+tid]*(1.f/(float)T_);
  __syncthreads();
  if(tid<R){ float s=0; for(int k=0;k<C;k++) s+=sm->ms[k]*w1[k*R+tid]; sm->hs2[tid]=fmaxf(s,0.f); }
  __syncthreads();
  if(tid<C){ float s=0; for(int k=0;k<R;k++) s+=sm->hs2[k]*w2[k*C+tid]; scale[b*C+tid]=sig_(s); }
}

// ================================================================ kernels

__global__ __launch_bounds__(256) void mega0_kernel(
    const float* c1w, const float* c2w, const float* c3w,
    unsigned short* wp1, unsigned short* wp2, unsigned short* wp3,
    const float* x, const float* kw1, const float* kb1, float* axT)
{
  __shared__ __align__(16) char sm[16*68*4 + 64*16*4];
  const int bid = blockIdx.x;
  if(bid < 1280) prepack_body(bid, c1w, c2w, c3w, wp1, wp2, wp3);
  else ax_body(bid-1280, sm, x, kw1, kb1, axT);
}

__global__ __launch_bounds__(256, 1) void mega1_kernel(
    const float* axT, const float* kw1, const float* kw2, const float* kb2, float* hidden,
    const float* x, const unsigned short* wp1, const float* c1b, float* y1, float* bn1)
{
  __shared__ __align__(16) char sm[5888];
  const int bid = blockIdx.x;
  if(bid < 32) lstm_body(bid, sm, axT, kw1, kw2, kb2, hidden);
  else {
    const int cb = bid - 32;
    conv_body(cb&15, (cb>>4)&1, cb>>5, sm, x, wp1, c1b, nullptr, y1, bn1, F_, C1_, 8);
  }
}

__global__ __launch_bounds__(256) void mega_n1_kernel(
    const float* hidden, float* norms,
    float* y1, const float* bn1, const float* g1w, const float* b1w, float* se1_in)
{
  __shared__ __align__(16) char sm[1024];
  const int bid = blockIdx.x;
  if(bid < 4096) norm_body(bid, hidden, norms);
  else { const int cb = bid-4096; bn_act_body(cb>>3, cb&7, sm, y1, bn1, g1w, b1w, se1_in, C1_, 1); }
}

__global__ __launch_bounds__(256) void mega_s_kernel(
    const float* hidden, const float* norms, double* rowsum, double* psum,
    const float* se1_in, const float* s1w1, const float* s1w2, float* se1_sc)
{
  __shared__ __align__(16) char sm[sizeof(SS)];
  const int bid = blockIdx.x;
  if(bid < 512) s_body(bid, sm, hidden, norms, rowsum, psum);
  else se_body(bid-512, sm, se1_in, s1w1, s1w2, se1_sc, C1_, C1_/16);
}

__global__ __launch_bounds__(256) void mega_c_kernel(
    const double* rowsum, const double* psum, const float* hidden, float* corr, int* cuts,
    const float* y1, const unsigned short* wp2, const float* c2b, const float* se1_sc,
    float* y2, float* bn2)
{
  __shared__ __align__(16) char sm[sizeof(CS) > 5888 ? sizeof(CS) : 5888];
  const int bid = blockIdx.x;
  if(bid < 32) cluster_body(bid, sm, rowsum, psum, hidden, corr, cuts);
  else {
    const int cb = bid - 32;
    conv_body(cb&15, (cb>>4)&3, cb>>6, sm, y1, wp2, c2b, se1_sc, y2, bn2, C1_, C2_, 5);
  }
}

__global__ __launch_bounds__(256) void mega_h_kernel(
    const float* corr, const float* hidden, const float* eps_z, const float* eps_cat,
    const float* mu_w, const float* mu_b, const float* std_w, const float* std_b,
    const float* muc_w, const float* muc_b, const float* stdc_w, const float* stdc_b,
    float* out_mu, float* out_std, float* out_muc, float* out_stdc, float* x1,
    float* y2, const float* bn2, const float* g2w, const float* b2w, float* se2_in)
{
  __shared__ __align__(16) char sm[1536];
  const int bid = blockIdx.x;
  if(bid < 32) head1_body(bid, sm, corr, hidden, eps_z, eps_cat, mu_w, mu_b, std_w, std_b,
                          muc_w, muc_b, stdc_w, stdc_b, out_mu, out_std, out_muc, out_stdc, x1);
  else { const int cb = bid-32; bn_act_body(cb>>3, cb&7, sm, y2, bn2, g2w, b2w, se2_in, C2_, 1); }
}

__global__ __launch_bounds__(256) void se_kernel(
    const float* mean_in, const float* w1, const float* w2, float* scale, int C, int R)
{
  __shared__ __align__(16) char sm[1088];
  se_body(blockIdx.x, sm, mean_in, w1, w2, scale, C, R);
}

__global__ __launch_bounds__(256) void convmf_kernel(
    const float* in, const unsigned short* wp, const float* bias, const float* scale,
    float* y, float* bnacc, int Cin, int Cout, int Kw)
{
  __shared__ __align__(16) char sm[5888];
  conv_body(blockIdx.x, blockIdx.y, blockIdx.z, sm, in, wp, bias, scale, y, bnacc, Cin, Cout, Kw);
}

__global__ __launch_bounds__(256) void bn_act_kernel(
    float* y, const float* bnacc, const float* gw, const float* bw,
    float* mean_acc, int C, int write_y)
{
  __shared__ __align__(16) char sm[1024];
  bn_act_body(blockIdx.x, blockIdx.y, sm, y, bnacc, gw, bw, mean_acc, C, write_y);
}

__global__ __launch_bounds__(64) void head2_kernel(
    const float* __restrict__ x1, const float* __restrict__ x2,
    const float* __restrict__ fcw, const float* __restrict__ fcb, float* __restrict__ outls)
{
  const int b=blockIdx.x, tid=threadIdx.x;
  __shared__ float xa[256]; __shared__ float lg[NC_];
  for(int k=tid;k<256;k+=64) xa[k] = (k<128)? x1[b*128+k] : x2[b*128+(k-128)]*(1.f/(float)T_);
  __syncthreads();
  if(tid<NC_){
    float s = fcb[tid];
    for(int k=0;k<256;k++) s += xa[k]*fcw[k*NC_+tid];
    lg[tid]=s;
  }
  __syncthreads();
  if(tid==0){
    float mx=lg[0];
    for(int q=1;q<NC_;q++) mx=fmaxf(mx,lg[q]);
    float se=0;
    for(int q=0;q<NC_;q++) se += __expf(lg[q]-mx);
    const float lse = logf(se)+mx;
    for(int q=0;q<NC_;q++) outls[b*NC_+q] = lg[q]-lse;
  }
}

// ================================================================ launch
extern "C" void kernel_launch(void* const* d_in, const int* in_sizes, int n_in,
                              void* d_out, int out_size, void* d_ws, size_t ws_size,
                              hipStream_t stream) {
  (void)in_sizes; (void)n_in; (void)out_size; (void)ws_size;
  const float* x        = (const float*)d_in[0];
  const float* eps_z    = (const float*)d_in[1];
  const float* eps_cat  = (const float*)d_in[2];
  const float* kan_w1   = (const float*)d_in[3];
  const float* kan_b1   = (const float*)d_in[4];
  const float* kan_w2   = (const float*)d_in[5];
  const float* kan_b2   = (const float*)d_in[6];
  const float* conv1_w  = (const float*)d_in[7];
  const float* conv1_b  = (const float*)d_in[8];
  const float* conv2_w  = (const float*)d_in[9];
  const float* conv2_b  = (const float*)d_in[10];
  const float* conv3_w  = (const float*)d_in[11];
  const float* conv3_b  = (const float*)d_in[12];
  const float* bn1_g    = (const float*)d_in[13];
  const float* bn1_b    = (const float*)d_in[14];
  const float* bn2_g    = (const float*)d_in[15];
  const float* bn2_b    = (const float*)d_in[16];
  const float* bn3_g    = (const float*)d_in[17];
  const float* bn3_b    = (const float*)d_in[18];
  const float* se1_w1   = (const float*)d_in[19];
  const float* se1_w2   = (const float*)d_in[20];
  const float* se2_w1   = (const float*)d_in[21];
  const float* se2_w2   = (const float*)d_in[22];
  const float* fc_mu_w  = (const float*)d_in[23];
  const float* fc_mu_b  = (const float*)d_in[24];
  const float* fc_std_w = (const float*)d_in[25];
  const float* fc_std_b = (const float*)d_in[26];
  const float* fc_muc_w = (const float*)d_in[27];
  const float* fc_muc_b = (const float*)d_in[28];
  const float* fc_stdc_w= (const float*)d_in[29];
  const float* fc_stdc_b= (const float*)d_in[30];
  const float* fc_w     = (const float*)d_in[31];
  const float* fc_b     = (const float*)d_in[32];

  float* out = (float*)d_out;
  float* out_ls   = out;
  float* out_mu   = out + 320;
  float* out_std  = out + 320 + 4096;
  float* out_muc  = out + 320 + 2*4096;
  float* out_stdc = out + 320 + 3*4096;

  float* ws = (float*)d_ws;
  const size_t SZ_HID = (size_t)B_*T_*H_;
  const size_t SZ_Y1  = (size_t)B_*T_*C1_;
  const size_t SZ_Y2  = (size_t)B_*T_*C2_;
  float*  hidden = ws;                      // [b][t][H]; reused as y3 [b][t][C3]
  float*  y1     = hidden + SZ_HID;
  float*  y2     = y1 + SZ_Y1;
  float*  norms  = y2 + SZ_Y2;
  double* rowsum = (double*)(norms + (size_t)B_*T_);
  double* psum   = rowsum + (size_t)B_*T_;
  float*  corr   = (float*)(psum + (size_t)B_*T_);
  float*  x1     = corr + (size_t)B_*H_;
  float*  bnbuf  = x1 + (size_t)B_*H_;      // 1024 floats
  float*  bn1    = bnbuf;
  float*  bn2    = bnbuf + 2*C1_;
  float*  bn3    = bnbuf + 2*C1_ + 2*C2_;
  float*  se1_in = bnbuf + 1024;
  float*  se1_sc = se1_in + (size_t)B_*C1_;
  float*  se2_in = se1_sc + (size_t)B_*C1_;
  float*  se2_sc = se2_in + (size_t)B_*C2_;
  float*  x2     = se2_sc + (size_t)B_*C2_;
  int*    cuts   = (int*)(x2 + (size_t)B_*C3_);
  float*  axbuf  = (float*)(cuts + B_);     // axT: B*16*T
  unsigned short* wp1 = (unsigned short*)(axbuf + (size_t)B_*16*T_);
  unsigned short* wp2 = wp1 + (size_t)C1_*F_*8;
  unsigned short* wp3 = wp2 + (size_t)C2_*C1_*5;
  float*  y3     = hidden;

  hipMemsetAsync(bnbuf, 0, (size_t)(1024 + 2*B_*C1_ + 2*B_*C2_ + B_*C3_)*sizeof(float), stream);

  // D0: prepack (1280) + ax (2048)
  mega0_kernel<<<3328, 256, 0, stream>>>(conv1_w, conv2_w, conv3_w, wp1, wp2, wp3,
                                         x, kan_w1, kan_b1, axbuf);
  // D1: lstm (32) + conv1 (1024) — conv1 hides under the scan
  mega1_kernel<<<1056, 256, 0, stream>>>(axbuf, kan_w1, kan_w2, kan_b2, hidden,
                                         x, wp1, conv1_b, y1, bn1);
  // D2: norm (4096) + bn_act1 (256)
  mega_n1_kernel<<<4352, 256, 0, stream>>>(hidden, norms, y1, bn1, bn1_g, bn1_b, se1_in);
  // D3: s (512) + se1 (32)
  mega_s_kernel<<<544, 256, 0, stream>>>(hidden, norms, rowsum, psum,
                                         se1_in, se1_w1, se1_w2, se1_sc);
  // D4: cluster (32) + conv2 (2048)
  mega_c_kernel<<<2080, 256, 0, stream>>>(rowsum, psum, hidden, corr, cuts,
                                          y1, wp2, conv2_b, se1_sc, y2, bn2);
  // D5: head1 (32) + bn_act2 (256)
  mega_h_kernel<<<288, 256, 0, stream>>>(corr, hidden, eps_z, eps_cat,
      fc_mu_w, fc_mu_b, fc_std_w, fc_std_b, fc_muc_w, fc_muc_b, fc_stdc_w, fc_stdc_b,
      out_mu, out_std, out_muc, out_stdc, x1,
      y2, bn2, bn2_g, bn2_b, se2_in);
  // D6..D9: serial tail
  se_kernel<<<B_, 256, 0, stream>>>(se2_in, se2_w1, se2_w2, se2_sc, C2_, C2_/16);
  convmf_kernel<<<dim3(16, C3_/64, B_), 256, 0, stream>>>(y2, wp3, conv3_b, se2_sc, y3, bn3, C2_, C3_, 3);
  bn_act_kernel<<<dim3(B_, 8), 256, 0, stream>>>(y3, bn3, bn3_g, bn3_b, x2, C3_, 0);
  head2_kernel<<<B_, 64, 0, stream>>>(x1, x2, fc_w, fc_b, out_ls);
}